// Round 8
// baseline (345.604 us; speedup 1.0000x reference)
//
#include <hip/hip_runtime.h>
#include <math.h>

#define EPS 1e-5f

constexpr int B = 8, S = 1024, E = 512, H = 8;
constexpr int M = B * S;          // 8192 rows

typedef __attribute__((ext_vector_type(8))) short short8;  // 8 bf16 (4 VGPRs)
typedef __attribute__((ext_vector_type(4))) float f32x4;

// fp32 -> bf16 bits, round-to-nearest-even
static __device__ __forceinline__ unsigned short f2bf(float f) {
    unsigned int x = __float_as_uint(f);
    x += 0x7FFFu + ((x >> 16) & 1u);
    return (unsigned short)(x >> 16);
}
static __device__ __forceinline__ float bf2f(unsigned short u) {
    return __uint_as_float(((unsigned int)u) << 16);
}

// async global->LDS, 16B per lane (global_load_lds_dwordx4)
typedef __attribute__((address_space(3))) unsigned int  lds_uint;
typedef __attribute__((address_space(1))) unsigned int  glb_uint;
static __device__ __forceinline__ void gload16(const unsigned short* g, unsigned short* l) {
    __builtin_amdgcn_global_load_lds((const glb_uint*)g, (lds_uint*)l, 16, 0, 0);
}
// s_waitcnt vmcnt(N) only (lgkm=15, exp=7 untouched). m135: in-order drain.
template <int N>
static __device__ __forceinline__ void waitvm() {
    __builtin_amdgcn_s_waitcnt(0x0F70 | N);
}

// ---------------------------------------------------------------------------
// LN -> bf16: one wave per row (E=512, 8 elems/lane), stats via 64-lane shuffles.
// ---------------------------------------------------------------------------
__global__ __launch_bounds__(256) void ln_bf16_kernel(
    const float* __restrict__ x, const float* __restrict__ w,
    const float* __restrict__ bb, unsigned short* __restrict__ out) {
    int row = blockIdx.x * 4 + (threadIdx.x >> 6);
    int lane = threadIdx.x & 63;
    const float* xr = x + (size_t)row * E + lane * 8;
    float4 v0 = *(const float4*)xr;
    float4 v1 = *(const float4*)(xr + 4);
    float vv[8] = {v0.x, v0.y, v0.z, v0.w, v1.x, v1.y, v1.z, v1.w};
    float s = 0.f;
    #pragma unroll
    for (int i = 0; i < 8; i++) s += vv[i];
    #pragma unroll
    for (int o = 1; o < 64; o <<= 1) s += __shfl_xor(s, o);
    float mu = s * (1.0f / E);
    float qs = 0.f;
    #pragma unroll
    for (int i = 0; i < 8; i++) { float d = vv[i] - mu; qs += d * d; }
    #pragma unroll
    for (int o = 1; o < 64; o <<= 1) qs += __shfl_xor(qs, o);
    float rs = rsqrtf(qs * (1.0f / E) + EPS);
    float4 w0 = *(const float4*)(w + lane * 8), w1 = *(const float4*)(w + lane * 8 + 4);
    float4 b0 = *(const float4*)(bb + lane * 8), b1 = *(const float4*)(bb + lane * 8 + 4);
    float ww[8] = {w0.x, w0.y, w0.z, w0.w, w1.x, w1.y, w1.z, w1.w};
    float bv[8] = {b0.x, b0.y, b0.z, b0.w, b1.x, b1.y, b1.z, b1.w};
    short8 o8;
    #pragma unroll
    for (int i = 0; i < 8; i++) o8[i] = (short)f2bf((vv[i] - mu) * rs * ww[i] + bv[i]);
    *(short8*)(out + (size_t)row * E + lane * 8) = o8;
}

// ---------------------------------------------------------------------------
// Full LN (fp32 out) for the final output — wave-per-row.
// ---------------------------------------------------------------------------
__global__ __launch_bounds__(256) void ln_full_kernel(
    const float* __restrict__ x, const float* __restrict__ w,
    const float* __restrict__ bb, float* __restrict__ out) {
    int row = blockIdx.x * 4 + (threadIdx.x >> 6);
    int lane = threadIdx.x & 63;
    const float* xr = x + (size_t)row * E + lane * 8;
    float4 v0 = *(const float4*)xr;
    float4 v1 = *(const float4*)(xr + 4);
    float vv[8] = {v0.x, v0.y, v0.z, v0.w, v1.x, v1.y, v1.z, v1.w};
    float s = 0.f;
    #pragma unroll
    for (int i = 0; i < 8; i++) s += vv[i];
    #pragma unroll
    for (int o = 1; o < 64; o <<= 1) s += __shfl_xor(s, o);
    float mu = s * (1.0f / E);
    float qs = 0.f;
    #pragma unroll
    for (int i = 0; i < 8; i++) { float d = vv[i] - mu; qs += d * d; }
    #pragma unroll
    for (int o = 1; o < 64; o <<= 1) qs += __shfl_xor(qs, o);
    float rs = rsqrtf(qs * (1.0f / E) + EPS);
    float4 w0 = *(const float4*)(w + lane * 8), w1 = *(const float4*)(w + lane * 8 + 4);
    float4 b0 = *(const float4*)(bb + lane * 8), b1 = *(const float4*)(bb + lane * 8 + 4);
    float* op = out + (size_t)row * E + lane * 8;
    float4 o0, o1;
    o0.x = (vv[0] - mu) * rs * w0.x + b0.x;
    o0.y = (vv[1] - mu) * rs * w0.y + b0.y;
    o0.z = (vv[2] - mu) * rs * w0.z + b0.z;
    o0.w = (vv[3] - mu) * rs * w0.w + b0.w;
    o1.x = (vv[4] - mu) * rs * w1.x + b1.x;
    o1.y = (vv[5] - mu) * rs * w1.y + b1.y;
    o1.z = (vv[6] - mu) * rs * w1.z + b1.z;
    o1.w = (vv[7] - mu) * rs * w1.w + b1.w;
    *(float4*)op = o0;
    *(float4*)(op + 4) = o1;
}

// ---------------------------------------------------------------------------
// Weight conversion f32 -> bf16 into one packed buffer: [qkv | o | f]
// ---------------------------------------------------------------------------
__global__ __launch_bounds__(256) void w2bf_kernel(
    const float* __restrict__ wqkv, const float* __restrict__ wo,
    const float* __restrict__ wf, unsigned short* __restrict__ out) {
    int base = (blockIdx.x * 256 + threadIdx.x) * 4;
    float4 v;
    if (base < 3 * E * E)           v = *(const float4*)(wqkv + base);
    else if (base < 4 * E * E)      v = *(const float4*)(wo + (base - 3 * E * E));
    else                            v = *(const float4*)(wf + (base - 4 * E * E));
    ushort4 o;
    o.x = f2bf(v.x); o.y = f2bf(v.y); o.z = f2bf(v.z); o.w = f2bf(v.w);
    *(ushort4*)(out + base) = o;
}

// ---------------------------------------------------------------------------
// bf16 MFMA GEMM (m97 structure): C[M,Ntot] = A[M,512] @ W[Ntot,512]^T + bias
//   OUT_MODE 1: f32 +residf; 2: f32 +bf16 resid   (o-proj / ff)
// ---------------------------------------------------------------------------
template <int OUT_MODE>
__global__ __launch_bounds__(256) void gemm_mfma(
    const unsigned short* __restrict__ A, const unsigned short* __restrict__ W,
    const float* __restrict__ bias,
    const float* __restrict__ residf, const unsigned short* __restrict__ residb,
    void* __restrict__ C0, int Ntot) {
    __shared__ unsigned short As[128 * 32];
    __shared__ unsigned short Bs[128 * 32];
    const int t = threadIdx.x;
    const int wave = t >> 6, lane = t & 63;
    const int quad = lane >> 4, l16 = lane & 15;
    const int m0 = blockIdx.x * 128, n0 = blockIdx.y * 128;
    const int wm = (wave >> 1) * 64, wn = (wave & 1) * 64;

    const int srow = t >> 2;
    const int skof = (t & 3) * 8;

    f32x4 acc[4][4];
    #pragma unroll
    for (int i = 0; i < 4; i++)
        #pragma unroll
        for (int j = 0; j < 4; j++) acc[i][j] = (f32x4){0.f, 0.f, 0.f, 0.f};

    for (int k0 = 0; k0 < E; k0 += 32) {
        gload16(A + (size_t)(m0 + srow) * E + k0 + skof,        As + t * 8);
        gload16(A + (size_t)(m0 + 64 + srow) * E + k0 + skof,   As + 2048 + t * 8);
        gload16(W + (size_t)(n0 + srow) * E + k0 + skof,        Bs + t * 8);
        gload16(W + (size_t)(n0 + 64 + srow) * E + k0 + skof,   Bs + 2048 + t * 8);
        __syncthreads();
        short8 af[4], bfr[4];
        #pragma unroll
        for (int i = 0; i < 4; i++)
            af[i] = *(const short8*)&As[(wm + i * 16 + l16) * 32 + quad * 8];
        #pragma unroll
        for (int j = 0; j < 4; j++)
            bfr[j] = *(const short8*)&Bs[(wn + j * 16 + l16) * 32 + quad * 8];
        #pragma unroll
        for (int i = 0; i < 4; i++)
            #pragma unroll
            for (int j = 0; j < 4; j++)
                acc[i][j] = __builtin_amdgcn_mfma_f32_16x16x32_bf16(af[i], bfr[j], acc[i][j], 0, 0, 0);
        __syncthreads();
    }

    #pragma unroll
    for (int i = 0; i < 4; i++) {
        const int mrow0 = m0 + wm + i * 16 + quad * 4;
        #pragma unroll
        for (int j = 0; j < 4; j++) {
            const int ncol = n0 + wn + j * 16 + l16;
            const float bval = bias[ncol];
            if (OUT_MODE == 1) {
                #pragma unroll
                for (int r = 0; r < 4; r++) {
                    size_t idx = (size_t)(mrow0 + r) * Ntot + ncol;
                    ((float*)C0)[idx] = acc[i][j][r] + bval + residf[idx];
                }
            } else {
                #pragma unroll
                for (int r = 0; r < 4; r++) {
                    size_t idx = (size_t)(mrow0 + r) * Ntot + ncol;
                    ((float*)C0)[idx] = acc[i][j][r] + bval + bf2f(residb[idx]);
                }
            }
        }
    }
}

// ---------------------------------------------------------------------------
// Fused q + kv projection GEMM. Grid (M/128, 12): y<4 -> q panel (A=Aq,
// out=qout bf16 [M,512]); y>=4 -> kv panel (A=Akv, out k bf16 / v^T bf16).
// One launch, 768 blocks = 3 blocks/CU (vs 1/CU + 2/CU sequential).
// ---------------------------------------------------------------------------
__global__ __launch_bounds__(256) void gemm_qkv(
    const unsigned short* __restrict__ Aq, const unsigned short* __restrict__ Akv,
    const unsigned short* __restrict__ W,   // packed [3E][E] bf16
    const float* __restrict__ bias,         // [3E]
    unsigned short* __restrict__ qout,      // [M][512] bf16
    unsigned short* __restrict__ kout,      // [M][512] bf16
    unsigned short* __restrict__ vtout) {   // [B][512][1024] bf16
    __shared__ unsigned short As[128 * 32];
    __shared__ unsigned short Bs[128 * 32];
    const int t = threadIdx.x;
    const int wave = t >> 6, lane = t & 63;
    const int quad = lane >> 4, l16 = lane & 15;
    const bool isq = blockIdx.y < 4;
    const int yy = isq ? blockIdx.y : blockIdx.y - 4;
    const unsigned short* A  = isq ? Aq : Akv;
    const unsigned short* Wb = W + (isq ? 0 : (size_t)E * E);
    const float* bb = bias + (isq ? 0 : E);
    const int m0 = blockIdx.x * 128, n0 = yy * 128;
    const int wm = (wave >> 1) * 64, wn = (wave & 1) * 64;

    const int srow = t >> 2;
    const int skof = (t & 3) * 8;

    f32x4 acc[4][4];
    #pragma unroll
    for (int i = 0; i < 4; i++)
        #pragma unroll
        for (int j = 0; j < 4; j++) acc[i][j] = (f32x4){0.f, 0.f, 0.f, 0.f};

    for (int k0 = 0; k0 < E; k0 += 32) {
        gload16(A + (size_t)(m0 + srow) * E + k0 + skof,         As + t * 8);
        gload16(A + (size_t)(m0 + 64 + srow) * E + k0 + skof,    As + 2048 + t * 8);
        gload16(Wb + (size_t)(n0 + srow) * E + k0 + skof,        Bs + t * 8);
        gload16(Wb + (size_t)(n0 + 64 + srow) * E + k0 + skof,   Bs + 2048 + t * 8);
        __syncthreads();
        short8 af[4], bfr[4];
        #pragma unroll
        for (int i = 0; i < 4; i++)
            af[i] = *(const short8*)&As[(wm + i * 16 + l16) * 32 + quad * 8];
        #pragma unroll
        for (int j = 0; j < 4; j++)
            bfr[j] = *(const short8*)&Bs[(wn + j * 16 + l16) * 32 + quad * 8];
        #pragma unroll
        for (int i = 0; i < 4; i++)
            #pragma unroll
            for (int j = 0; j < 4; j++)
                acc[i][j] = __builtin_amdgcn_mfma_f32_16x16x32_bf16(af[i], bfr[j], acc[i][j], 0, 0, 0);
        __syncthreads();
    }

    #pragma unroll
    for (int i = 0; i < 4; i++) {
        const int mrow0 = m0 + wm + i * 16 + quad * 4;
        #pragma unroll
        for (int j = 0; j < 4; j++) {
            const int ncol = n0 + wn + j * 16 + l16;
            const float bval = bb[ncol];
            if (isq) {
                #pragma unroll
                for (int r = 0; r < 4; r++)
                    qout[(size_t)(mrow0 + r) * 512 + ncol] = f2bf(acc[i][j][r] + bval);
            } else if (ncol < 512) {
                #pragma unroll
                for (int r = 0; r < 4; r++)
                    kout[(size_t)(mrow0 + r) * 512 + ncol] = f2bf(acc[i][j][r] + bval);
            } else {
                const int nv = ncol - 512;
                const int b2 = mrow0 >> 10, s0v = mrow0 & 1023;
                ushort4 o;
                o.x = f2bf(acc[i][j][0] + bval);
                o.y = f2bf(acc[i][j][1] + bval);
                o.z = f2bf(acc[i][j][2] + bval);
                o.w = f2bf(acc[i][j][3] + bval);
                *(ushort4*)(vtout + ((size_t)b2 * 512 + nv) * 1024 + s0v) = o;
            }
        }
    }
}

// ---------------------------------------------------------------------------
// MFMA attention v6: v5 structure (4 heads/block, grid 1024, staged K with
// XOR-swizzled wave-private LDS + vmcnt gating) but V loaded DIRECT from
// global into registers (depth-2 prefetch) — the V LDS roundtrip bought
// nothing (fragments are lane-contiguous 16B in vt) and its 16 KB capped
// residency at 3 blocks/CU. LDS now 33.5 KB -> 4 blocks/CU, 16 waves/CU,
// all 1024 blocks resident. launch_bounds(256,4) pins VGPR <= 128.
// ---------------------------------------------------------------------------
__global__ __launch_bounds__(256, 4) void attn_mfma_kernel(
    const unsigned short* __restrict__ q,   // [B][S][E] bf16
    const unsigned short* __restrict__ k,   // [B][S][E] bf16
    const unsigned short* __restrict__ vt,  // [B][E][S] bf16
    unsigned short* __restrict__ ctx,       // [B][S][E] bf16
    unsigned short* __restrict__ awp) {     // bf16 planes [2][B][S][S]
    __shared__ unsigned short s_mem[16 * 1032]; // P (16x1032) | K-staging union
    __shared__ float s_red[2][4][16];

    const int t = threadIdx.x;
    const int wave = t >> 6, lane = t & 63;
    const int quad = lane >> 4, l16 = lane & 15;
    const int qt   = blockIdx.x & 63;
    const int rest = blockIdx.x >> 6;
    const int hg   = rest & 1;              // head group (4 heads each)
    const int b    = rest >> 1;
    const int q0   = qt * 16;
    const size_t qrow = ((size_t)(b * S + q0 + l16)) * E;

    // wave-private K staging area (shorts)
    unsigned short* karea = s_mem + wave * 4128;   // 2 bufs x 2048 (32 rows x 64)

    // DMA lane mapping: dest = base + lane*8 shorts (HW rule); XOR source swizzle
    const int dr = lane >> 3;               // row within 8-row group
    const int dc = lane & 7;                // dest 16B col-block
    const int csrc = dc ^ dr;               // swizzled source col-block
    const int sw7 = l16 & 7;                // read-side swizzle key

    f32x4 awacc[16];
    #pragma unroll
    for (int i = 0; i < 16; i++) awacc[i] = (f32x4){0.f, 0.f, 0.f, 0.f};

    #pragma clang loop unroll(disable)
    for (int hh = 0; hh < 4; hh++) {
        const int h = hg * 4 + hh;

        // K chunk c (32 rows of wave's k-range) -> buf
        auto stage_k = [&](int c, int buf) {
            const unsigned short* src =
                k + ((size_t)(b * S + wave * 256 + c * 32 + dr)) * E + h * 64 + csrc * 8;
            unsigned short* dst = karea + buf * 2048 + dr * 64 + dc * 8;
            gload16(src,                  dst);
            gload16(src + (size_t)8 * E,  dst + 512);
            gload16(src + (size_t)16 * E, dst + 1024);
            gload16(src + (size_t)24 * E, dst + 1536);
        };

        short8 aq0 = *(const short8*)(q + qrow + h * 64 + quad * 8);
        short8 aq1 = *(const short8*)(q + qrow + h * 64 + 32 + quad * 8);

        // ---- scores: 8 staged K chunks, 2-deep prefetch ----
        f32x4 sacc[16];
        stage_k(0, 0);
        stage_k(1, 1);
        #pragma unroll
        for (int c = 0; c < 8; c++) {
            if (c < 7) waitvm<4>(); else waitvm<0>();
            const unsigned short* kbuf = karea + (c & 1) * 2048;
            #pragma unroll
            for (int ntl = 0; ntl < 2; ntl++) {
                const int rl = ntl * 16 + l16;
                short8 kf0 = *(const short8*)(kbuf + rl * 64 + ((quad)     ^ sw7) * 8);
                short8 kf1 = *(const short8*)(kbuf + rl * 64 + ((4 + quad) ^ sw7) * 8);
                f32x4 cc = (f32x4){0.f, 0.f, 0.f, 0.f};
                cc = __builtin_amdgcn_mfma_f32_16x16x32_bf16(aq0, kf0, cc, 0, 0, 0);
                cc = __builtin_amdgcn_mfma_f32_16x16x32_bf16(aq1, kf1, cc, 0, 0, 0);
                sacc[c * 2 + ntl] = cc * 0.125f;
            }
            if (c < 6) stage_k(c + 2, c & 1);
        }

        // ---- merged single-pass softmax: local max+exp+sum pre-barrier ----
        float lm[4], ls[4];
        #pragma unroll
        for (int r = 0; r < 4; r++) {
            float mv = sacc[0][r];
            #pragma unroll
            for (int nt = 1; nt < 16; nt++) mv = fmaxf(mv, sacc[nt][r]);
            #pragma unroll
            for (int o = 1; o < 16; o <<= 1) mv = fmaxf(mv, __shfl_xor(mv, o));
            lm[r] = mv;
            ls[r] = 0.f;
        }
        #pragma unroll
        for (int nt = 0; nt < 16; nt++)
            #pragma unroll
            for (int r = 0; r < 4; r++) {
                float e = __expf(sacc[nt][r] - lm[r]);
                sacc[nt][r] = e;
                ls[r] += e;
            }
        #pragma unroll
        for (int r = 0; r < 4; r++) {
            #pragma unroll
            for (int o = 1; o < 16; o <<= 1) ls[r] += __shfl_xor(ls[r], o);
        }
        if (l16 == 0) {
            #pragma unroll
            for (int r = 0; r < 4; r++) {
                s_red[0][wave][quad * 4 + r] = lm[r];
                s_red[1][wave][quad * 4 + r] = ls[r];
            }
        }
        __syncthreads();                                   // (B1) also: all K reads done
        float scale[4];
        #pragma unroll
        for (int r = 0; r < 4; r++) {
            const int row = quad * 4 + r;
            float m0 = s_red[0][0][row], m1 = s_red[0][1][row];
            float m2 = s_red[0][2][row], m3 = s_red[0][3][row];
            float gmax = fmaxf(fmaxf(m0, m1), fmaxf(m2, m3));
            float gsum = s_red[1][0][row] * __expf(m0 - gmax)
                       + s_red[1][1][row] * __expf(m1 - gmax)
                       + s_red[1][2][row] * __expf(m2 - gmax)
                       + s_red[1][3][row] * __expf(m3 - gmax);
            scale[r] = __expf(lm[r] - gmax) / gsum;
        }

        // ---- normalize, accumulate aw, write P (bf16) into s_mem [16][1032] ----
        #pragma unroll
        for (int nt = 0; nt < 16; nt++) {
            #pragma unroll
            for (int r = 0; r < 4; r++) {
                float p = sacc[nt][r] * scale[r];
                awacc[nt][r] += p;
                s_mem[(quad * 4 + r) * 1032 + wave * 256 + nt * 16 + l16] = f2bf(p);
            }
        }
        __syncthreads();                                   // (B2) P visible

        // ---- PV: direct global V fragment loads (lane-contiguous 16B in vt),
        // depth-2 register prefetch; P from s_mem ----
        const unsigned short* vbase =
            vt + ((size_t)(b * E + h * 64 + wave * 16 + l16)) * S + quad * 8;
        f32x4 cacc0 = (f32x4){0.f, 0.f, 0.f, 0.f};
        f32x4 cacc1 = (f32x4){0.f, 0.f, 0.f, 0.f};
        short8 va[2], vb[2];
        #pragma unroll
        for (int cv = 0; cv < 2; cv++) {
            va[cv] = *(const short8*)(vbase + cv * 64);
            vb[cv] = *(const short8*)(vbase + cv * 64 + 32);
        }
        #pragma unroll
        for (int cv = 0; cv < 16; cv++) {
            short8 pf0 = *(const short8*)(s_mem + l16 * 1032 + cv * 64 + quad * 8);
            short8 pf1 = *(const short8*)(s_mem + l16 * 1032 + cv * 64 + 32 + quad * 8);
            cacc0 = __builtin_amdgcn_mfma_f32_16x16x32_bf16(pf0, va[cv & 1], cacc0, 0, 0, 0);
            cacc1 = __builtin_amdgcn_mfma_f32_16x16x32_bf16(pf1, vb[cv & 1], cacc1, 0, 0, 0);
            if (cv < 14) {
                va[cv & 1] = *(const short8*)(vbase + (cv + 2) * 64);
                vb[cv & 1] = *(const short8*)(vbase + (cv + 2) * 64 + 32);
            }
        }
        f32x4 cacc = cacc0 + cacc1;
        unsigned short* crow = ctx + ((size_t)(b * S + q0)) * E + h * 64 + wave * 16 + l16;
        #pragma unroll
        for (int r = 0; r < 4; r++)
            crow[(size_t)(quad * 4 + r) * E] = f2bf(cacc[r]);
        __syncthreads();                                   // (B3) P reads done -> K restage safe
    }

    // ---- head-group partial plane (bf16) ----
    #pragma unroll
    for (int nt = 0; nt < 16; nt++) {
        #pragma unroll
        for (int r = 0; r < 4; r++)
            awp[((size_t)((hg * B + b) * S + q0 + quad * 4 + r)) * S +
                wave * 256 + nt * 16 + l16] = f2bf(awacc[nt][r]);
    }
}

// ---------------------------------------------------------------------------
// aw reduce: aw = (1/H) * sum of NP bf16 planes. 8 f32 outputs per thread.
// ---------------------------------------------------------------------------
template <int NP>
__global__ __launch_bounds__(256) void aw_reduce_kernel(
    const unsigned short* __restrict__ awp, float* __restrict__ aw) {
    const size_t PLN = (size_t)B * S * S;
    size_t idx = ((size_t)blockIdx.x * 256 + threadIdx.x) * 8;
    float acc[8] = {};
    #pragma unroll
    for (int p = 0; p < NP; p++) {
        short8 v = *(const short8*)(awp + p * PLN + idx);
        #pragma unroll
        for (int j = 0; j < 8; j++) acc[j] += bf2f((unsigned short)v[j]);
    }
    float4 o0 = make_float4(acc[0] * (1.0f / H), acc[1] * (1.0f / H),
                            acc[2] * (1.0f / H), acc[3] * (1.0f / H));
    float4 o1 = make_float4(acc[4] * (1.0f / H), acc[5] * (1.0f / H),
                            acc[6] * (1.0f / H), acc[7] * (1.0f / H));
    *(float4*)(aw + idx) = o0;
    *(float4*)(aw + idx + 4) = o1;
}

// ---------------------------------------------------------------------------
extern "C" void kernel_launch(void* const* d_in, const int* in_sizes, int n_in,
                              void* d_out, int out_size, void* d_ws, size_t ws_size,
                              hipStream_t stream) {
    const float* Zab  = (const float*)d_in[0];
    const float* Za   = (const float*)d_in[1];
    const float* lnw  = (const float*)d_in[2];
    const float* lnb  = (const float*)d_in[3];
    const float* Wqkv = (const float*)d_in[4];
    const float* bqkv = (const float*)d_in[5];
    const float* Wo   = (const float*)d_in[6];
    const float* bo   = (const float*)d_in[7];
    const float* Wf   = (const float*)d_in[8];
    const float* bf   = (const float*)d_in[9];

    float* out_final = (float*)d_out;
    float* out_aw    = out_final + (size_t)B * S * E;

    char* ws = (char*)d_ws;
    // Static buffers (live through attention):
    unsigned short* qb   = (unsigned short*)(ws);               // [0,8M)
    unsigned short* kb   = (unsigned short*)(ws + (8u << 20));  // [8,16M)
    unsigned short* vtb  = (unsigned short*)(ws + (16u << 20)); // [16,24M)
    unsigned short* ctxb = (unsigned short*)(ws + (24u << 20)); // [24,32M)
    // Pre-attention staging (dead once attention starts):
    unsigned short* aqb  = (unsigned short*)(ws + (32u << 20)); // [32,40M)
    unsigned short* akvb = (unsigned short*)(ws + (40u << 20)); // [40,48M)
    // awp planes: 2 x 16 MB at [32,64M) (aqb/akvb dead by attention)
    unsigned short* awp  = (unsigned short*)(ws + (32ull << 20));
    unsigned short* wbf  = (unsigned short*)(ws + (96ull << 20)); // 2.5 MB
    // Post-attention f32 buffers:
    float* xb  = (float*)(ws);                                  // [0,16M)
    float* tb  = (float*)(ws + (16u << 20));                    // [16,32M)
    unsigned short* xnb = aqb;                                  // [32,40M) after reduce

    dim3 blk(256);

    // 1. weights -> bf16 (packed: qkv | o | f)
    w2bf_kernel<<<(5 * E * E) / 1024, blk, 0, stream>>>(Wqkv, Wo, Wf, wbf);

    // 2. LN(Zab), LN(Za) -> bf16
    ln_bf16_kernel<<<M / 4, blk, 0, stream>>>(Zab, lnw, lnb, aqb);
    ln_bf16_kernel<<<M / 4, blk, 0, stream>>>(Za,  lnw, lnb, akvb);

    // 3. fused q/kv projection: one launch, 768 blocks = 3 blocks/CU
    gemm_qkv<<<dim3(M / 128, 12), blk, 0, stream>>>(aqb, akvb, wbf, bqkv, qb, kb, vtb);

    // 4. attention (staged K, direct V, 4 heads/block) -> ctx + 2 planes; reduce
    attn_mfma_kernel<<<B * 2 * 64, blk, 0, stream>>>(qb, kb, vtb, ctxb, awp);
    aw_reduce_kernel<2><<<4096, blk, 0, stream>>>(awp, out_aw);

    // 5. x = ctx@Wo^T + bo + Zab (f32)
    gemm_mfma<1><<<dim3(M / 128, 4), blk, 0, stream>>>(ctxb, wbf + (size_t)3*E*E, bo, Zab, nullptr, xb, 512);

    // 6. xn = LN(x) -> bf16
    ln_bf16_kernel<<<M / 4, blk, 0, stream>>>(xb, lnw, lnb, xnb);

    // 7. t = xn@Wf^T + bf + xn (f32)
    gemm_mfma<2><<<dim3(M / 128, 4), blk, 0, stream>>>(xnb, wbf + (size_t)4*E*E, bf, nullptr, xnb, tb, 512);

    // 8. final = LN(t)
    ln_full_kernel<<<M / 4, blk, 0, stream>>>(tb, lnw, lnb, out_final);
}

// Round 9
// 286.090 us; speedup vs baseline: 1.2080x; 1.2080x over previous
//
#include <hip/hip_runtime.h>
#include <math.h>

#define EPS 1e-5f

constexpr int B = 8, S = 1024, E = 512, H = 8;
constexpr int M = B * S;          // 8192 rows

typedef __attribute__((ext_vector_type(8))) short short8;  // 8 bf16 (4 VGPRs)
typedef __attribute__((ext_vector_type(4))) float f32x4;

// fp32 -> bf16 bits, round-to-nearest-even
static __device__ __forceinline__ unsigned short f2bf(float f) {
    unsigned int x = __float_as_uint(f);
    x += 0x7FFFu + ((x >> 16) & 1u);
    return (unsigned short)(x >> 16);
}
static __device__ __forceinline__ float bf2f(unsigned short u) {
    return __uint_as_float(((unsigned int)u) << 16);
}

// async global->LDS, 16B per lane (global_load_lds_dwordx4)
typedef __attribute__((address_space(3))) unsigned int  lds_uint;
typedef __attribute__((address_space(1))) unsigned int  glb_uint;
static __device__ __forceinline__ void gload16(const unsigned short* g, unsigned short* l) {
    __builtin_amdgcn_global_load_lds((const glb_uint*)g, (lds_uint*)l, 16, 0, 0);
}
// s_waitcnt vmcnt(N) only (lgkm=15, exp=7 untouched). m135: in-order drain.
template <int N>
static __device__ __forceinline__ void waitvm() {
    __builtin_amdgcn_s_waitcnt(0x0F70 | N);
}

// ---------------------------------------------------------------------------
// LN -> bf16: one wave per row (E=512, 8 elems/lane), stats via 64-lane shuffles.
// ---------------------------------------------------------------------------
__global__ __launch_bounds__(256) void ln_bf16_kernel(
    const float* __restrict__ x, const float* __restrict__ w,
    const float* __restrict__ bb, unsigned short* __restrict__ out) {
    int row = blockIdx.x * 4 + (threadIdx.x >> 6);
    int lane = threadIdx.x & 63;
    const float* xr = x + (size_t)row * E + lane * 8;
    float4 v0 = *(const float4*)xr;
    float4 v1 = *(const float4*)(xr + 4);
    float vv[8] = {v0.x, v0.y, v0.z, v0.w, v1.x, v1.y, v1.z, v1.w};
    float s = 0.f;
    #pragma unroll
    for (int i = 0; i < 8; i++) s += vv[i];
    #pragma unroll
    for (int o = 1; o < 64; o <<= 1) s += __shfl_xor(s, o);
    float mu = s * (1.0f / E);
    float qs = 0.f;
    #pragma unroll
    for (int i = 0; i < 8; i++) { float d = vv[i] - mu; qs += d * d; }
    #pragma unroll
    for (int o = 1; o < 64; o <<= 1) qs += __shfl_xor(qs, o);
    float rs = rsqrtf(qs * (1.0f / E) + EPS);
    float4 w0 = *(const float4*)(w + lane * 8), w1 = *(const float4*)(w + lane * 8 + 4);
    float4 b0 = *(const float4*)(bb + lane * 8), b1 = *(const float4*)(bb + lane * 8 + 4);
    float ww[8] = {w0.x, w0.y, w0.z, w0.w, w1.x, w1.y, w1.z, w1.w};
    float bv[8] = {b0.x, b0.y, b0.z, b0.w, b1.x, b1.y, b1.z, b1.w};
    short8 o8;
    #pragma unroll
    for (int i = 0; i < 8; i++) o8[i] = (short)f2bf((vv[i] - mu) * rs * ww[i] + bv[i]);
    *(short8*)(out + (size_t)row * E + lane * 8) = o8;
}

// ---------------------------------------------------------------------------
// Full LN (fp32 out) for the final output — wave-per-row.
// ---------------------------------------------------------------------------
__global__ __launch_bounds__(256) void ln_full_kernel(
    const float* __restrict__ x, const float* __restrict__ w,
    const float* __restrict__ bb, float* __restrict__ out) {
    int row = blockIdx.x * 4 + (threadIdx.x >> 6);
    int lane = threadIdx.x & 63;
    const float* xr = x + (size_t)row * E + lane * 8;
    float4 v0 = *(const float4*)xr;
    float4 v1 = *(const float4*)(xr + 4);
    float vv[8] = {v0.x, v0.y, v0.z, v0.w, v1.x, v1.y, v1.z, v1.w};
    float s = 0.f;
    #pragma unroll
    for (int i = 0; i < 8; i++) s += vv[i];
    #pragma unroll
    for (int o = 1; o < 64; o <<= 1) s += __shfl_xor(s, o);
    float mu = s * (1.0f / E);
    float qs = 0.f;
    #pragma unroll
    for (int i = 0; i < 8; i++) { float d = vv[i] - mu; qs += d * d; }
    #pragma unroll
    for (int o = 1; o < 64; o <<= 1) qs += __shfl_xor(qs, o);
    float rs = rsqrtf(qs * (1.0f / E) + EPS);
    float4 w0 = *(const float4*)(w + lane * 8), w1 = *(const float4*)(w + lane * 8 + 4);
    float4 b0 = *(const float4*)(bb + lane * 8), b1 = *(const float4*)(bb + lane * 8 + 4);
    float* op = out + (size_t)row * E + lane * 8;
    float4 o0, o1;
    o0.x = (vv[0] - mu) * rs * w0.x + b0.x;
    o0.y = (vv[1] - mu) * rs * w0.y + b0.y;
    o0.z = (vv[2] - mu) * rs * w0.z + b0.z;
    o0.w = (vv[3] - mu) * rs * w0.w + b0.w;
    o1.x = (vv[4] - mu) * rs * w1.x + b1.x;
    o1.y = (vv[5] - mu) * rs * w1.y + b1.y;
    o1.z = (vv[6] - mu) * rs * w1.z + b1.z;
    o1.w = (vv[7] - mu) * rs * w1.w + b1.w;
    *(float4*)op = o0;
    *(float4*)(op + 4) = o1;
}

// ---------------------------------------------------------------------------
// Weight conversion f32 -> bf16 into one packed buffer: [qkv | o | f]
// ---------------------------------------------------------------------------
__global__ __launch_bounds__(256) void w2bf_kernel(
    const float* __restrict__ wqkv, const float* __restrict__ wo,
    const float* __restrict__ wf, unsigned short* __restrict__ out) {
    int base = (blockIdx.x * 256 + threadIdx.x) * 4;
    float4 v;
    if (base < 3 * E * E)           v = *(const float4*)(wqkv + base);
    else if (base < 4 * E * E)      v = *(const float4*)(wo + (base - 3 * E * E));
    else                            v = *(const float4*)(wf + (base - 4 * E * E));
    ushort4 o;
    o.x = f2bf(v.x); o.y = f2bf(v.y); o.z = f2bf(v.z); o.w = f2bf(v.w);
    *(ushort4*)(out + base) = o;
}

// ---------------------------------------------------------------------------
// bf16 MFMA GEMM (m97 structure): C[M,Ntot] = A[M,512] @ W[Ntot,512]^T + bias
//   OUT_MODE 1: f32 +residf; 2: f32 +bf16 resid   (o-proj / ff)
// ---------------------------------------------------------------------------
template <int OUT_MODE>
__global__ __launch_bounds__(256) void gemm_mfma(
    const unsigned short* __restrict__ A, const unsigned short* __restrict__ W,
    const float* __restrict__ bias,
    const float* __restrict__ residf, const unsigned short* __restrict__ residb,
    void* __restrict__ C0, int Ntot) {
    __shared__ unsigned short As[128 * 32];
    __shared__ unsigned short Bs[128 * 32];
    const int t = threadIdx.x;
    const int wave = t >> 6, lane = t & 63;
    const int quad = lane >> 4, l16 = lane & 15;
    const int m0 = blockIdx.x * 128, n0 = blockIdx.y * 128;
    const int wm = (wave >> 1) * 64, wn = (wave & 1) * 64;

    const int srow = t >> 2;
    const int skof = (t & 3) * 8;

    f32x4 acc[4][4];
    #pragma unroll
    for (int i = 0; i < 4; i++)
        #pragma unroll
        for (int j = 0; j < 4; j++) acc[i][j] = (f32x4){0.f, 0.f, 0.f, 0.f};

    for (int k0 = 0; k0 < E; k0 += 32) {
        gload16(A + (size_t)(m0 + srow) * E + k0 + skof,        As + t * 8);
        gload16(A + (size_t)(m0 + 64 + srow) * E + k0 + skof,   As + 2048 + t * 8);
        gload16(W + (size_t)(n0 + srow) * E + k0 + skof,        Bs + t * 8);
        gload16(W + (size_t)(n0 + 64 + srow) * E + k0 + skof,   Bs + 2048 + t * 8);
        __syncthreads();
        short8 af[4], bfr[4];
        #pragma unroll
        for (int i = 0; i < 4; i++)
            af[i] = *(const short8*)&As[(wm + i * 16 + l16) * 32 + quad * 8];
        #pragma unroll
        for (int j = 0; j < 4; j++)
            bfr[j] = *(const short8*)&Bs[(wn + j * 16 + l16) * 32 + quad * 8];
        #pragma unroll
        for (int i = 0; i < 4; i++)
            #pragma unroll
            for (int j = 0; j < 4; j++)
                acc[i][j] = __builtin_amdgcn_mfma_f32_16x16x32_bf16(af[i], bfr[j], acc[i][j], 0, 0, 0);
        __syncthreads();
    }

    #pragma unroll
    for (int i = 0; i < 4; i++) {
        const int mrow0 = m0 + wm + i * 16 + quad * 4;
        #pragma unroll
        for (int j = 0; j < 4; j++) {
            const int ncol = n0 + wn + j * 16 + l16;
            const float bval = bias[ncol];
            if (OUT_MODE == 1) {
                #pragma unroll
                for (int r = 0; r < 4; r++) {
                    size_t idx = (size_t)(mrow0 + r) * Ntot + ncol;
                    ((float*)C0)[idx] = acc[i][j][r] + bval + residf[idx];
                }
            } else {
                #pragma unroll
                for (int r = 0; r < 4; r++) {
                    size_t idx = (size_t)(mrow0 + r) * Ntot + ncol;
                    ((float*)C0)[idx] = acc[i][j][r] + bval + bf2f(residb[idx]);
                }
            }
        }
    }
}

// ---------------------------------------------------------------------------
// Fused q + kv projection GEMM. Grid (M/128, 12): y<4 -> q panel (A=Aq,
// out=qout bf16 [M,512]); y>=4 -> kv panel (A=Akv, out k bf16 / v^T bf16).
// One launch, 768 blocks = 3 blocks/CU (vs 1/CU + 2/CU sequential).
// ---------------------------------------------------------------------------
__global__ __launch_bounds__(256) void gemm_qkv(
    const unsigned short* __restrict__ Aq, const unsigned short* __restrict__ Akv,
    const unsigned short* __restrict__ W,   // packed [3E][E] bf16
    const float* __restrict__ bias,         // [3E]
    unsigned short* __restrict__ qout,      // [M][512] bf16
    unsigned short* __restrict__ kout,      // [M][512] bf16
    unsigned short* __restrict__ vtout) {   // [B][512][1024] bf16
    __shared__ unsigned short As[128 * 32];
    __shared__ unsigned short Bs[128 * 32];
    const int t = threadIdx.x;
    const int wave = t >> 6, lane = t & 63;
    const int quad = lane >> 4, l16 = lane & 15;
    const bool isq = blockIdx.y < 4;
    const int yy = isq ? blockIdx.y : blockIdx.y - 4;
    const unsigned short* A  = isq ? Aq : Akv;
    const unsigned short* Wb = W + (isq ? 0 : (size_t)E * E);
    const float* bb = bias + (isq ? 0 : E);
    const int m0 = blockIdx.x * 128, n0 = yy * 128;
    const int wm = (wave >> 1) * 64, wn = (wave & 1) * 64;

    const int srow = t >> 2;
    const int skof = (t & 3) * 8;

    f32x4 acc[4][4];
    #pragma unroll
    for (int i = 0; i < 4; i++)
        #pragma unroll
        for (int j = 0; j < 4; j++) acc[i][j] = (f32x4){0.f, 0.f, 0.f, 0.f};

    for (int k0 = 0; k0 < E; k0 += 32) {
        gload16(A + (size_t)(m0 + srow) * E + k0 + skof,         As + t * 8);
        gload16(A + (size_t)(m0 + 64 + srow) * E + k0 + skof,    As + 2048 + t * 8);
        gload16(Wb + (size_t)(n0 + srow) * E + k0 + skof,        Bs + t * 8);
        gload16(Wb + (size_t)(n0 + 64 + srow) * E + k0 + skof,   Bs + 2048 + t * 8);
        __syncthreads();
        short8 af[4], bfr[4];
        #pragma unroll
        for (int i = 0; i < 4; i++)
            af[i] = *(const short8*)&As[(wm + i * 16 + l16) * 32 + quad * 8];
        #pragma unroll
        for (int j = 0; j < 4; j++)
            bfr[j] = *(const short8*)&Bs[(wn + j * 16 + l16) * 32 + quad * 8];
        #pragma unroll
        for (int i = 0; i < 4; i++)
            #pragma unroll
            for (int j = 0; j < 4; j++)
                acc[i][j] = __builtin_amdgcn_mfma_f32_16x16x32_bf16(af[i], bfr[j], acc[i][j], 0, 0, 0);
        __syncthreads();
    }

    #pragma unroll
    for (int i = 0; i < 4; i++) {
        const int mrow0 = m0 + wm + i * 16 + quad * 4;
        #pragma unroll
        for (int j = 0; j < 4; j++) {
            const int ncol = n0 + wn + j * 16 + l16;
            const float bval = bb[ncol];
            if (isq) {
                #pragma unroll
                for (int r = 0; r < 4; r++)
                    qout[(size_t)(mrow0 + r) * 512 + ncol] = f2bf(acc[i][j][r] + bval);
            } else if (ncol < 512) {
                #pragma unroll
                for (int r = 0; r < 4; r++)
                    kout[(size_t)(mrow0 + r) * 512 + ncol] = f2bf(acc[i][j][r] + bval);
            } else {
                const int nv = ncol - 512;
                const int b2 = mrow0 >> 10, s0v = mrow0 & 1023;
                ushort4 o;
                o.x = f2bf(acc[i][j][0] + bval);
                o.y = f2bf(acc[i][j][1] + bval);
                o.z = f2bf(acc[i][j][2] + bval);
                o.w = f2bf(acc[i][j][3] + bval);
                *(ushort4*)(vtout + ((size_t)b2 * 512 + nv) * 1024 + s0v) = o;
            }
        }
    }
}

// ---------------------------------------------------------------------------
// MFMA attention v6b: v6 structure (staged K, direct-V registers, 33.8 KB LDS)
// with __launch_bounds__(256, 2). Round-8 lesson: on this compiler the 2nd
// arg caps VGPRs at ~256/arg — (256,4) forced a 64-VGPR budget onto ~120 live
// regs -> 40+ spills -> 550 MB scratch traffic. (256,2) caps at 128; the
// ~120 live regs fit, and HW occupancy is then 4 waves/SIMD (VGPR<=128, m69)
// x LDS 33.8KBx4=135KB -> 4 blocks/CU with all 1024 blocks resident.
// ---------------------------------------------------------------------------
__global__ __launch_bounds__(256, 2) void attn_mfma_kernel(
    const unsigned short* __restrict__ q,   // [B][S][E] bf16
    const unsigned short* __restrict__ k,   // [B][S][E] bf16
    const unsigned short* __restrict__ vt,  // [B][E][S] bf16
    unsigned short* __restrict__ ctx,       // [B][S][E] bf16
    unsigned short* __restrict__ awp) {     // bf16 planes [2][B][S][S]
    __shared__ unsigned short s_mem[16 * 1032]; // P (16x1032) | K-staging union
    __shared__ float s_red[2][4][16];

    const int t = threadIdx.x;
    const int wave = t >> 6, lane = t & 63;
    const int quad = lane >> 4, l16 = lane & 15;
    const int qt   = blockIdx.x & 63;
    const int rest = blockIdx.x >> 6;
    const int hg   = rest & 1;              // head group (4 heads each)
    const int b    = rest >> 1;
    const int q0   = qt * 16;
    const size_t qrow = ((size_t)(b * S + q0 + l16)) * E;

    // wave-private K staging area (shorts)
    unsigned short* karea = s_mem + wave * 4128;   // 2 bufs x 2048 (32 rows x 64)

    // DMA lane mapping: dest = base + lane*8 shorts (HW rule); XOR source swizzle
    const int dr = lane >> 3;               // row within 8-row group
    const int dc = lane & 7;                // dest 16B col-block
    const int csrc = dc ^ dr;               // swizzled source col-block
    const int sw7 = l16 & 7;                // read-side swizzle key

    f32x4 awacc[16];
    #pragma unroll
    for (int i = 0; i < 16; i++) awacc[i] = (f32x4){0.f, 0.f, 0.f, 0.f};

    #pragma clang loop unroll(disable)
    for (int hh = 0; hh < 4; hh++) {
        const int h = hg * 4 + hh;

        // K chunk c (32 rows of wave's k-range) -> buf
        auto stage_k = [&](int c, int buf) {
            const unsigned short* src =
                k + ((size_t)(b * S + wave * 256 + c * 32 + dr)) * E + h * 64 + csrc * 8;
            unsigned short* dst = karea + buf * 2048 + dr * 64 + dc * 8;
            gload16(src,                  dst);
            gload16(src + (size_t)8 * E,  dst + 512);
            gload16(src + (size_t)16 * E, dst + 1024);
            gload16(src + (size_t)24 * E, dst + 1536);
        };

        short8 aq0 = *(const short8*)(q + qrow + h * 64 + quad * 8);
        short8 aq1 = *(const short8*)(q + qrow + h * 64 + 32 + quad * 8);

        // ---- scores: 8 staged K chunks, 2-deep prefetch ----
        f32x4 sacc[16];
        stage_k(0, 0);
        stage_k(1, 1);
        #pragma unroll
        for (int c = 0; c < 8; c++) {
            if (c < 7) waitvm<4>(); else waitvm<0>();
            const unsigned short* kbuf = karea + (c & 1) * 2048;
            #pragma unroll
            for (int ntl = 0; ntl < 2; ntl++) {
                const int rl = ntl * 16 + l16;
                short8 kf0 = *(const short8*)(kbuf + rl * 64 + ((quad)     ^ sw7) * 8);
                short8 kf1 = *(const short8*)(kbuf + rl * 64 + ((4 + quad) ^ sw7) * 8);
                f32x4 cc = (f32x4){0.f, 0.f, 0.f, 0.f};
                cc = __builtin_amdgcn_mfma_f32_16x16x32_bf16(aq0, kf0, cc, 0, 0, 0);
                cc = __builtin_amdgcn_mfma_f32_16x16x32_bf16(aq1, kf1, cc, 0, 0, 0);
                sacc[c * 2 + ntl] = cc * 0.125f;
            }
            if (c < 6) stage_k(c + 2, c & 1);
        }

        // ---- merged single-pass softmax: local max+exp+sum pre-barrier ----
        float lm[4], ls[4];
        #pragma unroll
        for (int r = 0; r < 4; r++) {
            float mv = sacc[0][r];
            #pragma unroll
            for (int nt = 1; nt < 16; nt++) mv = fmaxf(mv, sacc[nt][r]);
            #pragma unroll
            for (int o = 1; o < 16; o <<= 1) mv = fmaxf(mv, __shfl_xor(mv, o));
            lm[r] = mv;
            ls[r] = 0.f;
        }
        #pragma unroll
        for (int nt = 0; nt < 16; nt++)
            #pragma unroll
            for (int r = 0; r < 4; r++) {
                float e = __expf(sacc[nt][r] - lm[r]);
                sacc[nt][r] = e;
                ls[r] += e;
            }
        #pragma unroll
        for (int r = 0; r < 4; r++) {
            #pragma unroll
            for (int o = 1; o < 16; o <<= 1) ls[r] += __shfl_xor(ls[r], o);
        }
        if (l16 == 0) {
            #pragma unroll
            for (int r = 0; r < 4; r++) {
                s_red[0][wave][quad * 4 + r] = lm[r];
                s_red[1][wave][quad * 4 + r] = ls[r];
            }
        }
        __syncthreads();                                   // (B1) also: all K reads done
        float scale[4];
        #pragma unroll
        for (int r = 0; r < 4; r++) {
            const int row = quad * 4 + r;
            float m0 = s_red[0][0][row], m1 = s_red[0][1][row];
            float m2 = s_red[0][2][row], m3 = s_red[0][3][row];
            float gmax = fmaxf(fmaxf(m0, m1), fmaxf(m2, m3));
            float gsum = s_red[1][0][row] * __expf(m0 - gmax)
                       + s_red[1][1][row] * __expf(m1 - gmax)
                       + s_red[1][2][row] * __expf(m2 - gmax)
                       + s_red[1][3][row] * __expf(m3 - gmax);
            scale[r] = __expf(lm[r] - gmax) / gsum;
        }

        // ---- normalize, accumulate aw, write P (bf16) into s_mem [16][1032] ----
        #pragma unroll
        for (int nt = 0; nt < 16; nt++) {
            #pragma unroll
            for (int r = 0; r < 4; r++) {
                float p = sacc[nt][r] * scale[r];
                awacc[nt][r] += p;
                s_mem[(quad * 4 + r) * 1032 + wave * 256 + nt * 16 + l16] = f2bf(p);
            }
        }
        __syncthreads();                                   // (B2) P visible

        // ---- PV: direct global V fragment loads (lane-contiguous 16B in vt),
        // depth-2 register prefetch; P from s_mem ----
        const unsigned short* vbase =
            vt + ((size_t)(b * E + h * 64 + wave * 16 + l16)) * S + quad * 8;
        f32x4 cacc0 = (f32x4){0.f, 0.f, 0.f, 0.f};
        f32x4 cacc1 = (f32x4){0.f, 0.f, 0.f, 0.f};
        short8 va[2], vb[2];
        #pragma unroll
        for (int cv = 0; cv < 2; cv++) {
            va[cv] = *(const short8*)(vbase + cv * 64);
            vb[cv] = *(const short8*)(vbase + cv * 64 + 32);
        }
        #pragma unroll
        for (int cv = 0; cv < 16; cv++) {
            short8 pf0 = *(const short8*)(s_mem + l16 * 1032 + cv * 64 + quad * 8);
            short8 pf1 = *(const short8*)(s_mem + l16 * 1032 + cv * 64 + 32 + quad * 8);
            cacc0 = __builtin_amdgcn_mfma_f32_16x16x32_bf16(pf0, va[cv & 1], cacc0, 0, 0, 0);
            cacc1 = __builtin_amdgcn_mfma_f32_16x16x32_bf16(pf1, vb[cv & 1], cacc1, 0, 0, 0);
            if (cv < 14) {
                va[cv & 1] = *(const short8*)(vbase + (cv + 2) * 64);
                vb[cv & 1] = *(const short8*)(vbase + (cv + 2) * 64 + 32);
            }
        }
        f32x4 cacc = cacc0 + cacc1;
        unsigned short* crow = ctx + ((size_t)(b * S + q0)) * E + h * 64 + wave * 16 + l16;
        #pragma unroll
        for (int r = 0; r < 4; r++)
            crow[(size_t)(quad * 4 + r) * E] = f2bf(cacc[r]);
        __syncthreads();                                   // (B3) P reads done -> K restage safe
    }

    // ---- head-group partial plane (bf16) ----
    #pragma unroll
    for (int nt = 0; nt < 16; nt++) {
        #pragma unroll
        for (int r = 0; r < 4; r++)
            awp[((size_t)((hg * B + b) * S + q0 + quad * 4 + r)) * S +
                wave * 256 + nt * 16 + l16] = f2bf(awacc[nt][r]);
    }
}

// ---------------------------------------------------------------------------
// aw reduce: aw = (1/H) * sum of NP bf16 planes. 8 f32 outputs per thread.
// ---------------------------------------------------------------------------
template <int NP>
__global__ __launch_bounds__(256) void aw_reduce_kernel(
    const unsigned short* __restrict__ awp, float* __restrict__ aw) {
    const size_t PLN = (size_t)B * S * S;
    size_t idx = ((size_t)blockIdx.x * 256 + threadIdx.x) * 8;
    float acc[8] = {};
    #pragma unroll
    for (int p = 0; p < NP; p++) {
        short8 v = *(const short8*)(awp + p * PLN + idx);
        #pragma unroll
        for (int j = 0; j < 8; j++) acc[j] += bf2f((unsigned short)v[j]);
    }
    float4 o0 = make_float4(acc[0] * (1.0f / H), acc[1] * (1.0f / H),
                            acc[2] * (1.0f / H), acc[3] * (1.0f / H));
    float4 o1 = make_float4(acc[4] * (1.0f / H), acc[5] * (1.0f / H),
                            acc[6] * (1.0f / H), acc[7] * (1.0f / H));
    *(float4*)(aw + idx) = o0;
    *(float4*)(aw + idx + 4) = o1;
}

// ---------------------------------------------------------------------------
extern "C" void kernel_launch(void* const* d_in, const int* in_sizes, int n_in,
                              void* d_out, int out_size, void* d_ws, size_t ws_size,
                              hipStream_t stream) {
    const float* Zab  = (const float*)d_in[0];
    const float* Za   = (const float*)d_in[1];
    const float* lnw  = (const float*)d_in[2];
    const float* lnb  = (const float*)d_in[3];
    const float* Wqkv = (const float*)d_in[4];
    const float* bqkv = (const float*)d_in[5];
    const float* Wo   = (const float*)d_in[6];
    const float* bo   = (const float*)d_in[7];
    const float* Wf   = (const float*)d_in[8];
    const float* bf   = (const float*)d_in[9];

    float* out_final = (float*)d_out;
    float* out_aw    = out_final + (size_t)B * S * E;

    char* ws = (char*)d_ws;
    // Static buffers (live through attention):
    unsigned short* qb   = (unsigned short*)(ws);               // [0,8M)
    unsigned short* kb   = (unsigned short*)(ws + (8u << 20));  // [8,16M)
    unsigned short* vtb  = (unsigned short*)(ws + (16u << 20)); // [16,24M)
    unsigned short* ctxb = (unsigned short*)(ws + (24u << 20)); // [24,32M)
    // Pre-attention staging (dead once attention starts):
    unsigned short* aqb  = (unsigned short*)(ws + (32u << 20)); // [32,40M)
    unsigned short* akvb = (unsigned short*)(ws + (40u << 20)); // [40,48M)
    // awp planes: 2 x 16 MB at [32,64M) (aqb/akvb dead by attention)
    unsigned short* awp  = (unsigned short*)(ws + (32ull << 20));
    unsigned short* wbf  = (unsigned short*)(ws + (96ull << 20)); // 2.5 MB
    // Post-attention f32 buffers:
    float* xb  = (float*)(ws);                                  // [0,16M)
    float* tb  = (float*)(ws + (16u << 20));                    // [16,32M)
    unsigned short* xnb = aqb;                                  // [32,40M) after reduce

    dim3 blk(256);

    // 1. weights -> bf16 (packed: qkv | o | f)
    w2bf_kernel<<<(5 * E * E) / 1024, blk, 0, stream>>>(Wqkv, Wo, Wf, wbf);

    // 2. LN(Zab), LN(Za) -> bf16
    ln_bf16_kernel<<<M / 4, blk, 0, stream>>>(Zab, lnw, lnb, aqb);
    ln_bf16_kernel<<<M / 4, blk, 0, stream>>>(Za,  lnw, lnb, akvb);

    // 3. fused q/kv projection: one launch, 768 blocks = 3 blocks/CU
    gemm_qkv<<<dim3(M / 128, 12), blk, 0, stream>>>(aqb, akvb, wbf, bqkv, qb, kb, vtb);

    // 4. attention (staged K, direct V, 4 heads/block) -> ctx + 2 planes; reduce
    attn_mfma_kernel<<<B * 2 * 64, blk, 0, stream>>>(qb, kb, vtb, ctxb, awp);
    aw_reduce_kernel<2><<<4096, blk, 0, stream>>>(awp, out_aw);

    // 5. x = ctx@Wo^T + bo + Zab (f32)
    gemm_mfma<1><<<dim3(M / 128, 4), blk, 0, stream>>>(ctxb, wbf + (size_t)3*E*E, bo, Zab, nullptr, xb, 512);

    // 6. xn = LN(x) -> bf16
    ln_bf16_kernel<<<M / 4, blk, 0, stream>>>(xb, lnw, lnb, xnb);

    // 7. t = xn@Wf^T + bf + xn (f32)
    gemm_mfma<2><<<dim3(M / 128, 4), blk, 0, stream>>>(xnb, wbf + (size_t)4*E*E, bf, nullptr, xnb, tb, 512);

    // 8. final = LN(t)
    ln_full_kernel<<<M / 4, blk, 0, stream>>>(tb, lnw, lnb, out_final);
}

// Round 10
// 266.523 us; speedup vs baseline: 1.2967x; 1.0734x over previous
//
#include <hip/hip_runtime.h>
#include <math.h>

#define EPS 1e-5f

constexpr int B = 8, S = 1024, E = 512, H = 8;
constexpr int M = B * S;          // 8192 rows

typedef __attribute__((ext_vector_type(8))) short short8;  // 8 bf16 (4 VGPRs)
typedef __attribute__((ext_vector_type(4))) float f32x4;

// fp32 -> bf16 bits, round-to-nearest-even
static __device__ __forceinline__ unsigned short f2bf(float f) {
    unsigned int x = __float_as_uint(f);
    x += 0x7FFFu + ((x >> 16) & 1u);
    return (unsigned short)(x >> 16);
}
static __device__ __forceinline__ float bf2f(unsigned short u) {
    return __uint_as_float(((unsigned int)u) << 16);
}

// async global->LDS, 16B per lane (global_load_lds_dwordx4)
typedef __attribute__((address_space(3))) unsigned int  lds_uint;
typedef __attribute__((address_space(1))) unsigned int  glb_uint;
static __device__ __forceinline__ void gload16(const unsigned short* g, unsigned short* l) {
    __builtin_amdgcn_global_load_lds((const glb_uint*)g, (lds_uint*)l, 16, 0, 0);
}
// s_waitcnt vmcnt(N) only (lgkm=15, exp=7 untouched). m135: in-order drain.
template <int N>
static __device__ __forceinline__ void waitvm() {
    __builtin_amdgcn_s_waitcnt(0x0F70 | N);
}

// ---------------------------------------------------------------------------
// LN -> bf16: one wave per row (E=512, 8 elems/lane), stats via 64-lane shuffles.
// ---------------------------------------------------------------------------
__global__ __launch_bounds__(256) void ln_bf16_kernel(
    const float* __restrict__ x, const float* __restrict__ w,
    const float* __restrict__ bb, unsigned short* __restrict__ out) {
    int row = blockIdx.x * 4 + (threadIdx.x >> 6);
    int lane = threadIdx.x & 63;
    const float* xr = x + (size_t)row * E + lane * 8;
    float4 v0 = *(const float4*)xr;
    float4 v1 = *(const float4*)(xr + 4);
    float vv[8] = {v0.x, v0.y, v0.z, v0.w, v1.x, v1.y, v1.z, v1.w};
    float s = 0.f;
    #pragma unroll
    for (int i = 0; i < 8; i++) s += vv[i];
    #pragma unroll
    for (int o = 1; o < 64; o <<= 1) s += __shfl_xor(s, o);
    float mu = s * (1.0f / E);
    float qs = 0.f;
    #pragma unroll
    for (int i = 0; i < 8; i++) { float d = vv[i] - mu; qs += d * d; }
    #pragma unroll
    for (int o = 1; o < 64; o <<= 1) qs += __shfl_xor(qs, o);
    float rs = rsqrtf(qs * (1.0f / E) + EPS);
    float4 w0 = *(const float4*)(w + lane * 8), w1 = *(const float4*)(w + lane * 8 + 4);
    float4 b0 = *(const float4*)(bb + lane * 8), b1 = *(const float4*)(bb + lane * 8 + 4);
    float ww[8] = {w0.x, w0.y, w0.z, w0.w, w1.x, w1.y, w1.z, w1.w};
    float bv[8] = {b0.x, b0.y, b0.z, b0.w, b1.x, b1.y, b1.z, b1.w};
    short8 o8;
    #pragma unroll
    for (int i = 0; i < 8; i++) o8[i] = (short)f2bf((vv[i] - mu) * rs * ww[i] + bv[i]);
    *(short8*)(out + (size_t)row * E + lane * 8) = o8;
}

// ---------------------------------------------------------------------------
// Full LN (fp32 out) for the final output — wave-per-row.
// ---------------------------------------------------------------------------
__global__ __launch_bounds__(256) void ln_full_kernel(
    const float* __restrict__ x, const float* __restrict__ w,
    const float* __restrict__ bb, float* __restrict__ out) {
    int row = blockIdx.x * 4 + (threadIdx.x >> 6);
    int lane = threadIdx.x & 63;
    const float* xr = x + (size_t)row * E + lane * 8;
    float4 v0 = *(const float4*)xr;
    float4 v1 = *(const float4*)(xr + 4);
    float vv[8] = {v0.x, v0.y, v0.z, v0.w, v1.x, v1.y, v1.z, v1.w};
    float s = 0.f;
    #pragma unroll
    for (int i = 0; i < 8; i++) s += vv[i];
    #pragma unroll
    for (int o = 1; o < 64; o <<= 1) s += __shfl_xor(s, o);
    float mu = s * (1.0f / E);
    float qs = 0.f;
    #pragma unroll
    for (int i = 0; i < 8; i++) { float d = vv[i] - mu; qs += d * d; }
    #pragma unroll
    for (int o = 1; o < 64; o <<= 1) qs += __shfl_xor(qs, o);
    float rs = rsqrtf(qs * (1.0f / E) + EPS);
    float4 w0 = *(const float4*)(w + lane * 8), w1 = *(const float4*)(w + lane * 8 + 4);
    float4 b0 = *(const float4*)(bb + lane * 8), b1 = *(const float4*)(bb + lane * 8 + 4);
    float* op = out + (size_t)row * E + lane * 8;
    float4 o0, o1;
    o0.x = (vv[0] - mu) * rs * w0.x + b0.x;
    o0.y = (vv[1] - mu) * rs * w0.y + b0.y;
    o0.z = (vv[2] - mu) * rs * w0.z + b0.z;
    o0.w = (vv[3] - mu) * rs * w0.w + b0.w;
    o1.x = (vv[4] - mu) * rs * w1.x + b1.x;
    o1.y = (vv[5] - mu) * rs * w1.y + b1.y;
    o1.z = (vv[6] - mu) * rs * w1.z + b1.z;
    o1.w = (vv[7] - mu) * rs * w1.w + b1.w;
    *(float4*)op = o0;
    *(float4*)(op + 4) = o1;
}

// ---------------------------------------------------------------------------
// Weight conversion f32 -> bf16 into one packed buffer: [qkv | o | f]
// ---------------------------------------------------------------------------
__global__ __launch_bounds__(256) void w2bf_kernel(
    const float* __restrict__ wqkv, const float* __restrict__ wo,
    const float* __restrict__ wf, unsigned short* __restrict__ out) {
    int base = (blockIdx.x * 256 + threadIdx.x) * 4;
    float4 v;
    if (base < 3 * E * E)           v = *(const float4*)(wqkv + base);
    else if (base < 4 * E * E)      v = *(const float4*)(wo + (base - 3 * E * E));
    else                            v = *(const float4*)(wf + (base - 4 * E * E));
    ushort4 o;
    o.x = f2bf(v.x); o.y = f2bf(v.y); o.z = f2bf(v.z); o.w = f2bf(v.w);
    *(ushort4*)(out + base) = o;
}

// ---------------------------------------------------------------------------
// bf16 MFMA GEMM (m97 structure): C[M,Ntot] = A[M,512] @ W[Ntot,512]^T + bias
//   OUT_MODE 1: f32 +residf; 2: f32 +bf16 resid   (o-proj / ff)
// ---------------------------------------------------------------------------
template <int OUT_MODE>
__global__ __launch_bounds__(256) void gemm_mfma(
    const unsigned short* __restrict__ A, const unsigned short* __restrict__ W,
    const float* __restrict__ bias,
    const float* __restrict__ residf, const unsigned short* __restrict__ residb,
    void* __restrict__ C0, int Ntot) {
    __shared__ unsigned short As[128 * 32];
    __shared__ unsigned short Bs[128 * 32];
    const int t = threadIdx.x;
    const int wave = t >> 6, lane = t & 63;
    const int quad = lane >> 4, l16 = lane & 15;
    const int m0 = blockIdx.x * 128, n0 = blockIdx.y * 128;
    const int wm = (wave >> 1) * 64, wn = (wave & 1) * 64;

    const int srow = t >> 2;
    const int skof = (t & 3) * 8;

    f32x4 acc[4][4];
    #pragma unroll
    for (int i = 0; i < 4; i++)
        #pragma unroll
        for (int j = 0; j < 4; j++) acc[i][j] = (f32x4){0.f, 0.f, 0.f, 0.f};

    for (int k0 = 0; k0 < E; k0 += 32) {
        gload16(A + (size_t)(m0 + srow) * E + k0 + skof,        As + t * 8);
        gload16(A + (size_t)(m0 + 64 + srow) * E + k0 + skof,   As + 2048 + t * 8);
        gload16(W + (size_t)(n0 + srow) * E + k0 + skof,        Bs + t * 8);
        gload16(W + (size_t)(n0 + 64 + srow) * E + k0 + skof,   Bs + 2048 + t * 8);
        __syncthreads();
        short8 af[4], bfr[4];
        #pragma unroll
        for (int i = 0; i < 4; i++)
            af[i] = *(const short8*)&As[(wm + i * 16 + l16) * 32 + quad * 8];
        #pragma unroll
        for (int j = 0; j < 4; j++)
            bfr[j] = *(const short8*)&Bs[(wn + j * 16 + l16) * 32 + quad * 8];
        #pragma unroll
        for (int i = 0; i < 4; i++)
            #pragma unroll
            for (int j = 0; j < 4; j++)
                acc[i][j] = __builtin_amdgcn_mfma_f32_16x16x32_bf16(af[i], bfr[j], acc[i][j], 0, 0, 0);
        __syncthreads();
    }

    #pragma unroll
    for (int i = 0; i < 4; i++) {
        const int mrow0 = m0 + wm + i * 16 + quad * 4;
        #pragma unroll
        for (int j = 0; j < 4; j++) {
            const int ncol = n0 + wn + j * 16 + l16;
            const float bval = bias[ncol];
            if (OUT_MODE == 1) {
                #pragma unroll
                for (int r = 0; r < 4; r++) {
                    size_t idx = (size_t)(mrow0 + r) * Ntot + ncol;
                    ((float*)C0)[idx] = acc[i][j][r] + bval + residf[idx];
                }
            } else {
                #pragma unroll
                for (int r = 0; r < 4; r++) {
                    size_t idx = (size_t)(mrow0 + r) * Ntot + ncol;
                    ((float*)C0)[idx] = acc[i][j][r] + bval + bf2f(residb[idx]);
                }
            }
        }
    }
}

// ---------------------------------------------------------------------------
// Fused q + kv projection GEMM. Grid (M/128, 12): y<4 -> q panel (A=Aq,
// out=qout bf16 [M,512]); y>=4 -> kv panel (A=Akv, out k bf16 / v^T bf16).
// One launch, 768 blocks = 3 blocks/CU (vs 1/CU + 2/CU sequential).
// Measured (r9 vs r7): worth ~11.6 us over the split launches.
// ---------------------------------------------------------------------------
__global__ __launch_bounds__(256) void gemm_qkv(
    const unsigned short* __restrict__ Aq, const unsigned short* __restrict__ Akv,
    const unsigned short* __restrict__ W,   // packed [3E][E] bf16
    const float* __restrict__ bias,         // [3E]
    unsigned short* __restrict__ qout,      // [M][512] bf16
    unsigned short* __restrict__ kout,      // [M][512] bf16
    unsigned short* __restrict__ vtout) {   // [B][512][1024] bf16
    __shared__ unsigned short As[128 * 32];
    __shared__ unsigned short Bs[128 * 32];
    const int t = threadIdx.x;
    const int wave = t >> 6, lane = t & 63;
    const int quad = lane >> 4, l16 = lane & 15;
    const bool isq = blockIdx.y < 4;
    const int yy = isq ? blockIdx.y : blockIdx.y - 4;
    const unsigned short* A  = isq ? Aq : Akv;
    const unsigned short* Wb = W + (isq ? 0 : (size_t)E * E);
    const float* bb = bias + (isq ? 0 : E);
    const int m0 = blockIdx.x * 128, n0 = yy * 128;
    const int wm = (wave >> 1) * 64, wn = (wave & 1) * 64;

    const int srow = t >> 2;
    const int skof = (t & 3) * 8;

    f32x4 acc[4][4];
    #pragma unroll
    for (int i = 0; i < 4; i++)
        #pragma unroll
        for (int j = 0; j < 4; j++) acc[i][j] = (f32x4){0.f, 0.f, 0.f, 0.f};

    for (int k0 = 0; k0 < E; k0 += 32) {
        gload16(A + (size_t)(m0 + srow) * E + k0 + skof,         As + t * 8);
        gload16(A + (size_t)(m0 + 64 + srow) * E + k0 + skof,    As + 2048 + t * 8);
        gload16(Wb + (size_t)(n0 + srow) * E + k0 + skof,        Bs + t * 8);
        gload16(Wb + (size_t)(n0 + 64 + srow) * E + k0 + skof,   Bs + 2048 + t * 8);
        __syncthreads();
        short8 af[4], bfr[4];
        #pragma unroll
        for (int i = 0; i < 4; i++)
            af[i] = *(const short8*)&As[(wm + i * 16 + l16) * 32 + quad * 8];
        #pragma unroll
        for (int j = 0; j < 4; j++)
            bfr[j] = *(const short8*)&Bs[(wn + j * 16 + l16) * 32 + quad * 8];
        #pragma unroll
        for (int i = 0; i < 4; i++)
            #pragma unroll
            for (int j = 0; j < 4; j++)
                acc[i][j] = __builtin_amdgcn_mfma_f32_16x16x32_bf16(af[i], bfr[j], acc[i][j], 0, 0, 0);
        __syncthreads();
    }

    #pragma unroll
    for (int i = 0; i < 4; i++) {
        const int mrow0 = m0 + wm + i * 16 + quad * 4;
        #pragma unroll
        for (int j = 0; j < 4; j++) {
            const int ncol = n0 + wn + j * 16 + l16;
            const float bval = bb[ncol];
            if (isq) {
                #pragma unroll
                for (int r = 0; r < 4; r++)
                    qout[(size_t)(mrow0 + r) * 512 + ncol] = f2bf(acc[i][j][r] + bval);
            } else if (ncol < 512) {
                #pragma unroll
                for (int r = 0; r < 4; r++)
                    kout[(size_t)(mrow0 + r) * 512 + ncol] = f2bf(acc[i][j][r] + bval);
            } else {
                const int nv = ncol - 512;
                const int b2 = mrow0 >> 10, s0v = mrow0 & 1023;
                ushort4 o;
                o.x = f2bf(acc[i][j][0] + bval);
                o.y = f2bf(acc[i][j][1] + bval);
                o.z = f2bf(acc[i][j][2] + bval);
                o.w = f2bf(acc[i][j][3] + bval);
                *(ushort4*)(vtout + ((size_t)b2 * 512 + nv) * 1024 + s0v) = o;
            }
        }
    }
}

// ---------------------------------------------------------------------------
// MFMA attention v5 (reverted from v6b — measured best: 92 us):
// wave-private DMA staging of BOTH K and V (coalesced global_load_lds,
// XOR-swizzled LDS -> 2-way-max bank aliasing on ds_read_b128), 2-deep chunk
// prefetch gated by s_waitcnt vmcnt(N). Round-9 A/B: direct-global V loads
// (same occupancy, no spills) cost +20 us — the DMA path wins; do not remove
// staging again. 4 heads/block -> 2 bf16 aw planes. Grid = B*2*64 = 1024;
// 3 blocks/CU (LDS 50 KB).
// ---------------------------------------------------------------------------
__global__ __launch_bounds__(256, 2) void attn_mfma_kernel(
    const unsigned short* __restrict__ q,   // [B][S][E] bf16
    const unsigned short* __restrict__ k,   // [B][S][E] bf16
    const unsigned short* __restrict__ vt,  // [B][E][S] bf16
    unsigned short* __restrict__ ctx,       // [B][S][E] bf16
    unsigned short* __restrict__ awp) {     // bf16 planes [2][B][S][S]
    __shared__ unsigned short s_mem[16 * 1032]; // P (16x1032) | K-staging union
    __shared__ unsigned short s_v[4 * 2048];    // V staging: 4 waves x 2 bufs x 1024
    __shared__ float s_red[2][4][16];

    const int t = threadIdx.x;
    const int wave = t >> 6, lane = t & 63;
    const int quad = lane >> 4, l16 = lane & 15;
    const int qt   = blockIdx.x & 63;
    const int rest = blockIdx.x >> 6;
    const int hg   = rest & 1;              // head group (4 heads each)
    const int b    = rest >> 1;
    const int q0   = qt * 16;
    const size_t qrow = ((size_t)(b * S + q0 + l16)) * E;

    // wave-private staging areas (shorts)
    unsigned short* karea = s_mem + wave * 4128;   // 2 bufs x 2048 (32 rows x 64)
    unsigned short* varea = s_v + wave * 2048;     // 2 bufs x 1024 (16 rows x 64)

    // DMA lane mapping: dest = base + lane*8 shorts (HW rule); XOR source swizzle
    const int dr = lane >> 3;               // row within 8-row group
    const int dc = lane & 7;                // dest 16B col-block
    const int csrc = dc ^ dr;               // swizzled source col-block
    const int sw7 = l16 & 7;                // read-side swizzle key

    f32x4 awacc[16];
    #pragma unroll
    for (int i = 0; i < 16; i++) awacc[i] = (f32x4){0.f, 0.f, 0.f, 0.f};

    #pragma clang loop unroll(disable)
    for (int hh = 0; hh < 4; hh++) {
        const int h = hg * 4 + hh;

        // K chunk c (32 rows of wave's k-range) -> buf
        auto stage_k = [&](int c, int buf) {
            const unsigned short* src =
                k + ((size_t)(b * S + wave * 256 + c * 32 + dr)) * E + h * 64 + csrc * 8;
            unsigned short* dst = karea + buf * 2048 + dr * 64 + dc * 8;
            gload16(src,                  dst);
            gload16(src + (size_t)8 * E,  dst + 512);
            gload16(src + (size_t)16 * E, dst + 1024);
            gload16(src + (size_t)24 * E, dst + 1536);
        };
        // V chunk cv (64 s-cols of wave's 16 d-rows) -> buf
        auto stage_v = [&](int cv, int buf) {
            const unsigned short* src =
                vt + ((size_t)(b * E + h * 64 + wave * 16 + dr)) * S + cv * 64 + csrc * 8;
            unsigned short* dst = varea + buf * 1024 + dr * 64 + dc * 8;
            gload16(src,                 dst);
            gload16(src + (size_t)8 * S, dst + 512);
        };

        short8 aq0 = *(const short8*)(q + qrow + h * 64 + quad * 8);
        short8 aq1 = *(const short8*)(q + qrow + h * 64 + 32 + quad * 8);

        // ---- scores: 8 staged K chunks, 2-deep prefetch ----
        f32x4 sacc[16];
        stage_k(0, 0);
        stage_k(1, 1);
        #pragma unroll
        for (int c = 0; c < 8; c++) {
            if (c < 7) waitvm<4>(); else waitvm<0>();
            const unsigned short* kbuf = karea + (c & 1) * 2048;
            #pragma unroll
            for (int ntl = 0; ntl < 2; ntl++) {
                const int rl = ntl * 16 + l16;
                short8 kf0 = *(const short8*)(kbuf + rl * 64 + ((quad)     ^ sw7) * 8);
                short8 kf1 = *(const short8*)(kbuf + rl * 64 + ((4 + quad) ^ sw7) * 8);
                f32x4 cc = (f32x4){0.f, 0.f, 0.f, 0.f};
                cc = __builtin_amdgcn_mfma_f32_16x16x32_bf16(aq0, kf0, cc, 0, 0, 0);
                cc = __builtin_amdgcn_mfma_f32_16x16x32_bf16(aq1, kf1, cc, 0, 0, 0);
                sacc[c * 2 + ntl] = cc * 0.125f;
            }
            if (c < 6) stage_k(c + 2, c & 1);
        }

        // ---- merged single-pass softmax: local max+exp+sum pre-barrier ----
        float lm[4], ls[4];
        #pragma unroll
        for (int r = 0; r < 4; r++) {
            float mv = sacc[0][r];
            #pragma unroll
            for (int nt = 1; nt < 16; nt++) mv = fmaxf(mv, sacc[nt][r]);
            #pragma unroll
            for (int o = 1; o < 16; o <<= 1) mv = fmaxf(mv, __shfl_xor(mv, o));
            lm[r] = mv;
            ls[r] = 0.f;
        }
        #pragma unroll
        for (int nt = 0; nt < 16; nt++)
            #pragma unroll
            for (int r = 0; r < 4; r++) {
                float e = __expf(sacc[nt][r] - lm[r]);
                sacc[nt][r] = e;
                ls[r] += e;
            }
        #pragma unroll
        for (int r = 0; r < 4; r++) {
            #pragma unroll
            for (int o = 1; o < 16; o <<= 1) ls[r] += __shfl_xor(ls[r], o);
        }
        if (l16 == 0) {
            #pragma unroll
            for (int r = 0; r < 4; r++) {
                s_red[0][wave][quad * 4 + r] = lm[r];
                s_red[1][wave][quad * 4 + r] = ls[r];
            }
        }
        __syncthreads();                                   // (B1) also: all K reads done
        float scale[4];
        #pragma unroll
        for (int r = 0; r < 4; r++) {
            const int row = quad * 4 + r;
            float m0 = s_red[0][0][row], m1 = s_red[0][1][row];
            float m2 = s_red[0][2][row], m3 = s_red[0][3][row];
            float gmax = fmaxf(fmaxf(m0, m1), fmaxf(m2, m3));
            float gsum = s_red[1][0][row] * __expf(m0 - gmax)
                       + s_red[1][1][row] * __expf(m1 - gmax)
                       + s_red[1][2][row] * __expf(m2 - gmax)
                       + s_red[1][3][row] * __expf(m3 - gmax);
            scale[r] = __expf(lm[r] - gmax) / gsum;
        }

        // ---- normalize, accumulate aw, write P (bf16) into s_mem [16][1032] ----
        #pragma unroll
        for (int nt = 0; nt < 16; nt++) {
            #pragma unroll
            for (int r = 0; r < 4; r++) {
                float p = sacc[nt][r] * scale[r];
                awacc[nt][r] += p;
                s_mem[(quad * 4 + r) * 1032 + wave * 256 + nt * 16 + l16] = f2bf(p);
            }
        }
        __syncthreads();                                   // (B2) P visible

        // ---- PV: 16 staged V chunks, 2-deep prefetch; P from s_mem ----
        f32x4 cacc0 = (f32x4){0.f, 0.f, 0.f, 0.f};
        f32x4 cacc1 = (f32x4){0.f, 0.f, 0.f, 0.f};
        stage_v(0, 0);
        stage_v(1, 1);
        #pragma unroll
        for (int cv = 0; cv < 16; cv++) {
            if (cv < 15) waitvm<2>(); else waitvm<0>();
            const unsigned short* vbuf = varea + (cv & 1) * 1024;
            short8 vf0 = *(const short8*)(vbuf + l16 * 64 + ((quad)     ^ sw7) * 8);
            short8 vf1 = *(const short8*)(vbuf + l16 * 64 + ((4 + quad) ^ sw7) * 8);
            short8 pf0 = *(const short8*)(s_mem + l16 * 1032 + cv * 64 + quad * 8);
            short8 pf1 = *(const short8*)(s_mem + l16 * 1032 + cv * 64 + 32 + quad * 8);
            cacc0 = __builtin_amdgcn_mfma_f32_16x16x32_bf16(pf0, vf0, cacc0, 0, 0, 0);
            cacc1 = __builtin_amdgcn_mfma_f32_16x16x32_bf16(pf1, vf1, cacc1, 0, 0, 0);
            if (cv < 14) stage_v(cv + 2, cv & 1);
        }
        f32x4 cacc = cacc0 + cacc1;
        unsigned short* crow = ctx + ((size_t)(b * S + q0)) * E + h * 64 + wave * 16 + l16;
        #pragma unroll
        for (int r = 0; r < 4; r++)
            crow[(size_t)(quad * 4 + r) * E] = f2bf(cacc[r]);
        __syncthreads();                                   // (B3) P reads done -> K restage safe
    }

    // ---- head-group partial plane (bf16) ----
    #pragma unroll
    for (int nt = 0; nt < 16; nt++) {
        #pragma unroll
        for (int r = 0; r < 4; r++)
            awp[((size_t)((hg * B + b) * S + q0 + quad * 4 + r)) * S +
                wave * 256 + nt * 16 + l16] = f2bf(awacc[nt][r]);
    }
}

// ---------------------------------------------------------------------------
// aw reduce: aw = (1/H) * sum of NP bf16 planes. 8 f32 outputs per thread.
// ---------------------------------------------------------------------------
template <int NP>
__global__ __launch_bounds__(256) void aw_reduce_kernel(
    const unsigned short* __restrict__ awp, float* __restrict__ aw) {
    const size_t PLN = (size_t)B * S * S;
    size_t idx = ((size_t)blockIdx.x * 256 + threadIdx.x) * 8;
    float acc[8] = {};
    #pragma unroll
    for (int p = 0; p < NP; p++) {
        short8 v = *(const short8*)(awp + p * PLN + idx);
        #pragma unroll
        for (int j = 0; j < 8; j++) acc[j] += bf2f((unsigned short)v[j]);
    }
    float4 o0 = make_float4(acc[0] * (1.0f / H), acc[1] * (1.0f / H),
                            acc[2] * (1.0f / H), acc[3] * (1.0f / H));
    float4 o1 = make_float4(acc[4] * (1.0f / H), acc[5] * (1.0f / H),
                            acc[6] * (1.0f / H), acc[7] * (1.0f / H));
    *(float4*)(aw + idx) = o0;
    *(float4*)(aw + idx + 4) = o1;
}

// ---------------------------------------------------------------------------
extern "C" void kernel_launch(void* const* d_in, const int* in_sizes, int n_in,
                              void* d_out, int out_size, void* d_ws, size_t ws_size,
                              hipStream_t stream) {
    const float* Zab  = (const float*)d_in[0];
    const float* Za   = (const float*)d_in[1];
    const float* lnw  = (const float*)d_in[2];
    const float* lnb  = (const float*)d_in[3];
    const float* Wqkv = (const float*)d_in[4];
    const float* bqkv = (const float*)d_in[5];
    const float* Wo   = (const float*)d_in[6];
    const float* bo   = (const float*)d_in[7];
    const float* Wf   = (const float*)d_in[8];
    const float* bf   = (const float*)d_in[9];

    float* out_final = (float*)d_out;
    float* out_aw    = out_final + (size_t)B * S * E;

    char* ws = (char*)d_ws;
    // Static buffers (live through attention):
    unsigned short* qb   = (unsigned short*)(ws);               // [0,8M)
    unsigned short* kb   = (unsigned short*)(ws + (8u << 20));  // [8,16M)
    unsigned short* vtb  = (unsigned short*)(ws + (16u << 20)); // [16,24M)
    unsigned short* ctxb = (unsigned short*)(ws + (24u << 20)); // [24,32M)
    // Pre-attention staging (dead once attention starts):
    unsigned short* aqb  = (unsigned short*)(ws + (32u << 20)); // [32,40M)
    unsigned short* akvb = (unsigned short*)(ws + (40u << 20)); // [40,48M)
    // awp planes: 2 x 16 MB at [32,64M) (aqb/akvb dead by attention)
    unsigned short* awp  = (unsigned short*)(ws + (32ull << 20));
    unsigned short* wbf  = (unsigned short*)(ws + (96ull << 20)); // 2.5 MB
    // Post-attention f32 buffers:
    float* xb  = (float*)(ws);                                  // [0,16M)
    float* tb  = (float*)(ws + (16u << 20));                    // [16,32M)
    unsigned short* xnb = aqb;                                  // [32,40M) after reduce

    dim3 blk(256);

    // 1. weights -> bf16 (packed: qkv | o | f)
    w2bf_kernel<<<(5 * E * E) / 1024, blk, 0, stream>>>(Wqkv, Wo, Wf, wbf);

    // 2. LN(Zab), LN(Za) -> bf16
    ln_bf16_kernel<<<M / 4, blk, 0, stream>>>(Zab, lnw, lnb, aqb);
    ln_bf16_kernel<<<M / 4, blk, 0, stream>>>(Za,  lnw, lnb, akvb);

    // 3. fused q/kv projection: one launch, 768 blocks = 3 blocks/CU
    gemm_qkv<<<dim3(M / 128, 12), blk, 0, stream>>>(aqb, akvb, wbf, bqkv, qb, kb, vtb);

    // 4. attention (staged K/V, 4 heads/block) -> ctx + 2 planes; reduce
    attn_mfma_kernel<<<B * 2 * 64, blk, 0, stream>>>(qb, kb, vtb, ctxb, awp);
    aw_reduce_kernel<2><<<4096, blk, 0, stream>>>(awp, out_aw);

    // 5. x = ctx@Wo^T + bo + Zab (f32)
    gemm_mfma<1><<<dim3(M / 128, 4), blk, 0, stream>>>(ctxb, wbf + (size_t)3*E*E, bo, Zab, nullptr, xb, 512);

    // 6. xn = LN(x) -> bf16
    ln_bf16_kernel<<<M / 4, blk, 0, stream>>>(xb, lnw, lnb, xnb);

    // 7. t = xn@Wf^T + bf + xn (f32)
    gemm_mfma<2><<<dim3(M / 128, 4), blk, 0, stream>>>(xnb, wbf + (size_t)4*E*E, bf, nullptr, xnb, tb, 512);

    // 8. final = LN(t)
    ln_full_kernel<<<M / 4, blk, 0, stream>>>(tb, lnw, lnb, out_final);
}

// Round 11
// 264.580 us; speedup vs baseline: 1.3062x; 1.0073x over previous
//
#include <hip/hip_runtime.h>
#include <math.h>

#define EPS 1e-5f

constexpr int B = 8, S = 1024, E = 512, H = 8;
constexpr int M = B * S;          // 8192 rows

typedef __attribute__((ext_vector_type(8))) short short8;  // 8 bf16 (4 VGPRs)
typedef __attribute__((ext_vector_type(4))) float f32x4;

// fp32 -> bf16 bits, round-to-nearest-even
static __device__ __forceinline__ unsigned short f2bf(float f) {
    unsigned int x = __float_as_uint(f);
    x += 0x7FFFu + ((x >> 16) & 1u);
    return (unsigned short)(x >> 16);
}
static __device__ __forceinline__ float bf2f(unsigned short u) {
    return __uint_as_float(((unsigned int)u) << 16);
}

// async global->LDS, 16B per lane (global_load_lds_dwordx4)
typedef __attribute__((address_space(3))) unsigned int  lds_uint;
typedef __attribute__((address_space(1))) unsigned int  glb_uint;
static __device__ __forceinline__ void gload16(const unsigned short* g, unsigned short* l) {
    __builtin_amdgcn_global_load_lds((const glb_uint*)g, (lds_uint*)l, 16, 0, 0);
}
// s_waitcnt vmcnt(N) only (lgkm=15, exp=7 untouched). m135: in-order drain.
template <int N>
static __device__ __forceinline__ void waitvm() {
    __builtin_amdgcn_s_waitcnt(0x0F70 | N);
}

// ---------------------------------------------------------------------------
// LN -> bf16 over TWO inputs in one launch (rows [0,M) -> x0/o0, [M,2M) ->
// x1/o1). One wave per row, stats via 64-lane shuffles.
// ---------------------------------------------------------------------------
__global__ __launch_bounds__(256) void ln2_bf16_kernel(
    const float* __restrict__ x0, const float* __restrict__ x1,
    const float* __restrict__ w, const float* __restrict__ bb,
    unsigned short* __restrict__ o0, unsigned short* __restrict__ o1) {
    int row = blockIdx.x * 4 + (threadIdx.x >> 6);
    int lane = threadIdx.x & 63;
    const float* x = row < M ? x0 : x1;
    unsigned short* out = row < M ? o0 : o1;
    int r = row < M ? row : row - M;
    const float* xr = x + (size_t)r * E + lane * 8;
    float4 v0 = *(const float4*)xr;
    float4 v1 = *(const float4*)(xr + 4);
    float vv[8] = {v0.x, v0.y, v0.z, v0.w, v1.x, v1.y, v1.z, v1.w};
    float s = 0.f;
    #pragma unroll
    for (int i = 0; i < 8; i++) s += vv[i];
    #pragma unroll
    for (int o = 1; o < 64; o <<= 1) s += __shfl_xor(s, o);
    float mu = s * (1.0f / E);
    float qs = 0.f;
    #pragma unroll
    for (int i = 0; i < 8; i++) { float d = vv[i] - mu; qs += d * d; }
    #pragma unroll
    for (int o = 1; o < 64; o <<= 1) qs += __shfl_xor(qs, o);
    float rs = rsqrtf(qs * (1.0f / E) + EPS);
    float4 w0 = *(const float4*)(w + lane * 8), w1 = *(const float4*)(w + lane * 8 + 4);
    float4 b0 = *(const float4*)(bb + lane * 8), b1 = *(const float4*)(bb + lane * 8 + 4);
    float ww[8] = {w0.x, w0.y, w0.z, w0.w, w1.x, w1.y, w1.z, w1.w};
    float bv[8] = {b0.x, b0.y, b0.z, b0.w, b1.x, b1.y, b1.z, b1.w};
    short8 o8;
    #pragma unroll
    for (int i = 0; i < 8; i++) o8[i] = (short)f2bf((vv[i] - mu) * rs * ww[i] + bv[i]);
    *(short8*)(out + (size_t)r * E + lane * 8) = o8;
}

// ---------------------------------------------------------------------------
// LN -> bf16: one wave per row (single input; used post-attention).
// ---------------------------------------------------------------------------
__global__ __launch_bounds__(256) void ln_bf16_kernel(
    const float* __restrict__ x, const float* __restrict__ w,
    const float* __restrict__ bb, unsigned short* __restrict__ out) {
    int row = blockIdx.x * 4 + (threadIdx.x >> 6);
    int lane = threadIdx.x & 63;
    const float* xr = x + (size_t)row * E + lane * 8;
    float4 v0 = *(const float4*)xr;
    float4 v1 = *(const float4*)(xr + 4);
    float vv[8] = {v0.x, v0.y, v0.z, v0.w, v1.x, v1.y, v1.z, v1.w};
    float s = 0.f;
    #pragma unroll
    for (int i = 0; i < 8; i++) s += vv[i];
    #pragma unroll
    for (int o = 1; o < 64; o <<= 1) s += __shfl_xor(s, o);
    float mu = s * (1.0f / E);
    float qs = 0.f;
    #pragma unroll
    for (int i = 0; i < 8; i++) { float d = vv[i] - mu; qs += d * d; }
    #pragma unroll
    for (int o = 1; o < 64; o <<= 1) qs += __shfl_xor(qs, o);
    float rs = rsqrtf(qs * (1.0f / E) + EPS);
    float4 w0 = *(const float4*)(w + lane * 8), w1 = *(const float4*)(w + lane * 8 + 4);
    float4 b0 = *(const float4*)(bb + lane * 8), b1 = *(const float4*)(bb + lane * 8 + 4);
    float ww[8] = {w0.x, w0.y, w0.z, w0.w, w1.x, w1.y, w1.z, w1.w};
    float bv[8] = {b0.x, b0.y, b0.z, b0.w, b1.x, b1.y, b1.z, b1.w};
    short8 o8;
    #pragma unroll
    for (int i = 0; i < 8; i++) o8[i] = (short)f2bf((vv[i] - mu) * rs * ww[i] + bv[i]);
    *(short8*)(out + (size_t)row * E + lane * 8) = o8;
}

// ---------------------------------------------------------------------------
// Full LN (fp32 out) for the final output — wave-per-row.
// ---------------------------------------------------------------------------
__global__ __launch_bounds__(256) void ln_full_kernel(
    const float* __restrict__ x, const float* __restrict__ w,
    const float* __restrict__ bb, float* __restrict__ out) {
    int row = blockIdx.x * 4 + (threadIdx.x >> 6);
    int lane = threadIdx.x & 63;
    const float* xr = x + (size_t)row * E + lane * 8;
    float4 v0 = *(const float4*)xr;
    float4 v1 = *(const float4*)(xr + 4);
    float vv[8] = {v0.x, v0.y, v0.z, v0.w, v1.x, v1.y, v1.z, v1.w};
    float s = 0.f;
    #pragma unroll
    for (int i = 0; i < 8; i++) s += vv[i];
    #pragma unroll
    for (int o = 1; o < 64; o <<= 1) s += __shfl_xor(s, o);
    float mu = s * (1.0f / E);
    float qs = 0.f;
    #pragma unroll
    for (int i = 0; i < 8; i++) { float d = vv[i] - mu; qs += d * d; }
    #pragma unroll
    for (int o = 1; o < 64; o <<= 1) qs += __shfl_xor(qs, o);
    float rs = rsqrtf(qs * (1.0f / E) + EPS);
    float4 w0 = *(const float4*)(w + lane * 8), w1 = *(const float4*)(w + lane * 8 + 4);
    float4 b0 = *(const float4*)(bb + lane * 8), b1 = *(const float4*)(bb + lane * 8 + 4);
    float* op = out + (size_t)row * E + lane * 8;
    float4 o0, o1;
    o0.x = (vv[0] - mu) * rs * w0.x + b0.x;
    o0.y = (vv[1] - mu) * rs * w0.y + b0.y;
    o0.z = (vv[2] - mu) * rs * w0.z + b0.z;
    o0.w = (vv[3] - mu) * rs * w0.w + b0.w;
    o1.x = (vv[4] - mu) * rs * w1.x + b1.x;
    o1.y = (vv[5] - mu) * rs * w1.y + b1.y;
    o1.z = (vv[6] - mu) * rs * w1.z + b1.z;
    o1.w = (vv[7] - mu) * rs * w1.w + b1.w;
    *(float4*)op = o0;
    *(float4*)(op + 4) = o1;
}

// ---------------------------------------------------------------------------
// Weight conversion f32 -> bf16 into one packed buffer: [qkv | o | f]
// ---------------------------------------------------------------------------
__global__ __launch_bounds__(256) void w2bf_kernel(
    const float* __restrict__ wqkv, const float* __restrict__ wo,
    const float* __restrict__ wf, unsigned short* __restrict__ out) {
    int base = (blockIdx.x * 256 + threadIdx.x) * 4;
    float4 v;
    if (base < 3 * E * E)           v = *(const float4*)(wqkv + base);
    else if (base < 4 * E * E)      v = *(const float4*)(wo + (base - 3 * E * E));
    else                            v = *(const float4*)(wf + (base - 4 * E * E));
    ushort4 o;
    o.x = f2bf(v.x); o.y = f2bf(v.y); o.z = f2bf(v.z); o.w = f2bf(v.w);
    *(ushort4*)(out + base) = o;
}

// ---------------------------------------------------------------------------
// 64x128-tile bf16 MFMA GEMM for the post-attention projections (N=512 ->
// grid (M/64, 4) = 512 blocks = 2 blocks/CU vs 128-tile's 1/CU starvation).
// Wave w owns a 32x64 sub-tile: wm=(w>>1)*32, wn=(w&1)*64, acc[2][4].
//   OUT_MODE 1: f32 +residf; 2: f32 +bf16 resid.
// ---------------------------------------------------------------------------
template <int OUT_MODE>
__global__ __launch_bounds__(256) void gemm_mfma64(
    const unsigned short* __restrict__ A, const unsigned short* __restrict__ W,
    const float* __restrict__ bias,
    const float* __restrict__ residf, const unsigned short* __restrict__ residb,
    void* __restrict__ C0, int Ntot) {
    __shared__ unsigned short As[64 * 32];    // 4 KB
    __shared__ unsigned short Bs[128 * 32];   // 8 KB
    const int t = threadIdx.x;
    const int wave = t >> 6, lane = t & 63;
    const int quad = lane >> 4, l16 = lane & 15;
    const int m0 = blockIdx.x * 64, n0 = blockIdx.y * 128;
    const int wm = (wave >> 1) * 32, wn = (wave & 1) * 64;

    const int srow = t >> 2;
    const int skof = (t & 3) * 8;

    f32x4 acc[2][4];
    #pragma unroll
    for (int i = 0; i < 2; i++)
        #pragma unroll
        for (int j = 0; j < 4; j++) acc[i][j] = (f32x4){0.f, 0.f, 0.f, 0.f};

    for (int k0 = 0; k0 < E; k0 += 32) {
        gload16(A + (size_t)(m0 + srow) * E + k0 + skof,        As + t * 8);
        gload16(W + (size_t)(n0 + srow) * E + k0 + skof,        Bs + t * 8);
        gload16(W + (size_t)(n0 + 64 + srow) * E + k0 + skof,   Bs + 2048 + t * 8);
        __syncthreads();
        short8 af[2], bfr[4];
        #pragma unroll
        for (int i = 0; i < 2; i++)
            af[i] = *(const short8*)&As[(wm + i * 16 + l16) * 32 + quad * 8];
        #pragma unroll
        for (int j = 0; j < 4; j++)
            bfr[j] = *(const short8*)&Bs[(wn + j * 16 + l16) * 32 + quad * 8];
        #pragma unroll
        for (int i = 0; i < 2; i++)
            #pragma unroll
            for (int j = 0; j < 4; j++)
                acc[i][j] = __builtin_amdgcn_mfma_f32_16x16x32_bf16(af[i], bfr[j], acc[i][j], 0, 0, 0);
        __syncthreads();
    }

    #pragma unroll
    for (int i = 0; i < 2; i++) {
        const int mrow0 = m0 + wm + i * 16 + quad * 4;
        #pragma unroll
        for (int j = 0; j < 4; j++) {
            const int ncol = n0 + wn + j * 16 + l16;
            const float bval = bias[ncol];
            if (OUT_MODE == 1) {
                #pragma unroll
                for (int r = 0; r < 4; r++) {
                    size_t idx = (size_t)(mrow0 + r) * Ntot + ncol;
                    ((float*)C0)[idx] = acc[i][j][r] + bval + residf[idx];
                }
            } else {
                #pragma unroll
                for (int r = 0; r < 4; r++) {
                    size_t idx = (size_t)(mrow0 + r) * Ntot + ncol;
                    ((float*)C0)[idx] = acc[i][j][r] + bval + bf2f(residb[idx]);
                }
            }
        }
    }
}

// ---------------------------------------------------------------------------
// Fused q + kv projection GEMM (128x128 tile, 768 blocks = 3 blocks/CU).
// Measured (r9 vs r7): worth ~11.6 us over split launches. Keep 128-tile:
// at 3 blocks/CU it is in the throughput regime (m92: 64-tile ceiling lower).
// ---------------------------------------------------------------------------
__global__ __launch_bounds__(256) void gemm_qkv(
    const unsigned short* __restrict__ Aq, const unsigned short* __restrict__ Akv,
    const unsigned short* __restrict__ W,   // packed [3E][E] bf16
    const float* __restrict__ bias,         // [3E]
    unsigned short* __restrict__ qout,      // [M][512] bf16
    unsigned short* __restrict__ kout,      // [M][512] bf16
    unsigned short* __restrict__ vtout) {   // [B][512][1024] bf16
    __shared__ unsigned short As[128 * 32];
    __shared__ unsigned short Bs[128 * 32];
    const int t = threadIdx.x;
    const int wave = t >> 6, lane = t & 63;
    const int quad = lane >> 4, l16 = lane & 15;
    const bool isq = blockIdx.y < 4;
    const int yy = isq ? blockIdx.y : blockIdx.y - 4;
    const unsigned short* A  = isq ? Aq : Akv;
    const unsigned short* Wb = W + (isq ? 0 : (size_t)E * E);
    const float* bb = bias + (isq ? 0 : E);
    const int m0 = blockIdx.x * 128, n0 = yy * 128;
    const int wm = (wave >> 1) * 64, wn = (wave & 1) * 64;

    const int srow = t >> 2;
    const int skof = (t & 3) * 8;

    f32x4 acc[4][4];
    #pragma unroll
    for (int i = 0; i < 4; i++)
        #pragma unroll
        for (int j = 0; j < 4; j++) acc[i][j] = (f32x4){0.f, 0.f, 0.f, 0.f};

    for (int k0 = 0; k0 < E; k0 += 32) {
        gload16(A + (size_t)(m0 + srow) * E + k0 + skof,         As + t * 8);
        gload16(A + (size_t)(m0 + 64 + srow) * E + k0 + skof,    As + 2048 + t * 8);
        gload16(Wb + (size_t)(n0 + srow) * E + k0 + skof,        Bs + t * 8);
        gload16(Wb + (size_t)(n0 + 64 + srow) * E + k0 + skof,   Bs + 2048 + t * 8);
        __syncthreads();
        short8 af[4], bfr[4];
        #pragma unroll
        for (int i = 0; i < 4; i++)
            af[i] = *(const short8*)&As[(wm + i * 16 + l16) * 32 + quad * 8];
        #pragma unroll
        for (int j = 0; j < 4; j++)
            bfr[j] = *(const short8*)&Bs[(wn + j * 16 + l16) * 32 + quad * 8];
        #pragma unroll
        for (int i = 0; i < 4; i++)
            #pragma unroll
            for (int j = 0; j < 4; j++)
                acc[i][j] = __builtin_amdgcn_mfma_f32_16x16x32_bf16(af[i], bfr[j], acc[i][j], 0, 0, 0);
        __syncthreads();
    }

    #pragma unroll
    for (int i = 0; i < 4; i++) {
        const int mrow0 = m0 + wm + i * 16 + quad * 4;
        #pragma unroll
        for (int j = 0; j < 4; j++) {
            const int ncol = n0 + wn + j * 16 + l16;
            const float bval = bb[ncol];
            if (isq) {
                #pragma unroll
                for (int r = 0; r < 4; r++)
                    qout[(size_t)(mrow0 + r) * 512 + ncol] = f2bf(acc[i][j][r] + bval);
            } else if (ncol < 512) {
                #pragma unroll
                for (int r = 0; r < 4; r++)
                    kout[(size_t)(mrow0 + r) * 512 + ncol] = f2bf(acc[i][j][r] + bval);
            } else {
                const int nv = ncol - 512;
                const int b2 = mrow0 >> 10, s0v = mrow0 & 1023;
                ushort4 o;
                o.x = f2bf(acc[i][j][0] + bval);
                o.y = f2bf(acc[i][j][1] + bval);
                o.z = f2bf(acc[i][j][2] + bval);
                o.w = f2bf(acc[i][j][3] + bval);
                *(ushort4*)(vtout + ((size_t)b2 * 512 + nv) * 1024 + s0v) = o;
            }
        }
    }
}

// ---------------------------------------------------------------------------
// MFMA attention v5 (measured best: 92-94 us — DO NOT restructure):
// wave-private DMA staging of BOTH K and V (coalesced global_load_lds,
// XOR-swizzled LDS -> 2-way-max bank aliasing on ds_read_b128), 2-deep chunk
// prefetch gated by s_waitcnt vmcnt(N). Round-9 A/B: direct-global V loads
// (same occupancy, no spills) cost +20 us — the DMA path wins. 4 heads/block
// -> 2 bf16 aw planes. Grid = B*2*64 = 1024; 3 blocks/CU (LDS 50 KB).
// launch_bounds 2nd arg caps VGPR at ~256/arg (r5/r8): keep (256,2).
// ---------------------------------------------------------------------------
__global__ __launch_bounds__(256, 2) void attn_mfma_kernel(
    const unsigned short* __restrict__ q,   // [B][S][E] bf16
    const unsigned short* __restrict__ k,   // [B][S][E] bf16
    const unsigned short* __restrict__ vt,  // [B][E][S] bf16
    unsigned short* __restrict__ ctx,       // [B][S][E] bf16
    unsigned short* __restrict__ awp) {     // bf16 planes [2][B][S][S]
    __shared__ unsigned short s_mem[16 * 1032]; // P (16x1032) | K-staging union
    __shared__ unsigned short s_v[4 * 2048];    // V staging: 4 waves x 2 bufs x 1024
    __shared__ float s_red[2][4][16];

    const int t = threadIdx.x;
    const int wave = t >> 6, lane = t & 63;
    const int quad = lane >> 4, l16 = lane & 15;
    const int qt   = blockIdx.x & 63;
    const int rest = blockIdx.x >> 6;
    const int hg   = rest & 1;              // head group (4 heads each)
    const int b    = rest >> 1;
    const int q0   = qt * 16;
    const size_t qrow = ((size_t)(b * S + q0 + l16)) * E;

    // wave-private staging areas (shorts)
    unsigned short* karea = s_mem + wave * 4128;   // 2 bufs x 2048 (32 rows x 64)
    unsigned short* varea = s_v + wave * 2048;     // 2 bufs x 1024 (16 rows x 64)

    // DMA lane mapping: dest = base + lane*8 shorts (HW rule); XOR source swizzle
    const int dr = lane >> 3;               // row within 8-row group
    const int dc = lane & 7;                // dest 16B col-block
    const int csrc = dc ^ dr;               // swizzled source col-block
    const int sw7 = l16 & 7;                // read-side swizzle key

    f32x4 awacc[16];
    #pragma unroll
    for (int i = 0; i < 16; i++) awacc[i] = (f32x4){0.f, 0.f, 0.f, 0.f};

    #pragma clang loop unroll(disable)
    for (int hh = 0; hh < 4; hh++) {
        const int h = hg * 4 + hh;

        // K chunk c (32 rows of wave's k-range) -> buf
        auto stage_k = [&](int c, int buf) {
            const unsigned short* src =
                k + ((size_t)(b * S + wave * 256 + c * 32 + dr)) * E + h * 64 + csrc * 8;
            unsigned short* dst = karea + buf * 2048 + dr * 64 + dc * 8;
            gload16(src,                  dst);
            gload16(src + (size_t)8 * E,  dst + 512);
            gload16(src + (size_t)16 * E, dst + 1024);
            gload16(src + (size_t)24 * E, dst + 1536);
        };
        // V chunk cv (64 s-cols of wave's 16 d-rows) -> buf
        auto stage_v = [&](int cv, int buf) {
            const unsigned short* src =
                vt + ((size_t)(b * E + h * 64 + wave * 16 + dr)) * S + cv * 64 + csrc * 8;
            unsigned short* dst = varea + buf * 1024 + dr * 64 + dc * 8;
            gload16(src,                 dst);
            gload16(src + (size_t)8 * S, dst + 512);
        };

        short8 aq0 = *(const short8*)(q + qrow + h * 64 + quad * 8);
        short8 aq1 = *(const short8*)(q + qrow + h * 64 + 32 + quad * 8);

        // ---- scores: 8 staged K chunks, 2-deep prefetch ----
        f32x4 sacc[16];
        stage_k(0, 0);
        stage_k(1, 1);
        #pragma unroll
        for (int c = 0; c < 8; c++) {
            if (c < 7) waitvm<4>(); else waitvm<0>();
            const unsigned short* kbuf = karea + (c & 1) * 2048;
            #pragma unroll
            for (int ntl = 0; ntl < 2; ntl++) {
                const int rl = ntl * 16 + l16;
                short8 kf0 = *(const short8*)(kbuf + rl * 64 + ((quad)     ^ sw7) * 8);
                short8 kf1 = *(const short8*)(kbuf + rl * 64 + ((4 + quad) ^ sw7) * 8);
                f32x4 cc = (f32x4){0.f, 0.f, 0.f, 0.f};
                cc = __builtin_amdgcn_mfma_f32_16x16x32_bf16(aq0, kf0, cc, 0, 0, 0);
                cc = __builtin_amdgcn_mfma_f32_16x16x32_bf16(aq1, kf1, cc, 0, 0, 0);
                sacc[c * 2 + ntl] = cc * 0.125f;
            }
            if (c < 6) stage_k(c + 2, c & 1);
        }

        // ---- merged single-pass softmax: local max+exp+sum pre-barrier ----
        float lm[4], ls[4];
        #pragma unroll
        for (int r = 0; r < 4; r++) {
            float mv = sacc[0][r];
            #pragma unroll
            for (int nt = 1; nt < 16; nt++) mv = fmaxf(mv, sacc[nt][r]);
            #pragma unroll
            for (int o = 1; o < 16; o <<= 1) mv = fmaxf(mv, __shfl_xor(mv, o));
            lm[r] = mv;
            ls[r] = 0.f;
        }
        #pragma unroll
        for (int nt = 0; nt < 16; nt++)
            #pragma unroll
            for (int r = 0; r < 4; r++) {
                float e = __expf(sacc[nt][r] - lm[r]);
                sacc[nt][r] = e;
                ls[r] += e;
            }
        #pragma unroll
        for (int r = 0; r < 4; r++) {
            #pragma unroll
            for (int o = 1; o < 16; o <<= 1) ls[r] += __shfl_xor(ls[r], o);
        }
        if (l16 == 0) {
            #pragma unroll
            for (int r = 0; r < 4; r++) {
                s_red[0][wave][quad * 4 + r] = lm[r];
                s_red[1][wave][quad * 4 + r] = ls[r];
            }
        }
        __syncthreads();                                   // (B1) also: all K reads done
        float scale[4];
        #pragma unroll
        for (int r = 0; r < 4; r++) {
            const int row = quad * 4 + r;
            float m0 = s_red[0][0][row], m1 = s_red[0][1][row];
            float m2 = s_red[0][2][row], m3 = s_red[0][3][row];
            float gmax = fmaxf(fmaxf(m0, m1), fmaxf(m2, m3));
            float gsum = s_red[1][0][row] * __expf(m0 - gmax)
                       + s_red[1][1][row] * __expf(m1 - gmax)
                       + s_red[1][2][row] * __expf(m2 - gmax)
                       + s_red[1][3][row] * __expf(m3 - gmax);
            scale[r] = __expf(lm[r] - gmax) / gsum;
        }

        // ---- normalize, accumulate aw, write P (bf16) into s_mem [16][1032] ----
        #pragma unroll
        for (int nt = 0; nt < 16; nt++) {
            #pragma unroll
            for (int r = 0; r < 4; r++) {
                float p = sacc[nt][r] * scale[r];
                awacc[nt][r] += p;
                s_mem[(quad * 4 + r) * 1032 + wave * 256 + nt * 16 + l16] = f2bf(p);
            }
        }
        __syncthreads();                                   // (B2) P visible

        // ---- PV: 16 staged V chunks, 2-deep prefetch; P from s_mem ----
        f32x4 cacc0 = (f32x4){0.f, 0.f, 0.f, 0.f};
        f32x4 cacc1 = (f32x4){0.f, 0.f, 0.f, 0.f};
        stage_v(0, 0);
        stage_v(1, 1);
        #pragma unroll
        for (int cv = 0; cv < 16; cv++) {
            if (cv < 15) waitvm<2>(); else waitvm<0>();
            const unsigned short* vbuf = varea + (cv & 1) * 1024;
            short8 vf0 = *(const short8*)(vbuf + l16 * 64 + ((quad)     ^ sw7) * 8);
            short8 vf1 = *(const short8*)(vbuf + l16 * 64 + ((4 + quad) ^ sw7) * 8);
            short8 pf0 = *(const short8*)(s_mem + l16 * 1032 + cv * 64 + quad * 8);
            short8 pf1 = *(const short8*)(s_mem + l16 * 1032 + cv * 64 + 32 + quad * 8);
            cacc0 = __builtin_amdgcn_mfma_f32_16x16x32_bf16(pf0, vf0, cacc0, 0, 0, 0);
            cacc1 = __builtin_amdgcn_mfma_f32_16x16x32_bf16(pf1, vf1, cacc1, 0, 0, 0);
            if (cv < 14) stage_v(cv + 2, cv & 1);
        }
        f32x4 cacc = cacc0 + cacc1;
        unsigned short* crow = ctx + ((size_t)(b * S + q0)) * E + h * 64 + wave * 16 + l16;
        #pragma unroll
        for (int r = 0; r < 4; r++)
            crow[(size_t)(quad * 4 + r) * E] = f2bf(cacc[r]);
        __syncthreads();                                   // (B3) P reads done -> K restage safe
    }

    // ---- head-group partial plane (bf16) ----
    #pragma unroll
    for (int nt = 0; nt < 16; nt++) {
        #pragma unroll
        for (int r = 0; r < 4; r++)
            awp[((size_t)((hg * B + b) * S + q0 + quad * 4 + r)) * S +
                wave * 256 + nt * 16 + l16] = f2bf(awacc[nt][r]);
    }
}

// ---------------------------------------------------------------------------
// aw reduce: aw = (1/H) * sum of NP bf16 planes. 8 f32 outputs per thread.
// ---------------------------------------------------------------------------
template <int NP>
__global__ __launch_bounds__(256) void aw_reduce_kernel(
    const unsigned short* __restrict__ awp, float* __restrict__ aw) {
    const size_t PLN = (size_t)B * S * S;
    size_t idx = ((size_t)blockIdx.x * 256 + threadIdx.x) * 8;
    float acc[8] = {};
    #pragma unroll
    for (int p = 0; p < NP; p++) {
        short8 v = *(const short8*)(awp + p * PLN + idx);
        #pragma unroll
        for (int j = 0; j < 8; j++) acc[j] += bf2f((unsigned short)v[j]);
    }
    float4 o0 = make_float4(acc[0] * (1.0f / H), acc[1] * (1.0f / H),
                            acc[2] * (1.0f / H), acc[3] * (1.0f / H));
    float4 o1 = make_float4(acc[4] * (1.0f / H), acc[5] * (1.0f / H),
                            acc[6] * (1.0f / H), acc[7] * (1.0f / H));
    *(float4*)(aw + idx) = o0;
    *(float4*)(aw + idx + 4) = o1;
}

// ---------------------------------------------------------------------------
extern "C" void kernel_launch(void* const* d_in, const int* in_sizes, int n_in,
                              void* d_out, int out_size, void* d_ws, size_t ws_size,
                              hipStream_t stream) {
    const float* Zab  = (const float*)d_in[0];
    const float* Za   = (const float*)d_in[1];
    const float* lnw  = (const float*)d_in[2];
    const float* lnb  = (const float*)d_in[3];
    const float* Wqkv = (const float*)d_in[4];
    const float* bqkv = (const float*)d_in[5];
    const float* Wo   = (const float*)d_in[6];
    const float* bo   = (const float*)d_in[7];
    const float* Wf   = (const float*)d_in[8];
    const float* bf   = (const float*)d_in[9];

    float* out_final = (float*)d_out;
    float* out_aw    = out_final + (size_t)B * S * E;

    char* ws = (char*)d_ws;
    // Static buffers (live through attention):
    unsigned short* qb   = (unsigned short*)(ws);               // [0,8M)
    unsigned short* kb   = (unsigned short*)(ws + (8u << 20));  // [8,16M)
    unsigned short* vtb  = (unsigned short*)(ws + (16u << 20)); // [16,24M)
    unsigned short* ctxb = (unsigned short*)(ws + (24u << 20)); // [24,32M)
    // Pre-attention staging (dead once attention starts):
    unsigned short* aqb  = (unsigned short*)(ws + (32u << 20)); // [32,40M)
    unsigned short* akvb = (unsigned short*)(ws + (40u << 20)); // [40,48M)
    // awp planes: 2 x 16 MB at [32,64M) (aqb/akvb dead by attention)
    unsigned short* awp  = (unsigned short*)(ws + (32ull << 20));
    unsigned short* wbf  = (unsigned short*)(ws + (96ull << 20)); // 2.5 MB
    // Post-attention f32 buffers:
    float* xb  = (float*)(ws);                                  // [0,16M)
    float* tb  = (float*)(ws + (16u << 20));                    // [16,32M)
    unsigned short* xnb = aqb;                                  // [32,40M) after reduce

    dim3 blk(256);

    // 1. weights -> bf16 (packed: qkv | o | f)
    w2bf_kernel<<<(5 * E * E) / 1024, blk, 0, stream>>>(Wqkv, Wo, Wf, wbf);

    // 2. LN(Zab) + LN(Za) -> bf16, one launch (4096 blocks)
    ln2_bf16_kernel<<<2 * M / 4, blk, 0, stream>>>(Zab, Za, lnw, lnb, aqb, akvb);

    // 3. fused q/kv projection: one launch, 768 blocks = 3 blocks/CU
    gemm_qkv<<<dim3(M / 128, 12), blk, 0, stream>>>(aqb, akvb, wbf, bqkv, qb, kb, vtb);

    // 4. attention (staged K/V, 4 heads/block) -> ctx + 2 planes; reduce
    attn_mfma_kernel<<<B * 2 * 64, blk, 0, stream>>>(qb, kb, vtb, ctxb, awp);
    aw_reduce_kernel<2><<<4096, blk, 0, stream>>>(awp, out_aw);

    // 5. x = ctx@Wo^T + bo + Zab (f32) — 64-tile, 512 blocks = 2/CU
    gemm_mfma64<1><<<dim3(M / 64, 4), blk, 0, stream>>>(ctxb, wbf + (size_t)3*E*E, bo, Zab, nullptr, xb, 512);

    // 6. xn = LN(x) -> bf16
    ln_bf16_kernel<<<M / 4, blk, 0, stream>>>(xb, lnw, lnb, xnb);

    // 7. t = xn@Wf^T + bf + xn (f32) — 64-tile, 512 blocks = 2/CU
    gemm_mfma64<2><<<dim3(M / 64, 4), blk, 0, stream>>>(xnb, wbf + (size_t)4*E*E, bf, nullptr, xnb, tb, 512);

    // 8. final = LN(t)
    ln_full_kernel<<<M / 4, blk, 0, stream>>>(tb, lnw, lnb, out_final);
}

// Round 12
// 255.563 us; speedup vs baseline: 1.3523x; 1.0353x over previous
//
#include <hip/hip_runtime.h>
#include <math.h>

#define EPS 1e-5f

constexpr int B = 8, S = 1024, E = 512, H = 8;
constexpr int M = B * S;          // 8192 rows

typedef __attribute__((ext_vector_type(8))) short short8;  // 8 bf16 (4 VGPRs)
typedef __attribute__((ext_vector_type(4))) float f32x4;

// fp32 -> bf16 bits, round-to-nearest-even
static __device__ __forceinline__ unsigned short f2bf(float f) {
    unsigned int x = __float_as_uint(f);
    x += 0x7FFFu + ((x >> 16) & 1u);
    return (unsigned short)(x >> 16);
}
static __device__ __forceinline__ float bf2f(unsigned short u) {
    return __uint_as_float(((unsigned int)u) << 16);
}

// async global->LDS, 16B per lane (global_load_lds_dwordx4)
typedef __attribute__((address_space(3))) unsigned int  lds_uint;
typedef __attribute__((address_space(1))) unsigned int  glb_uint;
static __device__ __forceinline__ void gload16(const unsigned short* g, unsigned short* l) {
    __builtin_amdgcn_global_load_lds((const glb_uint*)g, (lds_uint*)l, 16, 0, 0);
}
// s_waitcnt vmcnt(N) only (lgkm=15, exp=7 untouched). m135: in-order drain.
template <int N>
static __device__ __forceinline__ void waitvm() {
    __builtin_amdgcn_s_waitcnt(0x0F70 | N);
}

// ---------------------------------------------------------------------------
// Fused prep: blocks [0,1280) convert weights f32->bf16 (packed qkv|o|f);
// blocks [1280,5376) LN both inputs -> bf16 (rows [0,M)->o0, [M,2M)->o1).
// Independent roles, one launch (saves a launch gap; fills the GPU).
// ---------------------------------------------------------------------------
__global__ __launch_bounds__(256) void prep_kernel(
    const float* __restrict__ wqkv, const float* __restrict__ wo,
    const float* __restrict__ wf, unsigned short* __restrict__ wout,
    const float* __restrict__ x0, const float* __restrict__ x1,
    const float* __restrict__ w, const float* __restrict__ bb,
    unsigned short* __restrict__ o0, unsigned short* __restrict__ o1) {
    const int bid = blockIdx.x;
    if (bid < 1280) {
        int base = (bid * 256 + threadIdx.x) * 4;
        float4 v;
        if (base < 3 * E * E)           v = *(const float4*)(wqkv + base);
        else if (base < 4 * E * E)      v = *(const float4*)(wo + (base - 3 * E * E));
        else                            v = *(const float4*)(wf + (base - 4 * E * E));
        ushort4 o;
        o.x = f2bf(v.x); o.y = f2bf(v.y); o.z = f2bf(v.z); o.w = f2bf(v.w);
        *(ushort4*)(wout + base) = o;
        return;
    }
    int row = (bid - 1280) * 4 + (threadIdx.x >> 6);
    int lane = threadIdx.x & 63;
    const float* x = row < M ? x0 : x1;
    unsigned short* out = row < M ? o0 : o1;
    int r = row < M ? row : row - M;
    const float* xr = x + (size_t)r * E + lane * 8;
    float4 v0 = *(const float4*)xr;
    float4 v1 = *(const float4*)(xr + 4);
    float vv[8] = {v0.x, v0.y, v0.z, v0.w, v1.x, v1.y, v1.z, v1.w};
    float s = 0.f;
    #pragma unroll
    for (int i = 0; i < 8; i++) s += vv[i];
    #pragma unroll
    for (int o = 1; o < 64; o <<= 1) s += __shfl_xor(s, o);
    float mu = s * (1.0f / E);
    float qs = 0.f;
    #pragma unroll
    for (int i = 0; i < 8; i++) { float d = vv[i] - mu; qs += d * d; }
    #pragma unroll
    for (int o = 1; o < 64; o <<= 1) qs += __shfl_xor(qs, o);
    float rs = rsqrtf(qs * (1.0f / E) + EPS);
    float4 w0 = *(const float4*)(w + lane * 8), w1 = *(const float4*)(w + lane * 8 + 4);
    float4 b0 = *(const float4*)(bb + lane * 8), b1 = *(const float4*)(bb + lane * 8 + 4);
    float ww[8] = {w0.x, w0.y, w0.z, w0.w, w1.x, w1.y, w1.z, w1.w};
    float bv[8] = {b0.x, b0.y, b0.z, b0.w, b1.x, b1.y, b1.z, b1.w};
    short8 o8;
    #pragma unroll
    for (int i = 0; i < 8; i++) o8[i] = (short)f2bf((vv[i] - mu) * rs * ww[i] + bv[i]);
    *(short8*)(out + (size_t)r * E + lane * 8) = o8;
}

// ---------------------------------------------------------------------------
// LN -> bf16: one wave per row (single input; used post-attention).
// ---------------------------------------------------------------------------
__global__ __launch_bounds__(256) void ln_bf16_kernel(
    const float* __restrict__ x, const float* __restrict__ w,
    const float* __restrict__ bb, unsigned short* __restrict__ out) {
    int row = blockIdx.x * 4 + (threadIdx.x >> 6);
    int lane = threadIdx.x & 63;
    const float* xr = x + (size_t)row * E + lane * 8;
    float4 v0 = *(const float4*)xr;
    float4 v1 = *(const float4*)(xr + 4);
    float vv[8] = {v0.x, v0.y, v0.z, v0.w, v1.x, v1.y, v1.z, v1.w};
    float s = 0.f;
    #pragma unroll
    for (int i = 0; i < 8; i++) s += vv[i];
    #pragma unroll
    for (int o = 1; o < 64; o <<= 1) s += __shfl_xor(s, o);
    float mu = s * (1.0f / E);
    float qs = 0.f;
    #pragma unroll
    for (int i = 0; i < 8; i++) { float d = vv[i] - mu; qs += d * d; }
    #pragma unroll
    for (int o = 1; o < 64; o <<= 1) qs += __shfl_xor(qs, o);
    float rs = rsqrtf(qs * (1.0f / E) + EPS);
    float4 w0 = *(const float4*)(w + lane * 8), w1 = *(const float4*)(w + lane * 8 + 4);
    float4 b0 = *(const float4*)(bb + lane * 8), b1 = *(const float4*)(bb + lane * 8 + 4);
    float ww[8] = {w0.x, w0.y, w0.z, w0.w, w1.x, w1.y, w1.z, w1.w};
    float bv[8] = {b0.x, b0.y, b0.z, b0.w, b1.x, b1.y, b1.z, b1.w};
    short8 o8;
    #pragma unroll
    for (int i = 0; i < 8; i++) o8[i] = (short)f2bf((vv[i] - mu) * rs * ww[i] + bv[i]);
    *(short8*)(out + (size_t)row * E + lane * 8) = o8;
}

// ---------------------------------------------------------------------------
// Full LN (fp32 out) for the final output — wave-per-row.
// ---------------------------------------------------------------------------
__global__ __launch_bounds__(256) void ln_full_kernel(
    const float* __restrict__ x, const float* __restrict__ w,
    const float* __restrict__ bb, float* __restrict__ out) {
    int row = blockIdx.x * 4 + (threadIdx.x >> 6);
    int lane = threadIdx.x & 63;
    const float* xr = x + (size_t)row * E + lane * 8;
    float4 v0 = *(const float4*)xr;
    float4 v1 = *(const float4*)(xr + 4);
    float vv[8] = {v0.x, v0.y, v0.z, v0.w, v1.x, v1.y, v1.z, v1.w};
    float s = 0.f;
    #pragma unroll
    for (int i = 0; i < 8; i++) s += vv[i];
    #pragma unroll
    for (int o = 1; o < 64; o <<= 1) s += __shfl_xor(s, o);
    float mu = s * (1.0f / E);
    float qs = 0.f;
    #pragma unroll
    for (int i = 0; i < 8; i++) { float d = vv[i] - mu; qs += d * d; }
    #pragma unroll
    for (int o = 1; o < 64; o <<= 1) qs += __shfl_xor(qs, o);
    float rs = rsqrtf(qs * (1.0f / E) + EPS);
    float4 w0 = *(const float4*)(w + lane * 8), w1 = *(const float4*)(w + lane * 8 + 4);
    float4 b0 = *(const float4*)(bb + lane * 8), b1 = *(const float4*)(bb + lane * 8 + 4);
    float* op = out + (size_t)row * E + lane * 8;
    float4 o0, o1;
    o0.x = (vv[0] - mu) * rs * w0.x + b0.x;
    o0.y = (vv[1] - mu) * rs * w0.y + b0.y;
    o0.z = (vv[2] - mu) * rs * w0.z + b0.z;
    o0.w = (vv[3] - mu) * rs * w0.w + b0.w;
    o1.x = (vv[4] - mu) * rs * w1.x + b1.x;
    o1.y = (vv[5] - mu) * rs * w1.y + b1.y;
    o1.z = (vv[6] - mu) * rs * w1.z + b1.z;
    o1.w = (vv[7] - mu) * rs * w1.w + b1.w;
    *(float4*)op = o0;
    *(float4*)(op + 4) = o1;
}

// ---------------------------------------------------------------------------
// Fused o-proj GEMM + aw-reduce. Blocks [0,512): 64x128-tile GEMM
// x = ctx@Wo^T + bo + Zab (f32). Blocks [512,4608): aw = (1/H)*sum of 2 bf16
// planes. Both roles depend only on attention output; outputs disjoint.
// GEMM blocks first in grid -> start immediately (critical path); reduce
// blocks (BW-bound) soak the remaining CUs instead of a separate launch.
// ---------------------------------------------------------------------------
__global__ __launch_bounds__(256) void gemm_o_red(
    const unsigned short* __restrict__ A, const unsigned short* __restrict__ W,
    const float* __restrict__ bias, const float* __restrict__ residf,
    float* __restrict__ C0,
    const unsigned short* __restrict__ awp, float* __restrict__ aw) {
    __shared__ unsigned short As[64 * 32];    // 4 KB
    __shared__ unsigned short Bs[128 * 32];   // 8 KB
    const int bid = blockIdx.x;
    const int t = threadIdx.x;
    if (bid >= 512) {
        // ---- reduce role ----
        const size_t PLN = (size_t)B * S * S;
        size_t idx = ((size_t)(bid - 512) * 256 + t) * 8;
        float acc[8] = {};
        #pragma unroll
        for (int p = 0; p < 2; p++) {
            short8 v = *(const short8*)(awp + p * PLN + idx);
            #pragma unroll
            for (int j = 0; j < 8; j++) acc[j] += bf2f((unsigned short)v[j]);
        }
        float4 o0 = make_float4(acc[0] * (1.0f / H), acc[1] * (1.0f / H),
                                acc[2] * (1.0f / H), acc[3] * (1.0f / H));
        float4 o1 = make_float4(acc[4] * (1.0f / H), acc[5] * (1.0f / H),
                                acc[6] * (1.0f / H), acc[7] * (1.0f / H));
        *(float4*)(aw + idx) = o0;
        *(float4*)(aw + idx + 4) = o1;
        return;
    }
    // ---- gemm role (64x128 tile, OUT_MODE 1) ----
    const int wave = t >> 6, lane = t & 63;
    const int quad = lane >> 4, l16 = lane & 15;
    const int m0 = (bid & 127) * 64, n0 = (bid >> 7) * 128;
    const int wm = (wave >> 1) * 32, wn = (wave & 1) * 64;
    const int srow = t >> 2;
    const int skof = (t & 3) * 8;

    f32x4 acc[2][4];
    #pragma unroll
    for (int i = 0; i < 2; i++)
        #pragma unroll
        for (int j = 0; j < 4; j++) acc[i][j] = (f32x4){0.f, 0.f, 0.f, 0.f};

    for (int k0 = 0; k0 < E; k0 += 32) {
        gload16(A + (size_t)(m0 + srow) * E + k0 + skof,        As + t * 8);
        gload16(W + (size_t)(n0 + srow) * E + k0 + skof,        Bs + t * 8);
        gload16(W + (size_t)(n0 + 64 + srow) * E + k0 + skof,   Bs + 2048 + t * 8);
        __syncthreads();
        short8 af[2], bfr[4];
        #pragma unroll
        for (int i = 0; i < 2; i++)
            af[i] = *(const short8*)&As[(wm + i * 16 + l16) * 32 + quad * 8];
        #pragma unroll
        for (int j = 0; j < 4; j++)
            bfr[j] = *(const short8*)&Bs[(wn + j * 16 + l16) * 32 + quad * 8];
        #pragma unroll
        for (int i = 0; i < 2; i++)
            #pragma unroll
            for (int j = 0; j < 4; j++)
                acc[i][j] = __builtin_amdgcn_mfma_f32_16x16x32_bf16(af[i], bfr[j], acc[i][j], 0, 0, 0);
        __syncthreads();
    }

    #pragma unroll
    for (int i = 0; i < 2; i++) {
        const int mrow0 = m0 + wm + i * 16 + quad * 4;
        #pragma unroll
        for (int j = 0; j < 4; j++) {
            const int ncol = n0 + wn + j * 16 + l16;
            const float bval = bias[ncol];
            #pragma unroll
            for (int r = 0; r < 4; r++) {
                size_t idx = (size_t)(mrow0 + r) * 512 + ncol;
                C0[idx] = acc[i][j][r] + bval + residf[idx];
            }
        }
    }
}

// ---------------------------------------------------------------------------
// 64x128-tile bf16 MFMA GEMM, OUT_MODE 2: f32 + bf16 resid (ff projection).
// Grid (M/64, 4) = 512 blocks = 2 blocks/CU.
// ---------------------------------------------------------------------------
__global__ __launch_bounds__(256) void gemm_mfma64_ff(
    const unsigned short* __restrict__ A, const unsigned short* __restrict__ W,
    const float* __restrict__ bias, const unsigned short* __restrict__ residb,
    float* __restrict__ C0) {
    __shared__ unsigned short As[64 * 32];
    __shared__ unsigned short Bs[128 * 32];
    const int t = threadIdx.x;
    const int wave = t >> 6, lane = t & 63;
    const int quad = lane >> 4, l16 = lane & 15;
    const int m0 = blockIdx.x * 64, n0 = blockIdx.y * 128;
    const int wm = (wave >> 1) * 32, wn = (wave & 1) * 64;
    const int srow = t >> 2;
    const int skof = (t & 3) * 8;

    f32x4 acc[2][4];
    #pragma unroll
    for (int i = 0; i < 2; i++)
        #pragma unroll
        for (int j = 0; j < 4; j++) acc[i][j] = (f32x4){0.f, 0.f, 0.f, 0.f};

    for (int k0 = 0; k0 < E; k0 += 32) {
        gload16(A + (size_t)(m0 + srow) * E + k0 + skof,        As + t * 8);
        gload16(W + (size_t)(n0 + srow) * E + k0 + skof,        Bs + t * 8);
        gload16(W + (size_t)(n0 + 64 + srow) * E + k0 + skof,   Bs + 2048 + t * 8);
        __syncthreads();
        short8 af[2], bfr[4];
        #pragma unroll
        for (int i = 0; i < 2; i++)
            af[i] = *(const short8*)&As[(wm + i * 16 + l16) * 32 + quad * 8];
        #pragma unroll
        for (int j = 0; j < 4; j++)
            bfr[j] = *(const short8*)&Bs[(wn + j * 16 + l16) * 32 + quad * 8];
        #pragma unroll
        for (int i = 0; i < 2; i++)
            #pragma unroll
            for (int j = 0; j < 4; j++)
                acc[i][j] = __builtin_amdgcn_mfma_f32_16x16x32_bf16(af[i], bfr[j], acc[i][j], 0, 0, 0);
        __syncthreads();
    }

    #pragma unroll
    for (int i = 0; i < 2; i++) {
        const int mrow0 = m0 + wm + i * 16 + quad * 4;
        #pragma unroll
        for (int j = 0; j < 4; j++) {
            const int ncol = n0 + wn + j * 16 + l16;
            const float bval = bias[ncol];
            #pragma unroll
            for (int r = 0; r < 4; r++) {
                size_t idx = (size_t)(mrow0 + r) * 512 + ncol;
                C0[idx] = acc[i][j][r] + bval + bf2f(residb[idx]);
            }
        }
    }
}

// ---------------------------------------------------------------------------
// Fused q + kv projection GEMM (128x128 tile, 768 blocks = 3 blocks/CU).
// Measured (r9 vs r7): worth ~11.6 us over split launches.
// ---------------------------------------------------------------------------
__global__ __launch_bounds__(256) void gemm_qkv(
    const unsigned short* __restrict__ Aq, const unsigned short* __restrict__ Akv,
    const unsigned short* __restrict__ W,   // packed [3E][E] bf16
    const float* __restrict__ bias,         // [3E]
    unsigned short* __restrict__ qout,      // [M][512] bf16
    unsigned short* __restrict__ kout,      // [M][512] bf16
    unsigned short* __restrict__ vtout) {   // [B][512][1024] bf16
    __shared__ unsigned short As[128 * 32];
    __shared__ unsigned short Bs[128 * 32];
    const int t = threadIdx.x;
    const int wave = t >> 6, lane = t & 63;
    const int quad = lane >> 4, l16 = lane & 15;
    const bool isq = blockIdx.y < 4;
    const int yy = isq ? blockIdx.y : blockIdx.y - 4;
    const unsigned short* A  = isq ? Aq : Akv;
    const unsigned short* Wb = W + (isq ? 0 : (size_t)E * E);
    const float* bb = bias + (isq ? 0 : E);
    const int m0 = blockIdx.x * 128, n0 = yy * 128;
    const int wm = (wave >> 1) * 64, wn = (wave & 1) * 64;

    const int srow = t >> 2;
    const int skof = (t & 3) * 8;

    f32x4 acc[4][4];
    #pragma unroll
    for (int i = 0; i < 4; i++)
        #pragma unroll
        for (int j = 0; j < 4; j++) acc[i][j] = (f32x4){0.f, 0.f, 0.f, 0.f};

    for (int k0 = 0; k0 < E; k0 += 32) {
        gload16(A + (size_t)(m0 + srow) * E + k0 + skof,         As + t * 8);
        gload16(A + (size_t)(m0 + 64 + srow) * E + k0 + skof,    As + 2048 + t * 8);
        gload16(Wb + (size_t)(n0 + srow) * E + k0 + skof,        Bs + t * 8);
        gload16(Wb + (size_t)(n0 + 64 + srow) * E + k0 + skof,   Bs + 2048 + t * 8);
        __syncthreads();
        short8 af[4], bfr[4];
        #pragma unroll
        for (int i = 0; i < 4; i++)
            af[i] = *(const short8*)&As[(wm + i * 16 + l16) * 32 + quad * 8];
        #pragma unroll
        for (int j = 0; j < 4; j++)
            bfr[j] = *(const short8*)&Bs[(wn + j * 16 + l16) * 32 + quad * 8];
        #pragma unroll
        for (int i = 0; i < 4; i++)
            #pragma unroll
            for (int j = 0; j < 4; j++)
                acc[i][j] = __builtin_amdgcn_mfma_f32_16x16x32_bf16(af[i], bfr[j], acc[i][j], 0, 0, 0);
        __syncthreads();
    }

    #pragma unroll
    for (int i = 0; i < 4; i++) {
        const int mrow0 = m0 + wm + i * 16 + quad * 4;
        #pragma unroll
        for (int j = 0; j < 4; j++) {
            const int ncol = n0 + wn + j * 16 + l16;
            const float bval = bb[ncol];
            if (isq) {
                #pragma unroll
                for (int r = 0; r < 4; r++)
                    qout[(size_t)(mrow0 + r) * 512 + ncol] = f2bf(acc[i][j][r] + bval);
            } else if (ncol < 512) {
                #pragma unroll
                for (int r = 0; r < 4; r++)
                    kout[(size_t)(mrow0 + r) * 512 + ncol] = f2bf(acc[i][j][r] + bval);
            } else {
                const int nv = ncol - 512;
                const int b2 = mrow0 >> 10, s0v = mrow0 & 1023;
                ushort4 o;
                o.x = f2bf(acc[i][j][0] + bval);
                o.y = f2bf(acc[i][j][1] + bval);
                o.z = f2bf(acc[i][j][2] + bval);
                o.w = f2bf(acc[i][j][3] + bval);
                *(ushort4*)(vtout + ((size_t)b2 * 512 + nv) * 1024 + s0v) = o;
            }
        }
    }
}

// ---------------------------------------------------------------------------
// MFMA attention v5 (measured best: 92-94 us — DO NOT restructure):
// wave-private DMA staging of BOTH K and V (coalesced global_load_lds,
// XOR-swizzled LDS -> 2-way-max bank aliasing on ds_read_b128), 2-deep chunk
// prefetch gated by s_waitcnt vmcnt(N). Round-9 A/B: direct-global V loads
// (same occupancy, no spills) cost +20 us — the DMA path wins. 4 heads/block
// -> 2 bf16 aw planes. Grid = B*2*64 = 1024; 3 blocks/CU (LDS 50 KB).
// launch_bounds 2nd arg caps VGPR at ~256/arg (r5/r8): keep (256,2).
// ---------------------------------------------------------------------------
__global__ __launch_bounds__(256, 2) void attn_mfma_kernel(
    const unsigned short* __restrict__ q,   // [B][S][E] bf16
    const unsigned short* __restrict__ k,   // [B][S][E] bf16
    const unsigned short* __restrict__ vt,  // [B][E][S] bf16
    unsigned short* __restrict__ ctx,       // [B][S][E] bf16
    unsigned short* __restrict__ awp) {     // bf16 planes [2][B][S][S]
    __shared__ unsigned short s_mem[16 * 1032]; // P (16x1032) | K-staging union
    __shared__ unsigned short s_v[4 * 2048];    // V staging: 4 waves x 2 bufs x 1024
    __shared__ float s_red[2][4][16];

    const int t = threadIdx.x;
    const int wave = t >> 6, lane = t & 63;
    const int quad = lane >> 4, l16 = lane & 15;
    const int qt   = blockIdx.x & 63;
    const int rest = blockIdx.x >> 6;
    const int hg   = rest & 1;              // head group (4 heads each)
    const int b    = rest >> 1;
    const int q0   = qt * 16;
    const size_t qrow = ((size_t)(b * S + q0 + l16)) * E;

    // wave-private staging areas (shorts)
    unsigned short* karea = s_mem + wave * 4128;   // 2 bufs x 2048 (32 rows x 64)
    unsigned short* varea = s_v + wave * 2048;     // 2 bufs x 1024 (16 rows x 64)

    // DMA lane mapping: dest = base + lane*8 shorts (HW rule); XOR source swizzle
    const int dr = lane >> 3;               // row within 8-row group
    const int dc = lane & 7;                // dest 16B col-block
    const int csrc = dc ^ dr;               // swizzled source col-block
    const int sw7 = l16 & 7;                // read-side swizzle key

    f32x4 awacc[16];
    #pragma unroll
    for (int i = 0; i < 16; i++) awacc[i] = (f32x4){0.f, 0.f, 0.f, 0.f};

    #pragma clang loop unroll(disable)
    for (int hh = 0; hh < 4; hh++) {
        const int h = hg * 4 + hh;

        // K chunk c (32 rows of wave's k-range) -> buf
        auto stage_k = [&](int c, int buf) {
            const unsigned short* src =
                k + ((size_t)(b * S + wave * 256 + c * 32 + dr)) * E + h * 64 + csrc * 8;
            unsigned short* dst = karea + buf * 2048 + dr * 64 + dc * 8;
            gload16(src,                  dst);
            gload16(src + (size_t)8 * E,  dst + 512);
            gload16(src + (size_t)16 * E, dst + 1024);
            gload16(src + (size_t)24 * E, dst + 1536);
        };
        // V chunk cv (64 s-cols of wave's 16 d-rows) -> buf
        auto stage_v = [&](int cv, int buf) {
            const unsigned short* src =
                vt + ((size_t)(b * E + h * 64 + wave * 16 + dr)) * S + cv * 64 + csrc * 8;
            unsigned short* dst = varea + buf * 1024 + dr * 64 + dc * 8;
            gload16(src,                 dst);
            gload16(src + (size_t)8 * S, dst + 512);
        };

        short8 aq0 = *(const short8*)(q + qrow + h * 64 + quad * 8);
        short8 aq1 = *(const short8*)(q + qrow + h * 64 + 32 + quad * 8);

        // ---- scores: 8 staged K chunks, 2-deep prefetch ----
        f32x4 sacc[16];
        stage_k(0, 0);
        stage_k(1, 1);
        #pragma unroll
        for (int c = 0; c < 8; c++) {
            if (c < 7) waitvm<4>(); else waitvm<0>();
            const unsigned short* kbuf = karea + (c & 1) * 2048;
            #pragma unroll
            for (int ntl = 0; ntl < 2; ntl++) {
                const int rl = ntl * 16 + l16;
                short8 kf0 = *(const short8*)(kbuf + rl * 64 + ((quad)     ^ sw7) * 8);
                short8 kf1 = *(const short8*)(kbuf + rl * 64 + ((4 + quad) ^ sw7) * 8);
                f32x4 cc = (f32x4){0.f, 0.f, 0.f, 0.f};
                cc = __builtin_amdgcn_mfma_f32_16x16x32_bf16(aq0, kf0, cc, 0, 0, 0);
                cc = __builtin_amdgcn_mfma_f32_16x16x32_bf16(aq1, kf1, cc, 0, 0, 0);
                sacc[c * 2 + ntl] = cc * 0.125f;
            }
            if (c < 6) stage_k(c + 2, c & 1);
        }

        // ---- merged single-pass softmax: local max+exp+sum pre-barrier ----
        float lm[4], ls[4];
        #pragma unroll
        for (int r = 0; r < 4; r++) {
            float mv = sacc[0][r];
            #pragma unroll
            for (int nt = 1; nt < 16; nt++) mv = fmaxf(mv, sacc[nt][r]);
            #pragma unroll
            for (int o = 1; o < 16; o <<= 1) mv = fmaxf(mv, __shfl_xor(mv, o));
            lm[r] = mv;
            ls[r] = 0.f;
        }
        #pragma unroll
        for (int nt = 0; nt < 16; nt++)
            #pragma unroll
            for (int r = 0; r < 4; r++) {
                float e = __expf(sacc[nt][r] - lm[r]);
                sacc[nt][r] = e;
                ls[r] += e;
            }
        #pragma unroll
        for (int r = 0; r < 4; r++) {
            #pragma unroll
            for (int o = 1; o < 16; o <<= 1) ls[r] += __shfl_xor(ls[r], o);
        }
        if (l16 == 0) {
            #pragma unroll
            for (int r = 0; r < 4; r++) {
                s_red[0][wave][quad * 4 + r] = lm[r];
                s_red[1][wave][quad * 4 + r] = ls[r];
            }
        }
        __syncthreads();                                   // (B1) also: all K reads done
        float scale[4];
        #pragma unroll
        for (int r = 0; r < 4; r++) {
            const int row = quad * 4 + r;
            float m0 = s_red[0][0][row], m1 = s_red[0][1][row];
            float m2 = s_red[0][2][row], m3 = s_red[0][3][row];
            float gmax = fmaxf(fmaxf(m0, m1), fmaxf(m2, m3));
            float gsum = s_red[1][0][row] * __expf(m0 - gmax)
                       + s_red[1][1][row] * __expf(m1 - gmax)
                       + s_red[1][2][row] * __expf(m2 - gmax)
                       + s_red[1][3][row] * __expf(m3 - gmax);
            scale[r] = __expf(lm[r] - gmax) / gsum;
        }

        // ---- normalize, accumulate aw, write P (bf16) into s_mem [16][1032] ----
        #pragma unroll
        for (int nt = 0; nt < 16; nt++) {
            #pragma unroll
            for (int r = 0; r < 4; r++) {
                float p = sacc[nt][r] * scale[r];
                awacc[nt][r] += p;
                s_mem[(quad * 4 + r) * 1032 + wave * 256 + nt * 16 + l16] = f2bf(p);
            }
        }
        __syncthreads();                                   // (B2) P visible

        // ---- PV: 16 staged V chunks, 2-deep prefetch; P from s_mem ----
        f32x4 cacc0 = (f32x4){0.f, 0.f, 0.f, 0.f};
        f32x4 cacc1 = (f32x4){0.f, 0.f, 0.f, 0.f};
        stage_v(0, 0);
        stage_v(1, 1);
        #pragma unroll
        for (int cv = 0; cv < 16; cv++) {
            if (cv < 15) waitvm<2>(); else waitvm<0>();
            const unsigned short* vbuf = varea + (cv & 1) * 1024;
            short8 vf0 = *(const short8*)(vbuf + l16 * 64 + ((quad)     ^ sw7) * 8);
            short8 vf1 = *(const short8*)(vbuf + l16 * 64 + ((4 + quad) ^ sw7) * 8);
            short8 pf0 = *(const short8*)(s_mem + l16 * 1032 + cv * 64 + quad * 8);
            short8 pf1 = *(const short8*)(s_mem + l16 * 1032 + cv * 64 + 32 + quad * 8);
            cacc0 = __builtin_amdgcn_mfma_f32_16x16x32_bf16(pf0, vf0, cacc0, 0, 0, 0);
            cacc1 = __builtin_amdgcn_mfma_f32_16x16x32_bf16(pf1, vf1, cacc1, 0, 0, 0);
            if (cv < 14) stage_v(cv + 2, cv & 1);
        }
        f32x4 cacc = cacc0 + cacc1;
        unsigned short* crow = ctx + ((size_t)(b * S + q0)) * E + h * 64 + wave * 16 + l16;
        #pragma unroll
        for (int r = 0; r < 4; r++)
            crow[(size_t)(quad * 4 + r) * E] = f2bf(cacc[r]);
        __syncthreads();                                   // (B3) P reads done -> K restage safe
    }

    // ---- head-group partial plane (bf16) ----
    #pragma unroll
    for (int nt = 0; nt < 16; nt++) {
        #pragma unroll
        for (int r = 0; r < 4; r++)
            awp[((size_t)((hg * B + b) * S + q0 + quad * 4 + r)) * S +
                wave * 256 + nt * 16 + l16] = f2bf(awacc[nt][r]);
    }
}

// ---------------------------------------------------------------------------
extern "C" void kernel_launch(void* const* d_in, const int* in_sizes, int n_in,
                              void* d_out, int out_size, void* d_ws, size_t ws_size,
                              hipStream_t stream) {
    const float* Zab  = (const float*)d_in[0];
    const float* Za   = (const float*)d_in[1];
    const float* lnw  = (const float*)d_in[2];
    const float* lnb  = (const float*)d_in[3];
    const float* Wqkv = (const float*)d_in[4];
    const float* bqkv = (const float*)d_in[5];
    const float* Wo   = (const float*)d_in[6];
    const float* bo   = (const float*)d_in[7];
    const float* Wf   = (const float*)d_in[8];
    const float* bf   = (const float*)d_in[9];

    float* out_final = (float*)d_out;
    float* out_aw    = out_final + (size_t)B * S * E;

    char* ws = (char*)d_ws;
    // Static buffers (live through attention):
    unsigned short* qb   = (unsigned short*)(ws);               // [0,8M)
    unsigned short* kb   = (unsigned short*)(ws + (8u << 20));  // [8,16M)
    unsigned short* vtb  = (unsigned short*)(ws + (16u << 20)); // [16,24M)
    unsigned short* ctxb = (unsigned short*)(ws + (24u << 20)); // [24,32M)
    // Pre-attention staging (dead once attention starts):
    unsigned short* aqb  = (unsigned short*)(ws + (32u << 20)); // [32,40M)
    unsigned short* akvb = (unsigned short*)(ws + (40u << 20)); // [40,48M)
    // awp planes: 2 x 16 MB at [32,64M) (aqb/akvb dead by attention)
    unsigned short* awp  = (unsigned short*)(ws + (32ull << 20));
    unsigned short* wbf  = (unsigned short*)(ws + (96ull << 20)); // 2.5 MB
    // Post-attention f32 buffers:
    float* xb  = (float*)(ws);                                  // [0,16M)
    float* tb  = (float*)(ws + (16u << 20));                    // [16,32M)
    unsigned short* xnb = aqb;                                  // [32,40M) after reduce

    dim3 blk(256);

    // 1+2. weights -> bf16 AND LN(Zab)+LN(Za) -> bf16, one launch
    prep_kernel<<<1280 + 4096, blk, 0, stream>>>(Wqkv, Wo, Wf, wbf,
                                                 Zab, Za, lnw, lnb, aqb, akvb);

    // 3. fused q/kv projection: one launch, 768 blocks = 3 blocks/CU
    gemm_qkv<<<dim3(M / 128, 12), blk, 0, stream>>>(aqb, akvb, wbf, bqkv, qb, kb, vtb);

    // 4. attention (staged K/V, 4 heads/block) -> ctx + 2 planes
    attn_mfma_kernel<<<B * 2 * 64, blk, 0, stream>>>(qb, kb, vtb, ctxb, awp);

    // 5. fused: x = ctx@Wo^T + bo + Zab (512 gemm blocks) ∥ aw reduce (4096)
    gemm_o_red<<<512 + 4096, blk, 0, stream>>>(ctxb, wbf + (size_t)3*E*E, bo,
                                               Zab, xb, awp, out_aw);

    // 6. xn = LN(x) -> bf16
    ln_bf16_kernel<<<M / 4, blk, 0, stream>>>(xb, lnw, lnb, xnb);

    // 7. t = xn@Wf^T + bf + xn (f32) — 64-tile, 512 blocks = 2/CU
    gemm_mfma64_ff<<<dim3(M / 64, 4), blk, 0, stream>>>(xnb, wbf + (size_t)4*E*E, bf, xnb, tb);

    // 8. final = LN(t)
    ln_full_kernel<<<M / 4, blk, 0, stream>>>(tb, lnw, lnb, out_final);
}

// Round 13
// 253.389 us; speedup vs baseline: 1.3639x; 1.0086x over previous
//
#include <hip/hip_runtime.h>
#include <math.h>

#define EPS 1e-5f

constexpr int B = 8, S = 1024, E = 512, H = 8;
constexpr int M = B * S;          // 8192 rows

typedef __attribute__((ext_vector_type(8))) short short8;  // 8 bf16 (4 VGPRs)
typedef __attribute__((ext_vector_type(4))) float f32x4;

// fp32 -> bf16 bits, round-to-nearest-even
static __device__ __forceinline__ unsigned short f2bf(float f) {
    unsigned int x = __float_as_uint(f);
    x += 0x7FFFu + ((x >> 16) & 1u);
    return (unsigned short)(x >> 16);
}
static __device__ __forceinline__ float bf2f(unsigned short u) {
    return __uint_as_float(((unsigned int)u) << 16);
}

// async global->LDS, 16B per lane (global_load_lds_dwordx4)
typedef __attribute__((address_space(3))) unsigned int  lds_uint;
typedef __attribute__((address_space(1))) unsigned int  glb_uint;
static __device__ __forceinline__ void gload16(const unsigned short* g, unsigned short* l) {
    __builtin_amdgcn_global_load_lds((const glb_uint*)g, (lds_uint*)l, 16, 0, 0);
}
// s_waitcnt vmcnt(N) only (lgkm=15, exp=7 untouched). m135: in-order drain.
template <int N>
static __device__ __forceinline__ void waitvm() {
    __builtin_amdgcn_s_waitcnt(0x0F70 | N);
}

// ---------------------------------------------------------------------------
// Fused prep: blocks [0,1280) convert weights f32->bf16 (packed qkv|o|f);
// blocks [1280,5376) LN both inputs -> bf16 (rows [0,M)->o0, [M,2M)->o1).
// ---------------------------------------------------------------------------
__global__ __launch_bounds__(256) void prep_kernel(
    const float* __restrict__ wqkv, const float* __restrict__ wo,
    const float* __restrict__ wf, unsigned short* __restrict__ wout,
    const float* __restrict__ x0, const float* __restrict__ x1,
    const float* __restrict__ w, const float* __restrict__ bb,
    unsigned short* __restrict__ o0, unsigned short* __restrict__ o1) {
    const int bid = blockIdx.x;
    if (bid < 1280) {
        int base = (bid * 256 + threadIdx.x) * 4;
        float4 v;
        if (base < 3 * E * E)           v = *(const float4*)(wqkv + base);
        else if (base < 4 * E * E)      v = *(const float4*)(wo + (base - 3 * E * E));
        else                            v = *(const float4*)(wf + (base - 4 * E * E));
        ushort4 o;
        o.x = f2bf(v.x); o.y = f2bf(v.y); o.z = f2bf(v.z); o.w = f2bf(v.w);
        *(ushort4*)(wout + base) = o;
        return;
    }
    int row = (bid - 1280) * 4 + (threadIdx.x >> 6);
    int lane = threadIdx.x & 63;
    const float* x = row < M ? x0 : x1;
    unsigned short* out = row < M ? o0 : o1;
    int r = row < M ? row : row - M;
    const float* xr = x + (size_t)r * E + lane * 8;
    float4 v0 = *(const float4*)xr;
    float4 v1 = *(const float4*)(xr + 4);
    float vv[8] = {v0.x, v0.y, v0.z, v0.w, v1.x, v1.y, v1.z, v1.w};
    float s = 0.f;
    #pragma unroll
    for (int i = 0; i < 8; i++) s += vv[i];
    #pragma unroll
    for (int o = 1; o < 64; o <<= 1) s += __shfl_xor(s, o);
    float mu = s * (1.0f / E);
    float qs = 0.f;
    #pragma unroll
    for (int i = 0; i < 8; i++) { float d = vv[i] - mu; qs += d * d; }
    #pragma unroll
    for (int o = 1; o < 64; o <<= 1) qs += __shfl_xor(qs, o);
    float rs = rsqrtf(qs * (1.0f / E) + EPS);
    float4 w0 = *(const float4*)(w + lane * 8), w1 = *(const float4*)(w + lane * 8 + 4);
    float4 b0 = *(const float4*)(bb + lane * 8), b1 = *(const float4*)(bb + lane * 8 + 4);
    float ww[8] = {w0.x, w0.y, w0.z, w0.w, w1.x, w1.y, w1.z, w1.w};
    float bv[8] = {b0.x, b0.y, b0.z, b0.w, b1.x, b1.y, b1.z, b1.w};
    short8 o8;
    #pragma unroll
    for (int i = 0; i < 8; i++) o8[i] = (short)f2bf((vv[i] - mu) * rs * ww[i] + bv[i]);
    *(short8*)(out + (size_t)r * E + lane * 8) = o8;
}

// ---------------------------------------------------------------------------
// LN -> bf16: one wave per row (single input; used post-attention).
// ---------------------------------------------------------------------------
__global__ __launch_bounds__(256) void ln_bf16_kernel(
    const float* __restrict__ x, const float* __restrict__ w,
    const float* __restrict__ bb, unsigned short* __restrict__ out) {
    int row = blockIdx.x * 4 + (threadIdx.x >> 6);
    int lane = threadIdx.x & 63;
    const float* xr = x + (size_t)row * E + lane * 8;
    float4 v0 = *(const float4*)xr;
    float4 v1 = *(const float4*)(xr + 4);
    float vv[8] = {v0.x, v0.y, v0.z, v0.w, v1.x, v1.y, v1.z, v1.w};
    float s = 0.f;
    #pragma unroll
    for (int i = 0; i < 8; i++) s += vv[i];
    #pragma unroll
    for (int o = 1; o < 64; o <<= 1) s += __shfl_xor(s, o);
    float mu = s * (1.0f / E);
    float qs = 0.f;
    #pragma unroll
    for (int i = 0; i < 8; i++) { float d = vv[i] - mu; qs += d * d; }
    #pragma unroll
    for (int o = 1; o < 64; o <<= 1) qs += __shfl_xor(qs, o);
    float rs = rsqrtf(qs * (1.0f / E) + EPS);
    float4 w0 = *(const float4*)(w + lane * 8), w1 = *(const float4*)(w + lane * 8 + 4);
    float4 b0 = *(const float4*)(bb + lane * 8), b1 = *(const float4*)(bb + lane * 8 + 4);
    float ww[8] = {w0.x, w0.y, w0.z, w0.w, w1.x, w1.y, w1.z, w1.w};
    float bv[8] = {b0.x, b0.y, b0.z, b0.w, b1.x, b1.y, b1.z, b1.w};
    short8 o8;
    #pragma unroll
    for (int i = 0; i < 8; i++) o8[i] = (short)f2bf((vv[i] - mu) * rs * ww[i] + bv[i]);
    *(short8*)(out + (size_t)row * E + lane * 8) = o8;
}

// ---------------------------------------------------------------------------
// Full LN (fp32 out) for the final output — wave-per-row.
// ---------------------------------------------------------------------------
__global__ __launch_bounds__(256) void ln_full_kernel(
    const float* __restrict__ x, const float* __restrict__ w,
    const float* __restrict__ bb, float* __restrict__ out) {
    int row = blockIdx.x * 4 + (threadIdx.x >> 6);
    int lane = threadIdx.x & 63;
    const float* xr = x + (size_t)row * E + lane * 8;
    float4 v0 = *(const float4*)xr;
    float4 v1 = *(const float4*)(xr + 4);
    float vv[8] = {v0.x, v0.y, v0.z, v0.w, v1.x, v1.y, v1.z, v1.w};
    float s = 0.f;
    #pragma unroll
    for (int i = 0; i < 8; i++) s += vv[i];
    #pragma unroll
    for (int o = 1; o < 64; o <<= 1) s += __shfl_xor(s, o);
    float mu = s * (1.0f / E);
    float qs = 0.f;
    #pragma unroll
    for (int i = 0; i < 8; i++) { float d = vv[i] - mu; qs += d * d; }
    #pragma unroll
    for (int o = 1; o < 64; o <<= 1) qs += __shfl_xor(qs, o);
    float rs = rsqrtf(qs * (1.0f / E) + EPS);
    float4 w0 = *(const float4*)(w + lane * 8), w1 = *(const float4*)(w + lane * 8 + 4);
    float4 b0 = *(const float4*)(bb + lane * 8), b1 = *(const float4*)(bb + lane * 8 + 4);
    float* op = out + (size_t)row * E + lane * 8;
    float4 o0, o1;
    o0.x = (vv[0] - mu) * rs * w0.x + b0.x;
    o0.y = (vv[1] - mu) * rs * w0.y + b0.y;
    o0.z = (vv[2] - mu) * rs * w0.z + b0.z;
    o0.w = (vv[3] - mu) * rs * w0.w + b0.w;
    o1.x = (vv[4] - mu) * rs * w1.x + b1.x;
    o1.y = (vv[5] - mu) * rs * w1.y + b1.y;
    o1.z = (vv[6] - mu) * rs * w1.z + b1.z;
    o1.w = (vv[7] - mu) * rs * w1.w + b1.w;
    *(float4*)op = o0;
    *(float4*)(op + 4) = o1;
}

// ---------------------------------------------------------------------------
// Fused o-proj GEMM + aw-reduce. Blocks [0,512): 64x128-tile GEMM
// x = ctx@Wo^T + bo + Zab (f32). Blocks [512,4608): aw = (1/H)*sum of 2 bf16
// planes. GEMM blocks first (critical path); reduce soaks remaining CUs.
// ---------------------------------------------------------------------------
__global__ __launch_bounds__(256) void gemm_o_red(
    const unsigned short* __restrict__ A, const unsigned short* __restrict__ W,
    const float* __restrict__ bias, const float* __restrict__ residf,
    float* __restrict__ C0,
    const unsigned short* __restrict__ awp, float* __restrict__ aw) {
    __shared__ unsigned short As[64 * 32];    // 4 KB
    __shared__ unsigned short Bs[128 * 32];   // 8 KB
    const int bid = blockIdx.x;
    const int t = threadIdx.x;
    if (bid >= 512) {
        // ---- reduce role ----
        const size_t PLN = (size_t)B * S * S;
        size_t idx = ((size_t)(bid - 512) * 256 + t) * 8;
        float acc[8] = {};
        #pragma unroll
        for (int p = 0; p < 2; p++) {
            short8 v = *(const short8*)(awp + p * PLN + idx);
            #pragma unroll
            for (int j = 0; j < 8; j++) acc[j] += bf2f((unsigned short)v[j]);
        }
        float4 o0 = make_float4(acc[0] * (1.0f / H), acc[1] * (1.0f / H),
                                acc[2] * (1.0f / H), acc[3] * (1.0f / H));
        float4 o1 = make_float4(acc[4] * (1.0f / H), acc[5] * (1.0f / H),
                                acc[6] * (1.0f / H), acc[7] * (1.0f / H));
        *(float4*)(aw + idx) = o0;
        *(float4*)(aw + idx + 4) = o1;
        return;
    }
    // ---- gemm role (64x128 tile, OUT_MODE 1) ----
    const int wave = t >> 6, lane = t & 63;
    const int quad = lane >> 4, l16 = lane & 15;
    const int m0 = (bid & 127) * 64, n0 = (bid >> 7) * 128;
    const int wm = (wave >> 1) * 32, wn = (wave & 1) * 64;
    const int srow = t >> 2;
    const int skof = (t & 3) * 8;

    f32x4 acc[2][4];
    #pragma unroll
    for (int i = 0; i < 2; i++)
        #pragma unroll
        for (int j = 0; j < 4; j++) acc[i][j] = (f32x4){0.f, 0.f, 0.f, 0.f};

    for (int k0 = 0; k0 < E; k0 += 32) {
        gload16(A + (size_t)(m0 + srow) * E + k0 + skof,        As + t * 8);
        gload16(W + (size_t)(n0 + srow) * E + k0 + skof,        Bs + t * 8);
        gload16(W + (size_t)(n0 + 64 + srow) * E + k0 + skof,   Bs + 2048 + t * 8);
        __syncthreads();
        short8 af[2], bfr[4];
        #pragma unroll
        for (int i = 0; i < 2; i++)
            af[i] = *(const short8*)&As[(wm + i * 16 + l16) * 32 + quad * 8];
        #pragma unroll
        for (int j = 0; j < 4; j++)
            bfr[j] = *(const short8*)&Bs[(wn + j * 16 + l16) * 32 + quad * 8];
        #pragma unroll
        for (int i = 0; i < 2; i++)
            #pragma unroll
            for (int j = 0; j < 4; j++)
                acc[i][j] = __builtin_amdgcn_mfma_f32_16x16x32_bf16(af[i], bfr[j], acc[i][j], 0, 0, 0);
        __syncthreads();
    }

    #pragma unroll
    for (int i = 0; i < 2; i++) {
        const int mrow0 = m0 + wm + i * 16 + quad * 4;
        #pragma unroll
        for (int j = 0; j < 4; j++) {
            const int ncol = n0 + wn + j * 16 + l16;
            const float bval = bias[ncol];
            #pragma unroll
            for (int r = 0; r < 4; r++) {
                size_t idx = (size_t)(mrow0 + r) * 512 + ncol;
                C0[idx] = acc[i][j][r] + bval + residf[idx];
            }
        }
    }
}

// ---------------------------------------------------------------------------
// 64x128-tile bf16 MFMA GEMM, OUT_MODE 2: f32 + bf16 resid (ff projection).
// Grid (M/64, 4) = 512 blocks = 2 blocks/CU.
// ---------------------------------------------------------------------------
__global__ __launch_bounds__(256) void gemm_mfma64_ff(
    const unsigned short* __restrict__ A, const unsigned short* __restrict__ W,
    const float* __restrict__ bias, const unsigned short* __restrict__ residb,
    float* __restrict__ C0) {
    __shared__ unsigned short As[64 * 32];
    __shared__ unsigned short Bs[128 * 32];
    const int t = threadIdx.x;
    const int wave = t >> 6, lane = t & 63;
    const int quad = lane >> 4, l16 = lane & 15;
    const int m0 = blockIdx.x * 64, n0 = blockIdx.y * 128;
    const int wm = (wave >> 1) * 32, wn = (wave & 1) * 64;
    const int srow = t >> 2;
    const int skof = (t & 3) * 8;

    f32x4 acc[2][4];
    #pragma unroll
    for (int i = 0; i < 2; i++)
        #pragma unroll
        for (int j = 0; j < 4; j++) acc[i][j] = (f32x4){0.f, 0.f, 0.f, 0.f};

    for (int k0 = 0; k0 < E; k0 += 32) {
        gload16(A + (size_t)(m0 + srow) * E + k0 + skof,        As + t * 8);
        gload16(W + (size_t)(n0 + srow) * E + k0 + skof,        Bs + t * 8);
        gload16(W + (size_t)(n0 + 64 + srow) * E + k0 + skof,   Bs + 2048 + t * 8);
        __syncthreads();
        short8 af[2], bfr[4];
        #pragma unroll
        for (int i = 0; i < 2; i++)
            af[i] = *(const short8*)&As[(wm + i * 16 + l16) * 32 + quad * 8];
        #pragma unroll
        for (int j = 0; j < 4; j++)
            bfr[j] = *(const short8*)&Bs[(wn + j * 16 + l16) * 32 + quad * 8];
        #pragma unroll
        for (int i = 0; i < 2; i++)
            #pragma unroll
            for (int j = 0; j < 4; j++)
                acc[i][j] = __builtin_amdgcn_mfma_f32_16x16x32_bf16(af[i], bfr[j], acc[i][j], 0, 0, 0);
        __syncthreads();
    }

    #pragma unroll
    for (int i = 0; i < 2; i++) {
        const int mrow0 = m0 + wm + i * 16 + quad * 4;
        #pragma unroll
        for (int j = 0; j < 4; j++) {
            const int ncol = n0 + wn + j * 16 + l16;
            const float bval = bias[ncol];
            #pragma unroll
            for (int r = 0; r < 4; r++) {
                size_t idx = (size_t)(mrow0 + r) * 512 + ncol;
                C0[idx] = acc[i][j][r] + bval + bf2f(residb[idx]);
            }
        }
    }
}

// ---------------------------------------------------------------------------
// Fused q + kv projection GEMM (128x128 tile, 768 blocks = 3 blocks/CU).
// ---------------------------------------------------------------------------
__global__ __launch_bounds__(256) void gemm_qkv(
    const unsigned short* __restrict__ Aq, const unsigned short* __restrict__ Akv,
    const unsigned short* __restrict__ W,   // packed [3E][E] bf16
    const float* __restrict__ bias,         // [3E]
    unsigned short* __restrict__ qout,      // [M][512] bf16
    unsigned short* __restrict__ kout,      // [M][512] bf16
    unsigned short* __restrict__ vtout) {   // [B][512][1024] bf16
    __shared__ unsigned short As[128 * 32];
    __shared__ unsigned short Bs[128 * 32];
    const int t = threadIdx.x;
    const int wave = t >> 6, lane = t & 63;
    const int quad = lane >> 4, l16 = lane & 15;
    const bool isq = blockIdx.y < 4;
    const int yy = isq ? blockIdx.y : blockIdx.y - 4;
    const unsigned short* A  = isq ? Aq : Akv;
    const unsigned short* Wb = W + (isq ? 0 : (size_t)E * E);
    const float* bb = bias + (isq ? 0 : E);
    const int m0 = blockIdx.x * 128, n0 = yy * 128;
    const int wm = (wave >> 1) * 64, wn = (wave & 1) * 64;

    const int srow = t >> 2;
    const int skof = (t & 3) * 8;

    f32x4 acc[4][4];
    #pragma unroll
    for (int i = 0; i < 4; i++)
        #pragma unroll
        for (int j = 0; j < 4; j++) acc[i][j] = (f32x4){0.f, 0.f, 0.f, 0.f};

    for (int k0 = 0; k0 < E; k0 += 32) {
        gload16(A + (size_t)(m0 + srow) * E + k0 + skof,         As + t * 8);
        gload16(A + (size_t)(m0 + 64 + srow) * E + k0 + skof,    As + 2048 + t * 8);
        gload16(Wb + (size_t)(n0 + srow) * E + k0 + skof,        Bs + t * 8);
        gload16(Wb + (size_t)(n0 + 64 + srow) * E + k0 + skof,   Bs + 2048 + t * 8);
        __syncthreads();
        short8 af[4], bfr[4];
        #pragma unroll
        for (int i = 0; i < 4; i++)
            af[i] = *(const short8*)&As[(wm + i * 16 + l16) * 32 + quad * 8];
        #pragma unroll
        for (int j = 0; j < 4; j++)
            bfr[j] = *(const short8*)&Bs[(wn + j * 16 + l16) * 32 + quad * 8];
        #pragma unroll
        for (int i = 0; i < 4; i++)
            #pragma unroll
            for (int j = 0; j < 4; j++)
                acc[i][j] = __builtin_amdgcn_mfma_f32_16x16x32_bf16(af[i], bfr[j], acc[i][j], 0, 0, 0);
        __syncthreads();
    }

    #pragma unroll
    for (int i = 0; i < 4; i++) {
        const int mrow0 = m0 + wm + i * 16 + quad * 4;
        #pragma unroll
        for (int j = 0; j < 4; j++) {
            const int ncol = n0 + wn + j * 16 + l16;
            const float bval = bb[ncol];
            if (isq) {
                #pragma unroll
                for (int r = 0; r < 4; r++)
                    qout[(size_t)(mrow0 + r) * 512 + ncol] = f2bf(acc[i][j][r] + bval);
            } else if (ncol < 512) {
                #pragma unroll
                for (int r = 0; r < 4; r++)
                    kout[(size_t)(mrow0 + r) * 512 + ncol] = f2bf(acc[i][j][r] + bval);
            } else {
                const int nv = ncol - 512;
                const int b2 = mrow0 >> 10, s0v = mrow0 & 1023;
                ushort4 o;
                o.x = f2bf(acc[i][j][0] + bval);
                o.y = f2bf(acc[i][j][1] + bval);
                o.z = f2bf(acc[i][j][2] + bval);
                o.w = f2bf(acc[i][j][3] + bval);
                *(ushort4*)(vtout + ((size_t)b2 * 512 + nv) * 1024 + s0v) = o;
            }
        }
    }
}

// ---------------------------------------------------------------------------
// MFMA attention v5b (v5 + XCD panel-pinning — ONLY the bid decode changed):
// v5 decode (qt = bid&63) spread the 64 blocks sharing one (b,hg) K/V panel
// across all 8 XCDs -> every per-XCD L2 re-fetched every panel (FETCH 70 MB
// vs ~24 ideal). New decode: qt = bid>>4, panel = bid&15 -> every block of
// panel p has bid = p (mod 16) = p (mod 8) -> all 64 land on XCD p%8; each
// XCD holds 2 panels (2 MB K+V < 4 MB L2). Bijective remap, same coverage.
// Rest of v5 (measured 92-94 us): staged K+V DMA, XOR swizzle, vmcnt gating,
// 4 heads/block, (256,2) — DO NOT restructure (r9 A/B: direct-V +20 us;
// r5/r8: launch_bounds 2nd arg caps VGPR at ~256/arg).
// ---------------------------------------------------------------------------
__global__ __launch_bounds__(256, 2) void attn_mfma_kernel(
    const unsigned short* __restrict__ q,   // [B][S][E] bf16
    const unsigned short* __restrict__ k,   // [B][S][E] bf16
    const unsigned short* __restrict__ vt,  // [B][E][S] bf16
    unsigned short* __restrict__ ctx,       // [B][S][E] bf16
    unsigned short* __restrict__ awp) {     // bf16 planes [2][B][S][S]
    __shared__ unsigned short s_mem[16 * 1032]; // P (16x1032) | K-staging union
    __shared__ unsigned short s_v[4 * 2048];    // V staging: 4 waves x 2 bufs x 1024
    __shared__ float s_red[2][4][16];

    const int t = threadIdx.x;
    const int wave = t >> 6, lane = t & 63;
    const int quad = lane >> 4, l16 = lane & 15;
    const int qt    = blockIdx.x >> 4;      // XCD-pin: panel in LOW bits
    const int panel = blockIdx.x & 15;
    const int hg    = panel & 1;            // head group (4 heads each)
    const int b     = panel >> 1;
    const int q0   = qt * 16;
    const size_t qrow = ((size_t)(b * S + q0 + l16)) * E;

    // wave-private staging areas (shorts)
    unsigned short* karea = s_mem + wave * 4128;   // 2 bufs x 2048 (32 rows x 64)
    unsigned short* varea = s_v + wave * 2048;     // 2 bufs x 1024 (16 rows x 64)

    // DMA lane mapping: dest = base + lane*8 shorts (HW rule); XOR source swizzle
    const int dr = lane >> 3;               // row within 8-row group
    const int dc = lane & 7;                // dest 16B col-block
    const int csrc = dc ^ dr;               // swizzled source col-block
    const int sw7 = l16 & 7;                // read-side swizzle key

    f32x4 awacc[16];
    #pragma unroll
    for (int i = 0; i < 16; i++) awacc[i] = (f32x4){0.f, 0.f, 0.f, 0.f};

    #pragma clang loop unroll(disable)
    for (int hh = 0; hh < 4; hh++) {
        const int h = hg * 4 + hh;

        // K chunk c (32 rows of wave's k-range) -> buf
        auto stage_k = [&](int c, int buf) {
            const unsigned short* src =
                k + ((size_t)(b * S + wave * 256 + c * 32 + dr)) * E + h * 64 + csrc * 8;
            unsigned short* dst = karea + buf * 2048 + dr * 64 + dc * 8;
            gload16(src,                  dst);
            gload16(src + (size_t)8 * E,  dst + 512);
            gload16(src + (size_t)16 * E, dst + 1024);
            gload16(src + (size_t)24 * E, dst + 1536);
        };
        // V chunk cv (64 s-cols of wave's 16 d-rows) -> buf
        auto stage_v = [&](int cv, int buf) {
            const unsigned short* src =
                vt + ((size_t)(b * E + h * 64 + wave * 16 + dr)) * S + cv * 64 + csrc * 8;
            unsigned short* dst = varea + buf * 1024 + dr * 64 + dc * 8;
            gload16(src,                 dst);
            gload16(src + (size_t)8 * S, dst + 512);
        };

        short8 aq0 = *(const short8*)(q + qrow + h * 64 + quad * 8);
        short8 aq1 = *(const short8*)(q + qrow + h * 64 + 32 + quad * 8);

        // ---- scores: 8 staged K chunks, 2-deep prefetch ----
        f32x4 sacc[16];
        stage_k(0, 0);
        stage_k(1, 1);
        #pragma unroll
        for (int c = 0; c < 8; c++) {
            if (c < 7) waitvm<4>(); else waitvm<0>();
            const unsigned short* kbuf = karea + (c & 1) * 2048;
            #pragma unroll
            for (int ntl = 0; ntl < 2; ntl++) {
                const int rl = ntl * 16 + l16;
                short8 kf0 = *(const short8*)(kbuf + rl * 64 + ((quad)     ^ sw7) * 8);
                short8 kf1 = *(const short8*)(kbuf + rl * 64 + ((4 + quad) ^ sw7) * 8);
                f32x4 cc = (f32x4){0.f, 0.f, 0.f, 0.f};
                cc = __builtin_amdgcn_mfma_f32_16x16x32_bf16(aq0, kf0, cc, 0, 0, 0);
                cc = __builtin_amdgcn_mfma_f32_16x16x32_bf16(aq1, kf1, cc, 0, 0, 0);
                sacc[c * 2 + ntl] = cc * 0.125f;
            }
            if (c < 6) stage_k(c + 2, c & 1);
        }

        // ---- merged single-pass softmax: local max+exp+sum pre-barrier ----
        float lm[4], ls[4];
        #pragma unroll
        for (int r = 0; r < 4; r++) {
            float mv = sacc[0][r];
            #pragma unroll
            for (int nt = 1; nt < 16; nt++) mv = fmaxf(mv, sacc[nt][r]);
            #pragma unroll
            for (int o = 1; o < 16; o <<= 1) mv = fmaxf(mv, __shfl_xor(mv, o));
            lm[r] = mv;
            ls[r] = 0.f;
        }
        #pragma unroll
        for (int nt = 0; nt < 16; nt++)
            #pragma unroll
            for (int r = 0; r < 4; r++) {
                float e = __expf(sacc[nt][r] - lm[r]);
                sacc[nt][r] = e;
                ls[r] += e;
            }
        #pragma unroll
        for (int r = 0; r < 4; r++) {
            #pragma unroll
            for (int o = 1; o < 16; o <<= 1) ls[r] += __shfl_xor(ls[r], o);
        }
        if (l16 == 0) {
            #pragma unroll
            for (int r = 0; r < 4; r++) {
                s_red[0][wave][quad * 4 + r] = lm[r];
                s_red[1][wave][quad * 4 + r] = ls[r];
            }
        }
        __syncthreads();                                   // (B1) also: all K reads done
        float scale[4];
        #pragma unroll
        for (int r = 0; r < 4; r++) {
            const int row = quad * 4 + r;
            float m0 = s_red[0][0][row], m1 = s_red[0][1][row];
            float m2 = s_red[0][2][row], m3 = s_red[0][3][row];
            float gmax = fmaxf(fmaxf(m0, m1), fmaxf(m2, m3));
            float gsum = s_red[1][0][row] * __expf(m0 - gmax)
                       + s_red[1][1][row] * __expf(m1 - gmax)
                       + s_red[1][2][row] * __expf(m2 - gmax)
                       + s_red[1][3][row] * __expf(m3 - gmax);
            scale[r] = __expf(lm[r] - gmax) / gsum;
        }

        // ---- normalize, accumulate aw, write P (bf16) into s_mem [16][1032] ----
        #pragma unroll
        for (int nt = 0; nt < 16; nt++) {
            #pragma unroll
            for (int r = 0; r < 4; r++) {
                float p = sacc[nt][r] * scale[r];
                awacc[nt][r] += p;
                s_mem[(quad * 4 + r) * 1032 + wave * 256 + nt * 16 + l16] = f2bf(p);
            }
        }
        __syncthreads();                                   // (B2) P visible

        // ---- PV: 16 staged V chunks, 2-deep prefetch; P from s_mem ----
        f32x4 cacc0 = (f32x4){0.f, 0.f, 0.f, 0.f};
        f32x4 cacc1 = (f32x4){0.f, 0.f, 0.f, 0.f};
        stage_v(0, 0);
        stage_v(1, 1);
        #pragma unroll
        for (int cv = 0; cv < 16; cv++) {
            if (cv < 15) waitvm<2>(); else waitvm<0>();
            const unsigned short* vbuf = varea + (cv & 1) * 1024;
            short8 vf0 = *(const short8*)(vbuf + l16 * 64 + ((quad)     ^ sw7) * 8);
            short8 vf1 = *(const short8*)(vbuf + l16 * 64 + ((4 + quad) ^ sw7) * 8);
            short8 pf0 = *(const short8*)(s_mem + l16 * 1032 + cv * 64 + quad * 8);
            short8 pf1 = *(const short8*)(s_mem + l16 * 1032 + cv * 64 + 32 + quad * 8);
            cacc0 = __builtin_amdgcn_mfma_f32_16x16x32_bf16(pf0, vf0, cacc0, 0, 0, 0);
            cacc1 = __builtin_amdgcn_mfma_f32_16x16x32_bf16(pf1, vf1, cacc1, 0, 0, 0);
            if (cv < 14) stage_v(cv + 2, cv & 1);
        }
        f32x4 cacc = cacc0 + cacc1;
        unsigned short* crow = ctx + ((size_t)(b * S + q0)) * E + h * 64 + wave * 16 + l16;
        #pragma unroll
        for (int r = 0; r < 4; r++)
            crow[(size_t)(quad * 4 + r) * E] = f2bf(cacc[r]);
        __syncthreads();                                   // (B3) P reads done -> K restage safe
    }

    // ---- head-group partial plane (bf16) ----
    #pragma unroll
    for (int nt = 0; nt < 16; nt++) {
        #pragma unroll
        for (int r = 0; r < 4; r++)
            awp[((size_t)((hg * B + b) * S + q0 + quad * 4 + r)) * S +
                wave * 256 + nt * 16 + l16] = f2bf(awacc[nt][r]);
    }
}

// ---------------------------------------------------------------------------
extern "C" void kernel_launch(void* const* d_in, const int* in_sizes, int n_in,
                              void* d_out, int out_size, void* d_ws, size_t ws_size,
                              hipStream_t stream) {
    const float* Zab  = (const float*)d_in[0];
    const float* Za   = (const float*)d_in[1];
    const float* lnw  = (const float*)d_in[2];
    const float* lnb  = (const float*)d_in[3];
    const float* Wqkv = (const float*)d_in[4];
    const float* bqkv = (const float*)d_in[5];
    const float* Wo   = (const float*)d_in[6];
    const float* bo   = (const float*)d_in[7];
    const float* Wf   = (const float*)d_in[8];
    const float* bf   = (const float*)d_in[9];

    float* out_final = (float*)d_out;
    float* out_aw    = out_final + (size_t)B * S * E;

    char* ws = (char*)d_ws;
    // Static buffers (live through attention):
    unsigned short* qb   = (unsigned short*)(ws);               // [0,8M)
    unsigned short* kb   = (unsigned short*)(ws + (8u << 20));  // [8,16M)
    unsigned short* vtb  = (unsigned short*)(ws + (16u << 20)); // [16,24M)
    unsigned short* ctxb = (unsigned short*)(ws + (24u << 20)); // [24,32M)
    // Pre-attention staging (dead once attention starts):
    unsigned short* aqb  = (unsigned short*)(ws + (32u << 20)); // [32,40M)
    unsigned short* akvb = (unsigned short*)(ws + (40u << 20)); // [40,48M)
    // awp planes: 2 x 16 MB at [32,64M) (aqb/akvb dead by attention)
    unsigned short* awp  = (unsigned short*)(ws + (32ull << 20));
    unsigned short* wbf  = (unsigned short*)(ws + (96ull << 20)); // 2.5 MB
    // Post-attention f32 buffers:
    float* xb  = (float*)(ws);                                  // [0,16M)
    float* tb  = (float*)(ws + (16u << 20));                    // [16,32M)
    unsigned short* xnb = aqb;                                  // [32,40M) after reduce

    dim3 blk(256);

    // 1+2. weights -> bf16 AND LN(Zab)+LN(Za) -> bf16, one launch
    prep_kernel<<<1280 + 4096, blk, 0, stream>>>(Wqkv, Wo, Wf, wbf,
                                                 Zab, Za, lnw, lnb, aqb, akvb);

    // 3. fused q/kv projection: one launch, 768 blocks = 3 blocks/CU
    gemm_qkv<<<dim3(M / 128, 12), blk, 0, stream>>>(aqb, akvb, wbf, bqkv, qb, kb, vtb);

    // 4. attention (staged K/V, 4 heads/block, XCD panel-pin) -> ctx + 2 planes
    attn_mfma_kernel<<<B * 2 * 64, blk, 0, stream>>>(qb, kb, vtb, ctxb, awp);

    // 5. fused: x = ctx@Wo^T + bo + Zab (512 gemm blocks) ∥ aw reduce (4096)
    gemm_o_red<<<512 + 4096, blk, 0, stream>>>(ctxb, wbf + (size_t)3*E*E, bo,
                                               Zab, xb, awp, out_aw);

    // 6. xn = LN(x) -> bf16
    ln_bf16_kernel<<<M / 4, blk, 0, stream>>>(xb, lnw, lnb, xnb);

    // 7. t = xn@Wf^T + bf + xn (f32) — 64-tile, 512 blocks = 2/CU
    gemm_mfma64_ff<<<dim3(M / 64, 4), blk, 0, stream>>>(xnb, wbf + (size_t)4*E*E, bf, xnb, tb);

    // 8. final = LN(t)
    ln_full_kernel<<<M / 4, blk, 0, stream>>>(tb, lnw, lnb, out_final);
}

// Round 15
// 249.111 us; speedup vs baseline: 1.3874x; 1.0172x over previous
//
#include <hip/hip_runtime.h>
#include <math.h>

#define EPS 1e-5f

constexpr int B = 8, S = 1024, E = 512, H = 8;
constexpr int M = B * S;          // 8192 rows

typedef __attribute__((ext_vector_type(8))) short short8;  // 8 bf16 (4 VGPRs)
typedef __attribute__((ext_vector_type(4))) float f32x4;

// fp32 -> bf16 bits, round-to-nearest-even
static __device__ __forceinline__ unsigned short f2bf(float f) {
    unsigned int x = __float_as_uint(f);
    x += 0x7FFFu + ((x >> 16) & 1u);
    return (unsigned short)(x >> 16);
}
static __device__ __forceinline__ float bf2f(unsigned short u) {
    return __uint_as_float(((unsigned int)u) << 16);
}

// async global->LDS, 16B per lane (global_load_lds_dwordx4)
typedef __attribute__((address_space(3))) unsigned int  lds_uint;
typedef __attribute__((address_space(1))) unsigned int  glb_uint;
static __device__ __forceinline__ void gload16(const unsigned short* g, unsigned short* l) {
    __builtin_amdgcn_global_load_lds((const glb_uint*)g, (lds_uint*)l, 16, 0, 0);
}
// s_waitcnt vmcnt(N) only (lgkm=15, exp=7 untouched). m135: in-order drain.
template <int N>
static __device__ __forceinline__ void waitvm() {
    __builtin_amdgcn_s_waitcnt(0x0F70 | N);
}

// ---------------------------------------------------------------------------
// Fused prep: blocks [0,1280) convert weights f32->bf16 (packed qkv|o|f);
// blocks [1280,5376) LN both inputs -> bf16 (rows [0,M)->o0, [M,2M)->o1).
// ---------------------------------------------------------------------------
__global__ __launch_bounds__(256) void prep_kernel(
    const float* __restrict__ wqkv, const float* __restrict__ wo,
    const float* __restrict__ wf, unsigned short* __restrict__ wout,
    const float* __restrict__ x0, const float* __restrict__ x1,
    const float* __restrict__ w, const float* __restrict__ bb,
    unsigned short* __restrict__ o0, unsigned short* __restrict__ o1) {
    const int bid = blockIdx.x;
    if (bid < 1280) {
        int base = (bid * 256 + threadIdx.x) * 4;
        float4 v;
        if (base < 3 * E * E)           v = *(const float4*)(wqkv + base);
        else if (base < 4 * E * E)      v = *(const float4*)(wo + (base - 3 * E * E));
        else                            v = *(const float4*)(wf + (base - 4 * E * E));
        ushort4 o;
        o.x = f2bf(v.x); o.y = f2bf(v.y); o.z = f2bf(v.z); o.w = f2bf(v.w);
        *(ushort4*)(wout + base) = o;
        return;
    }
    int row = (bid - 1280) * 4 + (threadIdx.x >> 6);
    int lane = threadIdx.x & 63;
    const float* x = row < M ? x0 : x1;
    unsigned short* out = row < M ? o0 : o1;
    int r = row < M ? row : row - M;
    const float* xr = x + (size_t)r * E + lane * 8;
    float4 v0 = *(const float4*)xr;
    float4 v1 = *(const float4*)(xr + 4);
    float vv[8] = {v0.x, v0.y, v0.z, v0.w, v1.x, v1.y, v1.z, v1.w};
    float s = 0.f;
    #pragma unroll
    for (int i = 0; i < 8; i++) s += vv[i];
    #pragma unroll
    for (int o = 1; o < 64; o <<= 1) s += __shfl_xor(s, o);
    float mu = s * (1.0f / E);
    float qs = 0.f;
    #pragma unroll
    for (int i = 0; i < 8; i++) { float d = vv[i] - mu; qs += d * d; }
    #pragma unroll
    for (int o = 1; o < 64; o <<= 1) qs += __shfl_xor(qs, o);
    float rs = rsqrtf(qs * (1.0f / E) + EPS);
    float4 w0 = *(const float4*)(w + lane * 8), w1 = *(const float4*)(w + lane * 8 + 4);
    float4 b0 = *(const float4*)(bb + lane * 8), b1 = *(const float4*)(bb + lane * 8 + 4);
    float ww[8] = {w0.x, w0.y, w0.z, w0.w, w1.x, w1.y, w1.z, w1.w};
    float bv[8] = {b0.x, b0.y, b0.z, b0.w, b1.x, b1.y, b1.z, b1.w};
    short8 o8;
    #pragma unroll
    for (int i = 0; i < 8; i++) o8[i] = (short)f2bf((vv[i] - mu) * rs * ww[i] + bv[i]);
    *(short8*)(out + (size_t)r * E + lane * 8) = o8;
}

// ---------------------------------------------------------------------------
// Fused o-proj GEMM + aw-reduce. Blocks [0,512): 64x128-tile GEMM
// x = ctx@Wo^T + bo + Zab (f32). Blocks [512,4608): aw = (1/H)*sum of 2 bf16
// planes. GEMM blocks first (critical path); reduce soaks remaining CUs.
// ---------------------------------------------------------------------------
__global__ __launch_bounds__(256) void gemm_o_red(
    const unsigned short* __restrict__ A, const unsigned short* __restrict__ W,
    const float* __restrict__ bias, const float* __restrict__ residf,
    float* __restrict__ C0,
    const unsigned short* __restrict__ awp, float* __restrict__ aw) {
    __shared__ unsigned short As[64 * 32];    // 4 KB
    __shared__ unsigned short Bs[128 * 32];   // 8 KB
    const int bid = blockIdx.x;
    const int t = threadIdx.x;
    if (bid >= 512) {
        // ---- reduce role ----
        const size_t PLN = (size_t)B * S * S;
        size_t idx = ((size_t)(bid - 512) * 256 + t) * 8;
        float acc[8] = {};
        #pragma unroll
        for (int p = 0; p < 2; p++) {
            short8 v = *(const short8*)(awp + p * PLN + idx);
            #pragma unroll
            for (int j = 0; j < 8; j++) acc[j] += bf2f((unsigned short)v[j]);
        }
        float4 o0 = make_float4(acc[0] * (1.0f / H), acc[1] * (1.0f / H),
                                acc[2] * (1.0f / H), acc[3] * (1.0f / H));
        float4 o1 = make_float4(acc[4] * (1.0f / H), acc[5] * (1.0f / H),
                                acc[6] * (1.0f / H), acc[7] * (1.0f / H));
        *(float4*)(aw + idx) = o0;
        *(float4*)(aw + idx + 4) = o1;
        return;
    }
    // ---- gemm role (64x128 tile, OUT_MODE 1) ----
    const int wave = t >> 6, lane = t & 63;
    const int quad = lane >> 4, l16 = lane & 15;
    const int m0 = (bid & 127) * 64, n0 = (bid >> 7) * 128;
    const int wm = (wave >> 1) * 32, wn = (wave & 1) * 64;
    const int srow = t >> 2;
    const int skof = (t & 3) * 8;

    f32x4 acc[2][4];
    #pragma unroll
    for (int i = 0; i < 2; i++)
        #pragma unroll
        for (int j = 0; j < 4; j++) acc[i][j] = (f32x4){0.f, 0.f, 0.f, 0.f};

    for (int k0 = 0; k0 < E; k0 += 32) {
        gload16(A + (size_t)(m0 + srow) * E + k0 + skof,        As + t * 8);
        gload16(W + (size_t)(n0 + srow) * E + k0 + skof,        Bs + t * 8);
        gload16(W + (size_t)(n0 + 64 + srow) * E + k0 + skof,   Bs + 2048 + t * 8);
        __syncthreads();
        short8 af[2], bfr[4];
        #pragma unroll
        for (int i = 0; i < 2; i++)
            af[i] = *(const short8*)&As[(wm + i * 16 + l16) * 32 + quad * 8];
        #pragma unroll
        for (int j = 0; j < 4; j++)
            bfr[j] = *(const short8*)&Bs[(wn + j * 16 + l16) * 32 + quad * 8];
        #pragma unroll
        for (int i = 0; i < 2; i++)
            #pragma unroll
            for (int j = 0; j < 4; j++)
                acc[i][j] = __builtin_amdgcn_mfma_f32_16x16x32_bf16(af[i], bfr[j], acc[i][j], 0, 0, 0);
        __syncthreads();
    }

    #pragma unroll
    for (int i = 0; i < 2; i++) {
        const int mrow0 = m0 + wm + i * 16 + quad * 4;
        #pragma unroll
        for (int j = 0; j < 4; j++) {
            const int ncol = n0 + wn + j * 16 + l16;
            const float bval = bias[ncol];
            #pragma unroll
            for (int r = 0; r < 4; r++) {
                size_t idx = (size_t)(mrow0 + r) * 512 + ncol;
                C0[idx] = acc[i][j][r] + bval + residf[idx];
            }
        }
    }
}

// ---------------------------------------------------------------------------
// FFN fused kernel: one block owns 16 FULL output rows (tile 16 x 512).
// Replaces steps 6+7+8: xn = LN(x); t = xn@Wf^T + bf + xn; final = LN(t).
// K-loop unroll-DISABLED (round-3 lesson: the "container failed twice"
// signature = compile blow-up from full unroll of a multi-barrier loop body).
// Grid = M/16 = 512 blocks; LDS ~50 KB -> 3 blocks/CU.
// ---------------------------------------------------------------------------
__global__ __launch_bounds__(256) void ffn_fused_kernel(
    const float* __restrict__ x,          // [M][E] f32
    const unsigned short* __restrict__ W, // Wf bf16 [E][E]
    const float* __restrict__ bias,       // bf [E]
    const float* __restrict__ lnw, const float* __restrict__ lnb,
    float* __restrict__ out) {            // final [M][E] f32
    __shared__ unsigned short Axn[16 * 520];   // 16.6 KB
    __shared__ unsigned short Bs[512 * 32];    // 32 KB
    __shared__ float s_red[2][4][16];
    const int t = threadIdx.x;
    const int wave = t >> 6, lane = t & 63;
    const int quad = lane >> 4, l16 = lane & 15;
    const int m0 = blockIdx.x * 16;

    // ---- phase 1: front LN, wave handles rows wave*4 .. wave*4+3 ----
    #pragma unroll
    for (int rr = 0; rr < 4; rr++) {
        const int row = wave * 4 + rr;
        const float* xr = x + (size_t)(m0 + row) * E + lane * 8;
        float4 v0 = *(const float4*)xr;
        float4 v1 = *(const float4*)(xr + 4);
        float vv[8] = {v0.x, v0.y, v0.z, v0.w, v1.x, v1.y, v1.z, v1.w};
        float s = 0.f;
        #pragma unroll
        for (int i = 0; i < 8; i++) s += vv[i];
        #pragma unroll
        for (int o = 1; o < 64; o <<= 1) s += __shfl_xor(s, o);
        float mu = s * (1.0f / E);
        float qs = 0.f;
        #pragma unroll
        for (int i = 0; i < 8; i++) { float d = vv[i] - mu; qs += d * d; }
        #pragma unroll
        for (int o = 1; o < 64; o <<= 1) qs += __shfl_xor(qs, o);
        float rs = rsqrtf(qs * (1.0f / E) + EPS);
        float4 w0 = *(const float4*)(lnw + lane * 8), w1 = *(const float4*)(lnw + lane * 8 + 4);
        float4 b0 = *(const float4*)(lnb + lane * 8), b1 = *(const float4*)(lnb + lane * 8 + 4);
        float ww[8] = {w0.x, w0.y, w0.z, w0.w, w1.x, w1.y, w1.z, w1.w};
        float bv[8] = {b0.x, b0.y, b0.z, b0.w, b1.x, b1.y, b1.z, b1.w};
        short8 o8;
        #pragma unroll
        for (int i = 0; i < 8; i++) o8[i] = (short)f2bf((vv[i] - mu) * rs * ww[i] + bv[i]);
        *(short8*)&Axn[row * 520 + lane * 8] = o8;
    }
    __syncthreads();

    // ---- phase 2: GEMM. wave owns cols [wave*128, wave*128+128) of all 16 rows ----
    f32x4 acc[8];
    #pragma unroll
    for (int j = 0; j < 8; j++) acc[j] = (f32x4){0.f, 0.f, 0.f, 0.f};
    const int srow = t >> 2;
    const int skof = (t & 3) * 8;
    #pragma clang loop unroll(disable)
    for (int k0 = 0; k0 < E; k0 += 32) {
        #pragma unroll
        for (int c = 0; c < 8; c++)
            gload16(W + (size_t)(c * 64 + srow) * E + k0 + skof, Bs + c * 2048 + t * 8);
        __syncthreads();
        short8 af = *(const short8*)&Axn[l16 * 520 + k0 + quad * 8];
        short8 bfr[8];
        #pragma unroll
        for (int j = 0; j < 8; j++)
            bfr[j] = *(const short8*)&Bs[(wave * 128 + j * 16 + l16) * 32 + quad * 8];
        #pragma unroll
        for (int j = 0; j < 8; j++)
            acc[j] = __builtin_amdgcn_mfma_f32_16x16x32_bf16(af, bfr[j], acc[j], 0, 0, 0);
        __syncthreads();
    }

    // ---- phase 3: t = acc + bias + xn, then final LN (2-pass) ----
    float tv[4][8];
    #pragma unroll
    for (int j = 0; j < 8; j++) {
        const int col = wave * 128 + j * 16 + l16;
        const float bval = bias[col];
        #pragma unroll
        for (int r = 0; r < 4; r++) {
            const int row = quad * 4 + r;
            tv[r][j] = acc[j][r] + bval + bf2f(Axn[row * 520 + col]);
        }
    }
    // pass 1: mean (per-wave 128-col partials, combine across waves)
    #pragma unroll
    for (int r = 0; r < 4; r++) {
        float s = 0.f;
        #pragma unroll
        for (int j = 0; j < 8; j++) s += tv[r][j];
        #pragma unroll
        for (int o = 1; o < 16; o <<= 1) s += __shfl_xor(s, o);
        if (l16 == 0) s_red[0][wave][quad * 4 + r] = s;
    }
    __syncthreads();
    float mu[4];
    #pragma unroll
    for (int r = 0; r < 4; r++) {
        const int row = quad * 4 + r;
        mu[r] = (s_red[0][0][row] + s_red[0][1][row] +
                 s_red[0][2][row] + s_red[0][3][row]) * (1.0f / E);
    }
    // pass 2: variance = mean((t-mu)^2)
    #pragma unroll
    for (int r = 0; r < 4; r++) {
        float s = 0.f;
        #pragma unroll
        for (int j = 0; j < 8; j++) { float d = tv[r][j] - mu[r]; s += d * d; }
        #pragma unroll
        for (int o = 1; o < 16; o <<= 1) s += __shfl_xor(s, o);
        if (l16 == 0) s_red[1][wave][quad * 4 + r] = s;
    }
    __syncthreads();
    float rsig[4];
    #pragma unroll
    for (int r = 0; r < 4; r++) {
        const int row = quad * 4 + r;
        float var = (s_red[1][0][row] + s_red[1][1][row] +
                     s_red[1][2][row] + s_red[1][3][row]) * (1.0f / E);
        rsig[r] = rsqrtf(var + EPS);
    }
    #pragma unroll
    for (int j = 0; j < 8; j++) {
        const int col = wave * 128 + j * 16 + l16;
        const float wc = lnw[col], bc = lnb[col];
        #pragma unroll
        for (int r = 0; r < 4; r++)
            out[(size_t)(m0 + quad * 4 + r) * E + col] =
                (tv[r][j] - mu[r]) * rsig[r] * wc + bc;
    }
}

// ---------------------------------------------------------------------------
// Fused q + kv projection GEMM (128x128 tile, 768 blocks = 3 blocks/CU).
// ---------------------------------------------------------------------------
__global__ __launch_bounds__(256) void gemm_qkv(
    const unsigned short* __restrict__ Aq, const unsigned short* __restrict__ Akv,
    const unsigned short* __restrict__ W,   // packed [3E][E] bf16
    const float* __restrict__ bias,         // [3E]
    unsigned short* __restrict__ qout,      // [M][512] bf16
    unsigned short* __restrict__ kout,      // [M][512] bf16
    unsigned short* __restrict__ vtout) {   // [B][512][1024] bf16
    __shared__ unsigned short As[128 * 32];
    __shared__ unsigned short Bs[128 * 32];
    const int t = threadIdx.x;
    const int wave = t >> 6, lane = t & 63;
    const int quad = lane >> 4, l16 = lane & 15;
    const bool isq = blockIdx.y < 4;
    const int yy = isq ? blockIdx.y : blockIdx.y - 4;
    const unsigned short* A  = isq ? Aq : Akv;
    const unsigned short* Wb = W + (isq ? 0 : (size_t)E * E);
    const float* bb = bias + (isq ? 0 : E);
    const int m0 = blockIdx.x * 128, n0 = yy * 128;
    const int wm = (wave >> 1) * 64, wn = (wave & 1) * 64;

    const int srow = t >> 2;
    const int skof = (t & 3) * 8;

    f32x4 acc[4][4];
    #pragma unroll
    for (int i = 0; i < 4; i++)
        #pragma unroll
        for (int j = 0; j < 4; j++) acc[i][j] = (f32x4){0.f, 0.f, 0.f, 0.f};

    for (int k0 = 0; k0 < E; k0 += 32) {
        gload16(A + (size_t)(m0 + srow) * E + k0 + skof,         As + t * 8);
        gload16(A + (size_t)(m0 + 64 + srow) * E + k0 + skof,    As + 2048 + t * 8);
        gload16(Wb + (size_t)(n0 + srow) * E + k0 + skof,        Bs + t * 8);
        gload16(Wb + (size_t)(n0 + 64 + srow) * E + k0 + skof,   Bs + 2048 + t * 8);
        __syncthreads();
        short8 af[4], bfr[4];
        #pragma unroll
        for (int i = 0; i < 4; i++)
            af[i] = *(const short8*)&As[(wm + i * 16 + l16) * 32 + quad * 8];
        #pragma unroll
        for (int j = 0; j < 4; j++)
            bfr[j] = *(const short8*)&Bs[(wn + j * 16 + l16) * 32 + quad * 8];
        #pragma unroll
        for (int i = 0; i < 4; i++)
            #pragma unroll
            for (int j = 0; j < 4; j++)
                acc[i][j] = __builtin_amdgcn_mfma_f32_16x16x32_bf16(af[i], bfr[j], acc[i][j], 0, 0, 0);
        __syncthreads();
    }

    #pragma unroll
    for (int i = 0; i < 4; i++) {
        const int mrow0 = m0 + wm + i * 16 + quad * 4;
        #pragma unroll
        for (int j = 0; j < 4; j++) {
            const int ncol = n0 + wn + j * 16 + l16;
            const float bval = bb[ncol];
            if (isq) {
                #pragma unroll
                for (int r = 0; r < 4; r++)
                    qout[(size_t)(mrow0 + r) * 512 + ncol] = f2bf(acc[i][j][r] + bval);
            } else if (ncol < 512) {
                #pragma unroll
                for (int r = 0; r < 4; r++)
                    kout[(size_t)(mrow0 + r) * 512 + ncol] = f2bf(acc[i][j][r] + bval);
            } else {
                const int nv = ncol - 512;
                const int b2 = mrow0 >> 10, s0v = mrow0 & 1023;
                ushort4 o;
                o.x = f2bf(acc[i][j][0] + bval);
                o.y = f2bf(acc[i][j][1] + bval);
                o.z = f2bf(acc[i][j][2] + bval);
                o.w = f2bf(acc[i][j][3] + bval);
                *(ushort4*)(vtout + ((size_t)b2 * 512 + nv) * 1024 + s0v) = o;
            }
        }
    }
}

// ---------------------------------------------------------------------------
// MFMA attention v5b (measured 90.6 us, FETCH 19 MB — DO NOT restructure):
// staged K+V DMA (gload_lds, XOR swizzle), vmcnt-gated 2-deep prefetch,
// 4 heads/block, XCD panel-pin decode (panel = bid&15). (256,2): launch_bounds
// 2nd arg caps VGPR at ~256/arg (r5/r8). r9 A/B: direct-V +20 us.
// r13: kernel is latency-bound internally, NOT L2-bound.
// ---------------------------------------------------------------------------
__global__ __launch_bounds__(256, 2) void attn_mfma_kernel(
    const unsigned short* __restrict__ q,   // [B][S][E] bf16
    const unsigned short* __restrict__ k,   // [B][S][E] bf16
    const unsigned short* __restrict__ vt,  // [B][E][S] bf16
    unsigned short* __restrict__ ctx,       // [B][S][E] bf16
    unsigned short* __restrict__ awp) {     // bf16 planes [2][B][S][S]
    __shared__ unsigned short s_mem[16 * 1032]; // P (16x1032) | K-staging union
    __shared__ unsigned short s_v[4 * 2048];    // V staging: 4 waves x 2 bufs x 1024
    __shared__ float s_red[2][4][16];

    const int t = threadIdx.x;
    const int wave = t >> 6, lane = t & 63;
    const int quad = lane >> 4, l16 = lane & 15;
    const int qt    = blockIdx.x >> 4;      // XCD-pin: panel in LOW bits
    const int panel = blockIdx.x & 15;
    const int hg    = panel & 1;            // head group (4 heads each)
    const int b     = panel >> 1;
    const int q0   = qt * 16;
    const size_t qrow = ((size_t)(b * S + q0 + l16)) * E;

    // wave-private staging areas (shorts)
    unsigned short* karea = s_mem + wave * 4128;   // 2 bufs x 2048 (32 rows x 64)
    unsigned short* varea = s_v + wave * 2048;     // 2 bufs x 1024 (16 rows x 64)

    // DMA lane mapping: dest = base + lane*8 shorts (HW rule); XOR source swizzle
    const int dr = lane >> 3;               // row within 8-row group
    const int dc = lane & 7;                // dest 16B col-block
    const int csrc = dc ^ dr;               // swizzled source col-block
    const int sw7 = l16 & 7;                // read-side swizzle key

    f32x4 awacc[16];
    #pragma unroll
    for (int i = 0; i < 16; i++) awacc[i] = (f32x4){0.f, 0.f, 0.f, 0.f};

    #pragma clang loop unroll(disable)
    for (int hh = 0; hh < 4; hh++) {
        const int h = hg * 4 + hh;

        // K chunk c (32 rows of wave's k-range) -> buf
        auto stage_k = [&](int c, int buf) {
            const unsigned short* src =
                k + ((size_t)(b * S + wave * 256 + c * 32 + dr)) * E + h * 64 + csrc * 8;
            unsigned short* dst = karea + buf * 2048 + dr * 64 + dc * 8;
            gload16(src,                  dst);
            gload16(src + (size_t)8 * E,  dst + 512);
            gload16(src + (size_t)16 * E, dst + 1024);
            gload16(src + (size_t)24 * E, dst + 1536);
        };
        // V chunk cv (64 s-cols of wave's 16 d-rows) -> buf
        auto stage_v = [&](int cv, int buf) {
            const unsigned short* src =
                vt + ((size_t)(b * E + h * 64 + wave * 16 + dr)) * S + cv * 64 + csrc * 8;
            unsigned short* dst = varea + buf * 1024 + dr * 64 + dc * 8;
            gload16(src,                 dst);
            gload16(src + (size_t)8 * S, dst + 512);
        };

        short8 aq0 = *(const short8*)(q + qrow + h * 64 + quad * 8);
        short8 aq1 = *(const short8*)(q + qrow + h * 64 + 32 + quad * 8);

        // ---- scores: 8 staged K chunks, 2-deep prefetch ----
        f32x4 sacc[16];
        stage_k(0, 0);
        stage_k(1, 1);
        #pragma unroll
        for (int c = 0; c < 8; c++) {
            if (c < 7) waitvm<4>(); else waitvm<0>();
            const unsigned short* kbuf = karea + (c & 1) * 2048;
            #pragma unroll
            for (int ntl = 0; ntl < 2; ntl++) {
                const int rl = ntl * 16 + l16;
                short8 kf0 = *(const short8*)(kbuf + rl * 64 + ((quad)     ^ sw7) * 8);
                short8 kf1 = *(const short8*)(kbuf + rl * 64 + ((4 + quad) ^ sw7) * 8);
                f32x4 cc = (f32x4){0.f, 0.f, 0.f, 0.f};
                cc = __builtin_amdgcn_mfma_f32_16x16x32_bf16(aq0, kf0, cc, 0, 0, 0);
                cc = __builtin_amdgcn_mfma_f32_16x16x32_bf16(aq1, kf1, cc, 0, 0, 0);
                sacc[c * 2 + ntl] = cc * 0.125f;
            }
            if (c < 6) stage_k(c + 2, c & 1);
        }

        // ---- merged single-pass softmax: local max+exp+sum pre-barrier ----
        float lm[4], ls[4];
        #pragma unroll
        for (int r = 0; r < 4; r++) {
            float mv = sacc[0][r];
            #pragma unroll
            for (int nt = 1; nt < 16; nt++) mv = fmaxf(mv, sacc[nt][r]);
            #pragma unroll
            for (int o = 1; o < 16; o <<= 1) mv = fmaxf(mv, __shfl_xor(mv, o));
            lm[r] = mv;
            ls[r] = 0.f;
        }
        #pragma unroll
        for (int nt = 0; nt < 16; nt++)
            #pragma unroll
            for (int r = 0; r < 4; r++) {
                float e = __expf(sacc[nt][r] - lm[r]);
                sacc[nt][r] = e;
                ls[r] += e;
            }
        #pragma unroll
        for (int r = 0; r < 4; r++) {
            #pragma unroll
            for (int o = 1; o < 16; o <<= 1) ls[r] += __shfl_xor(ls[r], o);
        }
        if (l16 == 0) {
            #pragma unroll
            for (int r = 0; r < 4; r++) {
                s_red[0][wave][quad * 4 + r] = lm[r];
                s_red[1][wave][quad * 4 + r] = ls[r];
            }
        }
        __syncthreads();                                   // (B1) also: all K reads done
        float scale[4];
        #pragma unroll
        for (int r = 0; r < 4; r++) {
            const int row = quad * 4 + r;
            float m0 = s_red[0][0][row], m1 = s_red[0][1][row];
            float m2 = s_red[0][2][row], m3 = s_red[0][3][row];
            float gmax = fmaxf(fmaxf(m0, m1), fmaxf(m2, m3));
            float gsum = s_red[1][0][row] * __expf(m0 - gmax)
                       + s_red[1][1][row] * __expf(m1 - gmax)
                       + s_red[1][2][row] * __expf(m2 - gmax)
                       + s_red[1][3][row] * __expf(m3 - gmax);
            scale[r] = __expf(lm[r] - gmax) / gsum;
        }

        // ---- normalize, accumulate aw, write P (bf16) into s_mem [16][1032] ----
        #pragma unroll
        for (int nt = 0; nt < 16; nt++) {
            #pragma unroll
            for (int r = 0; r < 4; r++) {
                float p = sacc[nt][r] * scale[r];
                awacc[nt][r] += p;
                s_mem[(quad * 4 + r) * 1032 + wave * 256 + nt * 16 + l16] = f2bf(p);
            }
        }
        __syncthreads();                                   // (B2) P visible

        // ---- PV: 16 staged V chunks, 2-deep prefetch; P from s_mem ----
        f32x4 cacc0 = (f32x4){0.f, 0.f, 0.f, 0.f};
        f32x4 cacc1 = (f32x4){0.f, 0.f, 0.f, 0.f};
        stage_v(0, 0);
        stage_v(1, 1);
        #pragma unroll
        for (int cv = 0; cv < 16; cv++) {
            if (cv < 15) waitvm<2>(); else waitvm<0>();
            const unsigned short* vbuf = varea + (cv & 1) * 1024;
            short8 vf0 = *(const short8*)(vbuf + l16 * 64 + ((quad)     ^ sw7) * 8);
            short8 vf1 = *(const short8*)(vbuf + l16 * 64 + ((4 + quad) ^ sw7) * 8);
            short8 pf0 = *(const short8*)(s_mem + l16 * 1032 + cv * 64 + quad * 8);
            short8 pf1 = *(const short8*)(s_mem + l16 * 1032 + cv * 64 + 32 + quad * 8);
            cacc0 = __builtin_amdgcn_mfma_f32_16x16x32_bf16(pf0, vf0, cacc0, 0, 0, 0);
            cacc1 = __builtin_amdgcn_mfma_f32_16x16x32_bf16(pf1, vf1, cacc1, 0, 0, 0);
            if (cv < 14) stage_v(cv + 2, cv & 1);
        }
        f32x4 cacc = cacc0 + cacc1;
        unsigned short* crow = ctx + ((size_t)(b * S + q0)) * E + h * 64 + wave * 16 + l16;
        #pragma unroll
        for (int r = 0; r < 4; r++)
            crow[(size_t)(quad * 4 + r) * E] = f2bf(cacc[r]);
        __syncthreads();                                   // (B3) P reads done -> K restage safe
    }

    // ---- head-group partial plane (bf16) ----
    #pragma unroll
    for (int nt = 0; nt < 16; nt++) {
        #pragma unroll
        for (int r = 0; r < 4; r++)
            awp[((size_t)((hg * B + b) * S + q0 + quad * 4 + r)) * S +
                wave * 256 + nt * 16 + l16] = f2bf(awacc[nt][r]);
    }
}

// ---------------------------------------------------------------------------
extern "C" void kernel_launch(void* const* d_in, const int* in_sizes, int n_in,
                              void* d_out, int out_size, void* d_ws, size_t ws_size,
                              hipStream_t stream) {
    const float* Zab  = (const float*)d_in[0];
    const float* Za   = (const float*)d_in[1];
    const float* lnw  = (const float*)d_in[2];
    const float* lnb  = (const float*)d_in[3];
    const float* Wqkv = (const float*)d_in[4];
    const float* bqkv = (const float*)d_in[5];
    const float* Wo   = (const float*)d_in[6];
    const float* bo   = (const float*)d_in[7];
    const float* Wf   = (const float*)d_in[8];
    const float* bf   = (const float*)d_in[9];

    float* out_final = (float*)d_out;
    float* out_aw    = out_final + (size_t)B * S * E;

    char* ws = (char*)d_ws;
    // Static buffers (live through attention):
    unsigned short* qb   = (unsigned short*)(ws);               // [0,8M)
    unsigned short* kb   = (unsigned short*)(ws + (8u << 20));  // [8,16M)
    unsigned short* vtb  = (unsigned short*)(ws + (16u << 20)); // [16,24M)
    unsigned short* ctxb = (unsigned short*)(ws + (24u << 20)); // [24,32M)
    // Pre-attention staging (dead once attention starts):
    unsigned short* aqb  = (unsigned short*)(ws + (32u << 20)); // [32,40M)
    unsigned short* akvb = (unsigned short*)(ws + (40u << 20)); // [40,48M)
    // awp planes: 2 x 16 MB at [32,64M) (aqb/akvb dead by attention)
    unsigned short* awp  = (unsigned short*)(ws + (32ull << 20));
    unsigned short* wbf  = (unsigned short*)(ws + (96ull << 20)); // 2.5 MB
    // Post-attention f32 buffer:
    float* xb  = (float*)(ws);                                  // [0,16M)

    dim3 blk(256);

    // 1+2. weights -> bf16 AND LN(Zab)+LN(Za) -> bf16, one launch
    prep_kernel<<<1280 + 4096, blk, 0, stream>>>(Wqkv, Wo, Wf, wbf,
                                                 Zab, Za, lnw, lnb, aqb, akvb);

    // 3. fused q/kv projection: one launch, 768 blocks = 3 blocks/CU
    gemm_qkv<<<dim3(M / 128, 12), blk, 0, stream>>>(aqb, akvb, wbf, bqkv, qb, kb, vtb);

    // 4. attention (staged K/V, 4 heads/block, XCD panel-pin) -> ctx + 2 planes
    attn_mfma_kernel<<<B * 2 * 64, blk, 0, stream>>>(qb, kb, vtb, ctxb, awp);

    // 5. fused: x = ctx@Wo^T + bo + Zab (512 gemm blocks) ∥ aw reduce (4096)
    gemm_o_red<<<512 + 4096, blk, 0, stream>>>(ctxb, wbf + (size_t)3*E*E, bo,
                                               Zab, xb, awp, out_aw);

    // 6. fused FFN: xn=LN(x); t=xn@Wf^T+bf+xn; final=LN(t) — one launch
    ffn_fused_kernel<<<M / 16, blk, 0, stream>>>(xb, wbf + (size_t)4*E*E, bf,
                                                 lnw, lnb, out_final);
}

// Round 17
// 247.043 us; speedup vs baseline: 1.3990x; 1.0084x over previous
//
#include <hip/hip_runtime.h>
#include <math.h>

#define EPS 1e-5f

constexpr int B = 8, S = 1024, E = 512, H = 8;
constexpr int M = B * S;          // 8192 rows

typedef __attribute__((ext_vector_type(8))) short short8;  // 8 bf16 (4 VGPRs)
typedef __attribute__((ext_vector_type(4))) float f32x4;

// fp32 -> bf16 bits, round-to-nearest-even
static __device__ __forceinline__ unsigned short f2bf(float f) {
    unsigned int x = __float_as_uint(f);
    x += 0x7FFFu + ((x >> 16) & 1u);
    return (unsigned short)(x >> 16);
}
static __device__ __forceinline__ float bf2f(unsigned short u) {
    return __uint_as_float(((unsigned int)u) << 16);
}

// async global->LDS, 16B per lane (global_load_lds_dwordx4)
typedef __attribute__((address_space(3))) unsigned int  lds_uint;
typedef __attribute__((address_space(1))) unsigned int  glb_uint;
static __device__ __forceinline__ void gload16(const unsigned short* g, unsigned short* l) {
    __builtin_amdgcn_global_load_lds((const glb_uint*)g, (lds_uint*)l, 16, 0, 0);
}
// s_waitcnt vmcnt(N) only (lgkm=15, exp=7 untouched). m135: in-order drain.
template <int N>
static __device__ __forceinline__ void waitvm() {
    __builtin_amdgcn_s_waitcnt(0x0F70 | N);
}

// ---------------------------------------------------------------------------
// Fused prep: blocks [0,1280) convert weights f32->bf16 (packed qkv|o|f);
// blocks [1280,5376) LN both inputs -> bf16 (rows [0,M)->o0, [M,2M)->o1).
// ---------------------------------------------------------------------------
__global__ __launch_bounds__(256) void prep_kernel(
    const float* __restrict__ wqkv, const float* __restrict__ wo,
    const float* __restrict__ wf, unsigned short* __restrict__ wout,
    const float* __restrict__ x0, const float* __restrict__ x1,
    const float* __restrict__ w, const float* __restrict__ bb,
    unsigned short* __restrict__ o0, unsigned short* __restrict__ o1) {
    const int bid = blockIdx.x;
    if (bid < 1280) {
        int base = (bid * 256 + threadIdx.x) * 4;
        float4 v;
        if (base < 3 * E * E)           v = *(const float4*)(wqkv + base);
        else if (base < 4 * E * E)      v = *(const float4*)(wo + (base - 3 * E * E));
        else                            v = *(const float4*)(wf + (base - 4 * E * E));
        ushort4 o;
        o.x = f2bf(v.x); o.y = f2bf(v.y); o.z = f2bf(v.z); o.w = f2bf(v.w);
        *(ushort4*)(wout + base) = o;
        return;
    }
    int row = (bid - 1280) * 4 + (threadIdx.x >> 6);
    int lane = threadIdx.x & 63;
    const float* x = row < M ? x0 : x1;
    unsigned short* out = row < M ? o0 : o1;
    int r = row < M ? row : row - M;
    const float* xr = x + (size_t)r * E + lane * 8;
    float4 v0 = *(const float4*)xr;
    float4 v1 = *(const float4*)(xr + 4);
    float vv[8] = {v0.x, v0.y, v0.z, v0.w, v1.x, v1.y, v1.z, v1.w};
    float s = 0.f;
    #pragma unroll
    for (int i = 0; i < 8; i++) s += vv[i];
    #pragma unroll
    for (int o = 1; o < 64; o <<= 1) s += __shfl_xor(s, o);
    float mu = s * (1.0f / E);
    float qs = 0.f;
    #pragma unroll
    for (int i = 0; i < 8; i++) { float d = vv[i] - mu; qs += d * d; }
    #pragma unroll
    for (int o = 1; o < 64; o <<= 1) qs += __shfl_xor(qs, o);
    float rs = rsqrtf(qs * (1.0f / E) + EPS);
    float4 w0 = *(const float4*)(w + lane * 8), w1 = *(const float4*)(w + lane * 8 + 4);
    float4 b0 = *(const float4*)(bb + lane * 8), b1 = *(const float4*)(bb + lane * 8 + 4);
    float ww[8] = {w0.x, w0.y, w0.z, w0.w, w1.x, w1.y, w1.z, w1.w};
    float bv[8] = {b0.x, b0.y, b0.z, b0.w, b1.x, b1.y, b1.z, b1.w};
    short8 o8;
    #pragma unroll
    for (int i = 0; i < 8; i++) o8[i] = (short)f2bf((vv[i] - mu) * rs * ww[i] + bv[i]);
    *(short8*)(out + (size_t)r * E + lane * 8) = o8;
}

// ---------------------------------------------------------------------------
// Fused o-proj GEMM + aw-reduce. Blocks [0,512): 64x128-tile GEMM
// x = ctx@Wo^T + bo + Zab (f32). Blocks [512,4608): aw = (1/H)*sum of 2 bf16
// planes. GEMM blocks first (critical path); reduce soaks remaining CUs.
// ---------------------------------------------------------------------------
__global__ __launch_bounds__(256) void gemm_o_red(
    const unsigned short* __restrict__ A, const unsigned short* __restrict__ W,
    const float* __restrict__ bias, const float* __restrict__ residf,
    float* __restrict__ C0,
    const unsigned short* __restrict__ awp, float* __restrict__ aw) {
    __shared__ unsigned short As[64 * 32];    // 4 KB
    __shared__ unsigned short Bs[128 * 32];   // 8 KB
    const int bid = blockIdx.x;
    const int t = threadIdx.x;
    if (bid >= 512) {
        // ---- reduce role ----
        const size_t PLN = (size_t)B * S * S;
        size_t idx = ((size_t)(bid - 512) * 256 + t) * 8;
        float acc[8] = {};
        #pragma unroll
        for (int p = 0; p < 2; p++) {
            short8 v = *(const short8*)(awp + p * PLN + idx);
            #pragma unroll
            for (int j = 0; j < 8; j++) acc[j] += bf2f((unsigned short)v[j]);
        }
        float4 o0 = make_float4(acc[0] * (1.0f / H), acc[1] * (1.0f / H),
                                acc[2] * (1.0f / H), acc[3] * (1.0f / H));
        float4 o1 = make_float4(acc[4] * (1.0f / H), acc[5] * (1.0f / H),
                                acc[6] * (1.0f / H), acc[7] * (1.0f / H));
        *(float4*)(aw + idx) = o0;
        *(float4*)(aw + idx + 4) = o1;
        return;
    }
    // ---- gemm role (64x128 tile, OUT_MODE 1) ----
    const int wave = t >> 6, lane = t & 63;
    const int quad = lane >> 4, l16 = lane & 15;
    const int m0 = (bid & 127) * 64, n0 = (bid >> 7) * 128;
    const int wm = (wave >> 1) * 32, wn = (wave & 1) * 64;
    const int srow = t >> 2;
    const int skof = (t & 3) * 8;

    f32x4 acc[2][4];
    #pragma unroll
    for (int i = 0; i < 2; i++)
        #pragma unroll
        for (int j = 0; j < 4; j++) acc[i][j] = (f32x4){0.f, 0.f, 0.f, 0.f};

    for (int k0 = 0; k0 < E; k0 += 32) {
        gload16(A + (size_t)(m0 + srow) * E + k0 + skof,        As + t * 8);
        gload16(W + (size_t)(n0 + srow) * E + k0 + skof,        Bs + t * 8);
        gload16(W + (size_t)(n0 + 64 + srow) * E + k0 + skof,   Bs + 2048 + t * 8);
        __syncthreads();
        short8 af[2], bfr[4];
        #pragma unroll
        for (int i = 0; i < 2; i++)
            af[i] = *(const short8*)&As[(wm + i * 16 + l16) * 32 + quad * 8];
        #pragma unroll
        for (int j = 0; j < 4; j++)
            bfr[j] = *(const short8*)&Bs[(wn + j * 16 + l16) * 32 + quad * 8];
        #pragma unroll
        for (int i = 0; i < 2; i++)
            #pragma unroll
            for (int j = 0; j < 4; j++)
                acc[i][j] = __builtin_amdgcn_mfma_f32_16x16x32_bf16(af[i], bfr[j], acc[i][j], 0, 0, 0);
        __syncthreads();
    }

    #pragma unroll
    for (int i = 0; i < 2; i++) {
        const int mrow0 = m0 + wm + i * 16 + quad * 4;
        #pragma unroll
        for (int j = 0; j < 4; j++) {
            const int ncol = n0 + wn + j * 16 + l16;
            const float bval = bias[ncol];
            #pragma unroll
            for (int r = 0; r < 4; r++) {
                size_t idx = (size_t)(mrow0 + r) * 512 + ncol;
                C0[idx] = acc[i][j][r] + bval + residf[idx];
            }
        }
    }
}

// ---------------------------------------------------------------------------
// FFN fused kernel v2b: one block owns 16 FULL output rows (tile 16 x 512).
// Replaces steps 6+7+8: xn = LN(x); t = xn@Wf^T + bf + xn; final = LN(t).
// Wave-private W staging (r16 FIX: chunk stride 512 shorts (=64 lanes x 16B),
// wave stride 4096 shorts (=128 rows x 32) — r16 used 1024/8192 which both
// mismatched the [row][32] read layout AND overflowed Bs into s_red/beyond
// declared LDS -> absmax 18). Zero barriers in K-loop (vmcnt(0) gates each
// wave's own DMA). K-loop unroll-DISABLED (r3/r14: full unroll of staged
// loop body = compile blow-up = container failure).
// Grid = M/16 = 512 blocks; LDS ~50 KB.
// ---------------------------------------------------------------------------
__global__ __launch_bounds__(256) void ffn_fused_kernel(
    const float* __restrict__ x,          // [M][E] f32
    const unsigned short* __restrict__ W, // Wf bf16 [E][E]
    const float* __restrict__ bias,       // bf [E]
    const float* __restrict__ lnw, const float* __restrict__ lnb,
    float* __restrict__ out) {            // final [M][E] f32
    __shared__ unsigned short Axn[16 * 520];   // 16.6 KB
    __shared__ unsigned short Bs[512 * 32];    // 32 KB (4 waves x 8 KB private)
    __shared__ float s_red[2][4][16];
    const int t = threadIdx.x;
    const int wave = t >> 6, lane = t & 63;
    const int quad = lane >> 4, l16 = lane & 15;
    const int m0 = blockIdx.x * 16;

    // ---- phase 1: front LN, wave handles rows wave*4 .. wave*4+3 ----
    #pragma unroll
    for (int rr = 0; rr < 4; rr++) {
        const int row = wave * 4 + rr;
        const float* xr = x + (size_t)(m0 + row) * E + lane * 8;
        float4 v0 = *(const float4*)xr;
        float4 v1 = *(const float4*)(xr + 4);
        float vv[8] = {v0.x, v0.y, v0.z, v0.w, v1.x, v1.y, v1.z, v1.w};
        float s = 0.f;
        #pragma unroll
        for (int i = 0; i < 8; i++) s += vv[i];
        #pragma unroll
        for (int o = 1; o < 64; o <<= 1) s += __shfl_xor(s, o);
        float mu = s * (1.0f / E);
        float qs = 0.f;
        #pragma unroll
        for (int i = 0; i < 8; i++) { float d = vv[i] - mu; qs += d * d; }
        #pragma unroll
        for (int o = 1; o < 64; o <<= 1) qs += __shfl_xor(qs, o);
        float rs = rsqrtf(qs * (1.0f / E) + EPS);
        float4 w0 = *(const float4*)(lnw + lane * 8), w1 = *(const float4*)(lnw + lane * 8 + 4);
        float4 b0 = *(const float4*)(lnb + lane * 8), b1 = *(const float4*)(lnb + lane * 8 + 4);
        float ww[8] = {w0.x, w0.y, w0.z, w0.w, w1.x, w1.y, w1.z, w1.w};
        float bv[8] = {b0.x, b0.y, b0.z, b0.w, b1.x, b1.y, b1.z, b1.w};
        short8 o8;
        #pragma unroll
        for (int i = 0; i < 8; i++) o8[i] = (short)f2bf((vv[i] - mu) * rs * ww[i] + bv[i]);
        *(short8*)&Axn[row * 520 + lane * 8] = o8;
    }
    __syncthreads();                               // Axn visible to all waves

    // ---- phase 2: GEMM, wave-private W staging, no K-loop barriers ----
    // Wave w owns output cols [w*128, w*128+128) and stages W rows
    // [w*128, w*128+128) into Bw = Bs + w*4096 ([row][32] layout: chunk c is
    // 512 shorts; lane l -> row c*16+(l>>2), colblock (l&3)*8).
    f32x4 acc[8];
    #pragma unroll
    for (int j = 0; j < 8; j++) acc[j] = (f32x4){0.f, 0.f, 0.f, 0.f};
    unsigned short* Bw = Bs + wave * 4096;
    const int brow = lane >> 2;            // row within 16-row chunk
    const int bcol = (lane & 3) * 8;       // 16B col block
    #pragma clang loop unroll(disable)
    for (int k0 = 0; k0 < E; k0 += 32) {
        #pragma unroll
        for (int c = 0; c < 8; c++)
            gload16(W + (size_t)(wave * 128 + c * 16 + brow) * E + k0 + bcol,
                    Bw + c * 512 + lane * 8);
        waitvm<0>();
        short8 af = *(const short8*)&Axn[l16 * 520 + k0 + quad * 8];
        short8 bfr[8];
        #pragma unroll
        for (int j = 0; j < 8; j++)
            bfr[j] = *(const short8*)&Bw[(j * 16 + l16) * 32 + quad * 8];
        #pragma unroll
        for (int j = 0; j < 8; j++)
            acc[j] = __builtin_amdgcn_mfma_f32_16x16x32_bf16(af, bfr[j], acc[j], 0, 0, 0);
    }

    // ---- phase 3: t = acc + bias + xn, then final LN (2-pass) ----
    float tv[4][8];
    #pragma unroll
    for (int j = 0; j < 8; j++) {
        const int col = wave * 128 + j * 16 + l16;
        const float bval = bias[col];
        #pragma unroll
        for (int r = 0; r < 4; r++) {
            const int row = quad * 4 + r;
            tv[r][j] = acc[j][r] + bval + bf2f(Axn[row * 520 + col]);
        }
    }
    // pass 1: mean (per-wave 128-col partials, combine across waves)
    #pragma unroll
    for (int r = 0; r < 4; r++) {
        float s = 0.f;
        #pragma unroll
        for (int j = 0; j < 8; j++) s += tv[r][j];
        #pragma unroll
        for (int o = 1; o < 16; o <<= 1) s += __shfl_xor(s, o);
        if (l16 == 0) s_red[0][wave][quad * 4 + r] = s;
    }
    __syncthreads();
    float mu[4];
    #pragma unroll
    for (int r = 0; r < 4; r++) {
        const int row = quad * 4 + r;
        mu[r] = (s_red[0][0][row] + s_red[0][1][row] +
                 s_red[0][2][row] + s_red[0][3][row]) * (1.0f / E);
    }
    // pass 2: variance = mean((t-mu)^2)
    #pragma unroll
    for (int r = 0; r < 4; r++) {
        float s = 0.f;
        #pragma unroll
        for (int j = 0; j < 8; j++) { float d = tv[r][j] - mu[r]; s += d * d; }
        #pragma unroll
        for (int o = 1; o < 16; o <<= 1) s += __shfl_xor(s, o);
        if (l16 == 0) s_red[1][wave][quad * 4 + r] = s;
    }
    __syncthreads();
    float rsig[4];
    #pragma unroll
    for (int r = 0; r < 4; r++) {
        const int row = quad * 4 + r;
        float var = (s_red[1][0][row] + s_red[1][1][row] +
                     s_red[1][2][row] + s_red[1][3][row]) * (1.0f / E);
        rsig[r] = rsqrtf(var + EPS);
    }
    #pragma unroll
    for (int j = 0; j < 8; j++) {
        const int col = wave * 128 + j * 16 + l16;
        const float wc = lnw[col], bc = lnb[col];
        #pragma unroll
        for (int r = 0; r < 4; r++)
            out[(size_t)(m0 + quad * 4 + r) * E + col] =
                (tv[r][j] - mu[r]) * rsig[r] * wc + bc;
    }
}

// ---------------------------------------------------------------------------
// Fused q + kv projection GEMM (128x128 tile, 768 blocks = 3 blocks/CU).
// ---------------------------------------------------------------------------
__global__ __launch_bounds__(256) void gemm_qkv(
    const unsigned short* __restrict__ Aq, const unsigned short* __restrict__ Akv,
    const unsigned short* __restrict__ W,   // packed [3E][E] bf16
    const float* __restrict__ bias,         // [3E]
    unsigned short* __restrict__ qout,      // [M][512] bf16
    unsigned short* __restrict__ kout,      // [M][512] bf16
    unsigned short* __restrict__ vtout) {   // [B][512][1024] bf16
    __shared__ unsigned short As[128 * 32];
    __shared__ unsigned short Bs[128 * 32];
    const int t = threadIdx.x;
    const int wave = t >> 6, lane = t & 63;
    const int quad = lane >> 4, l16 = lane & 15;
    const bool isq = blockIdx.y < 4;
    const int yy = isq ? blockIdx.y : blockIdx.y - 4;
    const unsigned short* A  = isq ? Aq : Akv;
    const unsigned short* Wb = W + (isq ? 0 : (size_t)E * E);
    const float* bb = bias + (isq ? 0 : E);
    const int m0 = blockIdx.x * 128, n0 = yy * 128;
    const int wm = (wave >> 1) * 64, wn = (wave & 1) * 64;

    const int srow = t >> 2;
    const int skof = (t & 3) * 8;

    f32x4 acc[4][4];
    #pragma unroll
    for (int i = 0; i < 4; i++)
        #pragma unroll
        for (int j = 0; j < 4; j++) acc[i][j] = (f32x4){0.f, 0.f, 0.f, 0.f};

    for (int k0 = 0; k0 < E; k0 += 32) {
        gload16(A + (size_t)(m0 + srow) * E + k0 + skof,         As + t * 8);
        gload16(A + (size_t)(m0 + 64 + srow) * E + k0 + skof,    As + 2048 + t * 8);
        gload16(Wb + (size_t)(n0 + srow) * E + k0 + skof,        Bs + t * 8);
        gload16(Wb + (size_t)(n0 + 64 + srow) * E + k0 + skof,   Bs + 2048 + t * 8);
        __syncthreads();
        short8 af[4], bfr[4];
        #pragma unroll
        for (int i = 0; i < 4; i++)
            af[i] = *(const short8*)&As[(wm + i * 16 + l16) * 32 + quad * 8];
        #pragma unroll
        for (int j = 0; j < 4; j++)
            bfr[j] = *(const short8*)&Bs[(wn + j * 16 + l16) * 32 + quad * 8];
        #pragma unroll
        for (int i = 0; i < 4; i++)
            #pragma unroll
            for (int j = 0; j < 4; j++)
                acc[i][j] = __builtin_amdgcn_mfma_f32_16x16x32_bf16(af[i], bfr[j], acc[i][j], 0, 0, 0);
        __syncthreads();
    }

    #pragma unroll
    for (int i = 0; i < 4; i++) {
        const int mrow0 = m0 + wm + i * 16 + quad * 4;
        #pragma unroll
        for (int j = 0; j < 4; j++) {
            const int ncol = n0 + wn + j * 16 + l16;
            const float bval = bb[ncol];
            if (isq) {
                #pragma unroll
                for (int r = 0; r < 4; r++)
                    qout[(size_t)(mrow0 + r) * 512 + ncol] = f2bf(acc[i][j][r] + bval);
            } else if (ncol < 512) {
                #pragma unroll
                for (int r = 0; r < 4; r++)
                    kout[(size_t)(mrow0 + r) * 512 + ncol] = f2bf(acc[i][j][r] + bval);
            } else {
                const int nv = ncol - 512;
                const int b2 = mrow0 >> 10, s0v = mrow0 & 1023;
                ushort4 o;
                o.x = f2bf(acc[i][j][0] + bval);
                o.y = f2bf(acc[i][j][1] + bval);
                o.z = f2bf(acc[i][j][2] + bval);
                o.w = f2bf(acc[i][j][3] + bval);
                *(ushort4*)(vtout + ((size_t)b2 * 512 + nv) * 1024 + s0v) = o;
            }
        }
    }
}

// ---------------------------------------------------------------------------
// MFMA attention v5b (measured 90.2-90.6 us, FETCH 19 MB — DO NOT
// restructure): staged K+V DMA (gload_lds, XOR swizzle), vmcnt-gated 2-deep
// prefetch, 4 heads/block, XCD panel-pin decode (panel = bid&15). (256,2):
// launch_bounds 2nd arg caps VGPR at ~256/arg (r5/r8). r9 A/B: direct-V
// +20 us. r13: latency-bound internally, NOT L2-bound.
// ---------------------------------------------------------------------------
__global__ __launch_bounds__(256, 2) void attn_mfma_kernel(
    const unsigned short* __restrict__ q,   // [B][S][E] bf16
    const unsigned short* __restrict__ k,   // [B][S][E] bf16
    const unsigned short* __restrict__ vt,  // [B][E][S] bf16
    unsigned short* __restrict__ ctx,       // [B][S][E] bf16
    unsigned short* __restrict__ awp) {     // bf16 planes [2][B][S][S]
    __shared__ unsigned short s_mem[16 * 1032]; // P (16x1032) | K-staging union
    __shared__ unsigned short s_v[4 * 2048];    // V staging: 4 waves x 2 bufs x 1024
    __shared__ float s_red[2][4][16];

    const int t = threadIdx.x;
    const int wave = t >> 6, lane = t & 63;
    const int quad = lane >> 4, l16 = lane & 15;
    const int qt    = blockIdx.x >> 4;      // XCD-pin: panel in LOW bits
    const int panel = blockIdx.x & 15;
    const int hg    = panel & 1;            // head group (4 heads each)
    const int b     = panel >> 1;
    const int q0   = qt * 16;
    const size_t qrow = ((size_t)(b * S + q0 + l16)) * E;

    // wave-private staging areas (shorts)
    unsigned short* karea = s_mem + wave * 4128;   // 2 bufs x 2048 (32 rows x 64)
    unsigned short* varea = s_v + wave * 2048;     // 2 bufs x 1024 (16 rows x 64)

    // DMA lane mapping: dest = base + lane*8 shorts (HW rule); XOR source swizzle
    const int dr = lane >> 3;               // row within 8-row group
    const int dc = lane & 7;                // dest 16B col-block
    const int csrc = dc ^ dr;               // swizzled source col-block
    const int sw7 = l16 & 7;                // read-side swizzle key

    f32x4 awacc[16];
    #pragma unroll
    for (int i = 0; i < 16; i++) awacc[i] = (f32x4){0.f, 0.f, 0.f, 0.f};

    #pragma clang loop unroll(disable)
    for (int hh = 0; hh < 4; hh++) {
        const int h = hg * 4 + hh;

        // K chunk c (32 rows of wave's k-range) -> buf
        auto stage_k = [&](int c, int buf) {
            const unsigned short* src =
                k + ((size_t)(b * S + wave * 256 + c * 32 + dr)) * E + h * 64 + csrc * 8;
            unsigned short* dst = karea + buf * 2048 + dr * 64 + dc * 8;
            gload16(src,                  dst);
            gload16(src + (size_t)8 * E,  dst + 512);
            gload16(src + (size_t)16 * E, dst + 1024);
            gload16(src + (size_t)24 * E, dst + 1536);
        };
        // V chunk cv (64 s-cols of wave's 16 d-rows) -> buf
        auto stage_v = [&](int cv, int buf) {
            const unsigned short* src =
                vt + ((size_t)(b * E + h * 64 + wave * 16 + dr)) * S + cv * 64 + csrc * 8;
            unsigned short* dst = varea + buf * 1024 + dr * 64 + dc * 8;
            gload16(src,                 dst);
            gload16(src + (size_t)8 * S, dst + 512);
        };

        short8 aq0 = *(const short8*)(q + qrow + h * 64 + quad * 8);
        short8 aq1 = *(const short8*)(q + qrow + h * 64 + 32 + quad * 8);

        // ---- scores: 8 staged K chunks, 2-deep prefetch ----
        f32x4 sacc[16];
        stage_k(0, 0);
        stage_k(1, 1);
        #pragma unroll
        for (int c = 0; c < 8; c++) {
            if (c < 7) waitvm<4>(); else waitvm<0>();
            const unsigned short* kbuf = karea + (c & 1) * 2048;
            #pragma unroll
            for (int ntl = 0; ntl < 2; ntl++) {
                const int rl = ntl * 16 + l16;
                short8 kf0 = *(const short8*)(kbuf + rl * 64 + ((quad)     ^ sw7) * 8);
                short8 kf1 = *(const short8*)(kbuf + rl * 64 + ((4 + quad) ^ sw7) * 8);
                f32x4 cc = (f32x4){0.f, 0.f, 0.f, 0.f};
                cc = __builtin_amdgcn_mfma_f32_16x16x32_bf16(aq0, kf0, cc, 0, 0, 0);
                cc = __builtin_amdgcn_mfma_f32_16x16x32_bf16(aq1, kf1, cc, 0, 0, 0);
                sacc[c * 2 + ntl] = cc * 0.125f;
            }
            if (c < 6) stage_k(c + 2, c & 1);
        }

        // ---- merged single-pass softmax: local max+exp+sum pre-barrier ----
        float lm[4], ls[4];
        #pragma unroll
        for (int r = 0; r < 4; r++) {
            float mv = sacc[0][r];
            #pragma unroll
            for (int nt = 1; nt < 16; nt++) mv = fmaxf(mv, sacc[nt][r]);
            #pragma unroll
            for (int o = 1; o < 16; o <<= 1) mv = fmaxf(mv, __shfl_xor(mv, o));
            lm[r] = mv;
            ls[r] = 0.f;
        }
        #pragma unroll
        for (int nt = 0; nt < 16; nt++)
            #pragma unroll
            for (int r = 0; r < 4; r++) {
                float e = __expf(sacc[nt][r] - lm[r]);
                sacc[nt][r] = e;
                ls[r] += e;
            }
        #pragma unroll
        for (int r = 0; r < 4; r++) {
            #pragma unroll
            for (int o = 1; o < 16; o <<= 1) ls[r] += __shfl_xor(ls[r], o);
        }
        if (l16 == 0) {
            #pragma unroll
            for (int r = 0; r < 4; r++) {
                s_red[0][wave][quad * 4 + r] = lm[r];
                s_red[1][wave][quad * 4 + r] = ls[r];
            }
        }
        __syncthreads();                                   // (B1) also: all K reads done
        float scale[4];
        #pragma unroll
        for (int r = 0; r < 4; r++) {
            const int row = quad * 4 + r;
            float m0 = s_red[0][0][row], m1 = s_red[0][1][row];
            float m2 = s_red[0][2][row], m3 = s_red[0][3][row];
            float gmax = fmaxf(fmaxf(m0, m1), fmaxf(m2, m3));
            float gsum = s_red[1][0][row] * __expf(m0 - gmax)
                       + s_red[1][1][row] * __expf(m1 - gmax)
                       + s_red[1][2][row] * __expf(m2 - gmax)
                       + s_red[1][3][row] * __expf(m3 - gmax);
            scale[r] = __expf(lm[r] - gmax) / gsum;
        }

        // ---- normalize, accumulate aw, write P (bf16) into s_mem [16][1032] ----
        #pragma unroll
        for (int nt = 0; nt < 16; nt++) {
            #pragma unroll
            for (int r = 0; r < 4; r++) {
                float p = sacc[nt][r] * scale[r];
                awacc[nt][r] += p;
                s_mem[(quad * 4 + r) * 1032 + wave * 256 + nt * 16 + l16] = f2bf(p);
            }
        }
        __syncthreads();                                   // (B2) P visible

        // ---- PV: 16 staged V chunks, 2-deep prefetch; P from s_mem ----
        f32x4 cacc0 = (f32x4){0.f, 0.f, 0.f, 0.f};
        f32x4 cacc1 = (f32x4){0.f, 0.f, 0.f, 0.f};
        stage_v(0, 0);
        stage_v(1, 1);
        #pragma unroll
        for (int cv = 0; cv < 16; cv++) {
            if (cv < 15) waitvm<2>(); else waitvm<0>();
            const unsigned short* vbuf = varea + (cv & 1) * 1024;
            short8 vf0 = *(const short8*)(vbuf + l16 * 64 + ((quad)     ^ sw7) * 8);
            short8 vf1 = *(const short8*)(vbuf + l16 * 64 + ((4 + quad) ^ sw7) * 8);
            short8 pf0 = *(const short8*)(s_mem + l16 * 1032 + cv * 64 + quad * 8);
            short8 pf1 = *(const short8*)(s_mem + l16 * 1032 + cv * 64 + 32 + quad * 8);
            cacc0 = __builtin_amdgcn_mfma_f32_16x16x32_bf16(pf0, vf0, cacc0, 0, 0, 0);
            cacc1 = __builtin_amdgcn_mfma_f32_16x16x32_bf16(pf1, vf1, cacc1, 0, 0, 0);
            if (cv < 14) stage_v(cv + 2, cv & 1);
        }
        f32x4 cacc = cacc0 + cacc1;
        unsigned short* crow = ctx + ((size_t)(b * S + q0)) * E + h * 64 + wave * 16 + l16;
        #pragma unroll
        for (int r = 0; r < 4; r++)
            crow[(size_t)(quad * 4 + r) * E] = f2bf(cacc[r]);
        __syncthreads();                                   // (B3) P reads done -> K restage safe
    }

    // ---- head-group partial plane (bf16) ----
    #pragma unroll
    for (int nt = 0; nt < 16; nt++) {
        #pragma unroll
        for (int r = 0; r < 4; r++)
            awp[((size_t)((hg * B + b) * S + q0 + quad * 4 + r)) * S +
                wave * 256 + nt * 16 + l16] = f2bf(awacc[nt][r]);
    }
}

// ---------------------------------------------------------------------------
extern "C" void kernel_launch(void* const* d_in, const int* in_sizes, int n_in,
                              void* d_out, int out_size, void* d_ws, size_t ws_size,
                              hipStream_t stream) {
    const float* Zab  = (const float*)d_in[0];
    const float* Za   = (const float*)d_in[1];
    const float* lnw  = (const float*)d_in[2];
    const float* lnb  = (const float*)d_in[3];
    const float* Wqkv = (const float*)d_in[4];
    const float* bqkv = (const float*)d_in[5];
    const float* Wo   = (const float*)d_in[6];
    const float* bo   = (const float*)d_in[7];
    const float* Wf   = (const float*)d_in[8];
    const float* bf   = (const float*)d_in[9];

    float* out_final = (float*)d_out;
    float* out_aw    = out_final + (size_t)B * S * E;

    char* ws = (char*)d_ws;
    // Static buffers (live through attention):
    unsigned short* qb   = (unsigned short*)(ws);               // [0,8M)
    unsigned short* kb   = (unsigned short*)(ws + (8u << 20));  // [8,16M)
    unsigned short* vtb  = (unsigned short*)(ws + (16u << 20)); // [16,24M)
    unsigned short* ctxb = (unsigned short*)(ws + (24u << 20)); // [24,32M)
    // Pre-attention staging (dead once attention starts):
    unsigned short* aqb  = (unsigned short*)(ws + (32u << 20)); // [32,40M)
    unsigned short* akvb = (unsigned short*)(ws + (40u << 20)); // [40,48M)
    // awp planes: 2 x 16 MB at [32,64M) (aqb/akvb dead by attention)
    unsigned short* awp  = (unsigned short*)(ws + (32ull << 20));
    unsigned short* wbf  = (unsigned short*)(ws + (96ull << 20)); // 2.5 MB
    // Post-attention f32 buffer:
    float* xb  = (float*)(ws);                                  // [0,16M)

    dim3 blk(256);

    // 1+2. weights -> bf16 AND LN(Zab)+LN(Za) -> bf16, one launch
    prep_kernel<<<1280 + 4096, blk, 0, stream>>>(Wqkv, Wo, Wf, wbf,
                                                 Zab, Za, lnw, lnb, aqb, akvb);

    // 3. fused q/kv projection: one launch, 768 blocks = 3 blocks/CU
    gemm_qkv<<<dim3(M / 128, 12), blk, 0, stream>>>(aqb, akvb, wbf, bqkv, qb, kb, vtb);

    // 4. attention (staged K/V, 4 heads/block, XCD panel-pin) -> ctx + 2 planes
    attn_mfma_kernel<<<B * 2 * 64, blk, 0, stream>>>(qb, kb, vtb, ctxb, awp);

    // 5. fused: x = ctx@Wo^T + bo + Zab (512 gemm blocks) ∥ aw reduce (4096)
    gemm_o_red<<<512 + 4096, blk, 0, stream>>>(ctxb, wbf + (size_t)3*E*E, bo,
                                               Zab, xb, awp, out_aw);

    // 6. fused FFN v2b: xn=LN(x); t=xn@Wf^T+bf+xn; final=LN(t) — wave-private
    // W staging (fixed strides), no K-loop barriers
    ffn_fused_kernel<<<M / 16, blk, 0, stream>>>(xb, wbf + (size_t)4*E*E, bf,
                                                 lnw, lnb, out_final);
}